// Round 4
// baseline (73605.542 us; speedup 1.0000x reference)
//
#include <hip/hip_runtime.h>
#include <cmath>

constexpr int NB = 128;     // batch
constexpr int NS = 384;     // seq len
constexpr int NH = 384;     // hidden = input dim

typedef __attribute__((ext_vector_type(2))) float f32x2;

__device__ __forceinline__ double clampd(double x, double lo, double hi){ return fmin(fmax(x,lo),hi); }
__device__ __forceinline__ double artanh_(double x){ return atanh(clampd(x, -1.0 + 1e-7, 1.0 - 1e-7)); }
__device__ __forceinline__ double normclip(double s){ return sqrt(fmax(s, 1e-15)); }
__device__ __forceinline__ double wredsumd(double v){
  #pragma unroll
  for (int off = 32; off; off >>= 1) v += __shfl_xor(v, off, 64);
  return v;
}

// ---- coherent (agent-scope, relaxed) element access: bypasses stale caches, no fences ----
__device__ __forceinline__ float ldc(const float* p){
  return __hip_atomic_load((const float*)p, __ATOMIC_RELAXED, __HIP_MEMORY_SCOPE_AGENT);
}
__device__ __forceinline__ void stc(float* p, float v){
  __hip_atomic_store(p, v, __ATOMIC_RELAXED, __HIP_MEMORY_SCOPE_AGENT);
}
__device__ __forceinline__ void waitflag(unsigned* f, unsigned target){
  while (__hip_atomic_load(f, __ATOMIC_RELAXED, __HIP_MEMORY_SCOPE_AGENT) < target)
    __builtin_amdgcn_s_sleep(2);
}

// ---------------- zero / init ----------------
__global__ void kzerod(double* p, int n){
  int i = blockIdx.x * 256 + threadIdx.x;
  if (i < n) p[i] = 0.0;
}
__global__ void kzerof(float* p, int n){
  int i = blockIdx.x * 256 + threadIdx.x;
  if (i < n) p[i] = 0.f;
}
__global__ void kinit(unsigned* FLG, int n){
  int i = blockIdx.x * 256 + threadIdx.x;
  if (i < n) FLG[i] = (i < 4) ? 32u : 0u;   // FA[0][rg] preset: step-0 GEMM reads zero state
}

// ---------------- weight pack (k-major): WTP2[k][j], j<1536 gates W, [1536,1920) W_d ----------------
__global__ void kprepW2(const float* __restrict__ W_all, const float* __restrict__ W_d,
                        float* __restrict__ WTP2)
{
  int i = blockIdx.x * 256 + threadIdx.x;
  if (i >= 384 * 1920) return;
  int k = i / 1920, j = i - k * 1920;
  float v;
  if (j < 1536){ int g = j / 384, r = j - g * 384; v = W_all[r * 1536 + g * 384 + k]; }
  else { int r = j - 1536; v = W_d[r * 384 + k]; }
  WTP2[i] = v;
}

// ---------------- legacy pack for the no-Qp fallback: WTP[c][j], NW=4096 ----------------
__global__ void kprepW(const float* __restrict__ W_all, const float* __restrict__ W_d,
                       const float* __restrict__ U_all, float* __restrict__ WTP, int NW)
{
  int i = blockIdx.x * 256 + threadIdx.x;
  int total = 392 * NW;
  if (i >= total) return;
  int c = i / NW, j = i % NW;
  float v = 0.f;
  if (c < 384){
    if (j < 1536){ int g = j / 384, r = j % 384; v = W_all[r * 1536 + g * 384 + c]; }
    else if (j < 1920){ int r = j - 1536; v = W_d[r * 384 + c]; }
    else if (NW == 4096 && j >= 2048 && j < 3584){
      int jj = j - 2048; int g = jj / 384, r = jj % 384; v = U_all[(g * 384 + r) * 384 + c];
    }
  }
  WTP[i] = v;
}

// UT[c][jj] = U_g[r][c], stride 1536 (for the Qp precompute GEMM)
__global__ void kprepU(const float* __restrict__ U_all, float* __restrict__ UT)
{
  int i = blockIdx.x * 256 + threadIdx.x;
  if (i >= 384 * 1536) return;
  int c = i / 1536, jj = i % 1536;
  int g = jj / 384, r = jj % 384;
  UT[i] = U_all[(g * 384 + r) * 384 + c];
}

// ---------------- xn precompute: XND[b*NS+t] = {xn, artanh(xn)} ----------------
__global__ void kxn(const float* __restrict__ xin, double* __restrict__ XND)
{
  int w = (blockIdx.x * 256 + threadIdx.x) >> 6;
  int ln = threadIdx.x & 63;
  int nw = (gridDim.x * 256) >> 6;
  for (int idx = w; idx < NB * NS; idx += nw){
    double s = 0;
    #pragma unroll
    for (int i = 0; i < 6; ++i){
      float v = xin[(size_t)idx * NH + ln + 64 * i];
      s += (double)v * v;
    }
    s = wredsumd(s);
    if (ln == 0){
      double xn = normclip(s);
      XND[idx * 2] = xn;
      XND[idx * 2 + 1] = artanh_(xn);
    }
  }
}

// ---------------- one-time Q GEMM: Qp[bs][jj] = sum_c X[bs][c] * UT[c][jj] ----------------
__global__ __launch_bounds__(256) void kqgemm2(const float* __restrict__ X,
    const float* __restrict__ Bw, float* __restrict__ Q)
{
  int j0 = blockIdx.x * 64, i0 = blockIdx.y * 64;
  __shared__ __align__(16) float As[32][68];
  __shared__ __align__(16) float Bs[32][64];
  int tid = threadIdx.x;
  int tn = tid & 15, tm = tid >> 4;
  int slm = tid >> 2;
  int slc = (tid & 3) * 8;
  int blk = tid >> 3;
  int bln = (tid & 7) * 8;
  double accd[4][4] = {{0.0}};
  const float* arow = X + (size_t)(i0 + slm) * NH;
  for (int c0 = 0; c0 < NH; c0 += 32){
    float4 a4 = *(const float4*)(arow + c0 + slc);
    float4 a4b = *(const float4*)(arow + c0 + slc + 4);
    As[slc+0][slm] = a4.x;  As[slc+1][slm] = a4.y;
    As[slc+2][slm] = a4.z;  As[slc+3][slm] = a4.w;
    As[slc+4][slm] = a4b.x; As[slc+5][slm] = a4b.y;
    As[slc+6][slm] = a4b.z; As[slc+7][slm] = a4b.w;
    const float* bp = Bw + (size_t)(c0 + blk) * 1536 + j0 + bln;
    float4 b4a = *(const float4*)bp;
    float4 b4b = *(const float4*)(bp + 4);
    *(float4*)&Bs[blk][bln] = b4a;
    *(float4*)&Bs[blk][bln+4] = b4b;
    __syncthreads();
    float acc[4][4] = {{0.f}};
    #pragma unroll 8
    for (int c = 0; c < 32; ++c){
      float4 av = *(const float4*)&As[c][tm*4];
      float4 bv = *(const float4*)&Bs[c][tn*4];
      float a[4] = {av.x, av.y, av.z, av.w};
      float bb[4] = {bv.x, bv.y, bv.z, bv.w};
      #pragma unroll
      for (int mm = 0; mm < 4; ++mm)
        #pragma unroll
        for (int jj = 0; jj < 4; ++jj)
          acc[mm][jj] += a[mm] * bb[jj];
    }
    __syncthreads();
    #pragma unroll
    for (int mm = 0; mm < 4; ++mm)
      #pragma unroll
      for (int jj = 0; jj < 4; ++jj) accd[mm][jj] += (double)acc[mm][jj];
  }
  #pragma unroll
  for (int mm = 0; mm < 4; ++mm){
    float4 o; o.x = (float)accd[mm][0]; o.y = (float)accd[mm][1];
    o.z = (float)accd[mm][2]; o.w = (float)accd[mm][3];
    *(float4*)(Q + (size_t)(i0 + tm*4 + mm) * 1536 + j0 + tn*4) = o;
  }
}

// ---------------- gate chain (identical math to the verified knl) ----------------
__device__ __forceinline__ void gate_chain(const float* __restrict__ pg, const float* __restrict__ qg,
    double hn, double art_hn, double xn, double art_xn, float* __restrict__ out)
{
  double s_p = 0, s_q = 0;
  #pragma unroll
  for (int i = 0; i < 6; ++i){ s_p += (double)pg[i] * pg[i]; s_q += (double)qg[i] * qg[i]; }
  double pn = normclip(wredsumd(s_p));
  double qn = normclip(wredsumd(s_q));
  float saf = (float)(tanh(pn / hn * art_hn) / pn);
  float sbf = (float)(tanh(qn / xn * art_xn) / qn);
  float a6[6], b6[6]; double sx2 = 0, sy2 = 0, sxy = 0;
  #pragma unroll
  for (int i = 0; i < 6; ++i){
    a6[i] = saf * pg[i]; b6[i] = sbf * qg[i];
    sx2 += (double)a6[i] * a6[i]; sy2 += (double)b6[i] * b6[i]; sxy += (double)a6[i] * b6[i];
  }
  sx2 = wredsumd(sx2); sy2 = wredsumd(sy2); sxy = wredsumd(sxy);
  double dd = fmax(1.0 + 2.0 * sxy + sx2 * sy2, 1e-15);
  float fX = (float)((1.0 + 2.0 * sxy + sy2) / dd);
  float fY = (float)((1.0 - sx2) / dd);
  float m6[6]; double smm = 0;
  #pragma unroll
  for (int i = 0; i < 6; ++i){ m6[i] = fX * a6[i] + fY * b6[i]; smm += (double)m6[i] * m6[i]; }
  double nm = normclip(wredsumd(smm));
  float slf = (float)(artanh_(nm) / nm);
  #pragma unroll
  for (int i = 0; i < 6; ++i) out[i] = 1.f / (1.f + expf(-slf * m6[i]));
}

// ================= fused recurrence: weight-stationary column-split + flag sync =================
// 184 persistent blocks x 512 threads (<=240 proven co-resident in an earlier round).
//  blocks 0..119 : GEMM. jt = bid>>2 (30 col-tiles of 64), rg = bid&3 (4 groups of 32 rows).
//                  W tile [384][64] lives in LDS across all steps.
//  blocks 120..183: NL. 2 rows each; per row 4 waves: c-path / gates f,i / gate o(+ctx) / gate ct.
// Cross-block data via relaxed agent atomics (no cache flushes); flags: release fetch_add,
// relaxed poll + control dependency (no acquire -> no L2 invalidation).
struct GemmSM { float W[384 * 64]; float A[32 * 392]; };
struct NlSM   { float g[2][4 * 384]; double hn[2]; double arthn[2]; };

__global__ __launch_bounds__(512, 1) void kstep(
    const float* __restrict__ WTP2, const float* __restrict__ tst,
    const double* __restrict__ XND, const float* __restrict__ Qp,
    float* __restrict__ Zbuf, float* __restrict__ HST, float* __restrict__ CCT,
    float* __restrict__ ctx, float* __restrict__ HS,
    unsigned* __restrict__ FA, unsigned* __restrict__ FZ)
{
  __shared__ union { GemmSM g; NlSM n; } sm;
  const int bid = blockIdx.x;
  const int tid = threadIdx.x;
  const int wv = tid >> 6, ln = tid & 63;

  if (bid < 120){
    // ================= GEMM role =================
    const int jt = bid >> 2, rg = bid & 3;
    // load the fixed W tile once: W[k][c], c = jt*64..+63
    for (int i = tid; i < 384 * 64; i += 512){
      int k = i >> 6, c = i & 63;
      sm.g.W[i] = WTP2[(size_t)k * 1920 + jt * 64 + c];
    }
    __syncthreads();
    const int r  = tid >> 4;            // 0..31
    const int cg = (tid & 15) << 2;     // col offset 0..60
    const float* asrc0 = (jt < 24 ? HST : CCT) + (size_t)rg * 32 * 384;
    for (int t = 0; t < NS; ++t){
      if (tid == 0) waitflag(&FA[t * 4 + rg], 32u);
      __syncthreads();                                   // B0: state ready
      // stage this group's 32-row state slice (coherent loads)
      for (int i = tid; i < 32 * 384; i += 512){
        int rr = i / 384, kk = i - rr * 384;
        sm.g.A[rr * 392 + kk] = ldc(asrc0 + i);
      }
      __syncthreads();                                   // B1: A staged
      const float* Ar = sm.g.A + r * 392;
      double ad[4] = {0.0, 0.0, 0.0, 0.0};
      for (int k0 = 0; k0 < 384; k0 += 96){
        f32x2 ac0 = {0.f, 0.f}, ac1 = {0.f, 0.f};
        #pragma unroll 8
        for (int k = k0; k < k0 + 96; ++k){
          float4 w = *(const float4*)&sm.g.W[k * 64 + cg];
          float a = Ar[k];
          f32x2 av = {a, a};
          ac0 += f32x2{w.x, w.y} * av;
          ac1 += f32x2{w.z, w.w} * av;
        }
        ad[0] += (double)ac0.x; ad[1] += (double)ac0.y;
        ad[2] += (double)ac1.x; ad[3] += (double)ac1.y;
      }
      float* zp = Zbuf + (size_t)(rg * 32 + r) * 1920 + jt * 64 + cg;
      stc(zp + 0, (float)ad[0]); stc(zp + 1, (float)ad[1]);
      stc(zp + 2, (float)ad[2]); stc(zp + 3, (float)ad[3]);
      __syncthreads();                                   // B2: drains all waves' stores
      if (tid == 0)
        __hip_atomic_fetch_add(&FZ[t * 4 + rg], 1u, __ATOMIC_RELEASE, __HIP_MEMORY_SCOPE_AGENT);
    }
  } else {
    // ================= NL role =================
    const int nb = bid - 120;           // 0..63
    const int row = wv >> 2;            // 0/1
    const int wr  = wv & 3;             // wave role within row
    const int b   = nb * 2 + row;
    const int rg  = (nb * 2) >> 5;
    float* Zb = Zbuf + (size_t)b * 1920;
    float cc6[6]; double cc2 = 0.0;
    #pragma unroll
    for (int i = 0; i < 6; ++i) cc6[i] = 0.f;
    if (tid == 0){
      double h0 = normclip(0.0);
      sm.n.hn[0] = h0; sm.n.hn[1] = h0;
      sm.n.arthn[0] = artanh_(h0); sm.n.arthn[1] = artanh_(h0);
    }
    __syncthreads();
    for (int t = 0; t < NS; ++t){
      if (tid == 0) waitflag(&FZ[t * 4 + rg], 30u);
      __syncthreads();                                   // B0: Z ready
      double hn = sm.n.hn[row];
      double art_hn = sm.n.arthn[row];
      float cadj[6];
      if (wr == 0){
        // ---- c path ----
        double ts = (double)tst[b * NS + t];
        float tsf = (float)ts;
        double cn = normclip(cc2);
        float mv6[6]; double s_mv = 0;
        #pragma unroll
        for (int i = 0; i < 6; ++i){
          mv6[i] = ldc(Zb + 1536 + ln + 64 * i);
          s_mv += (double)mv6[i] * mv6[i];
        }
        double mvn = normclip(wredsumd(s_mv));
        double s1 = tanh(mvn / cn * artanh_(cn));
        float c1f = (float)(s1 / mvn);
        float m1[6]; double sm1 = 0;
        #pragma unroll
        for (int i = 0; i < 6; ++i){ m1[i] = c1f * mv6[i]; sm1 += (double)m1[i] * m1[i]; }
        double n1 = normclip(wredsumd(sm1));
        float l1f = (float)(artanh_(n1) / n1);
        float v6[6]; double sv = 0;
        #pragma unroll
        for (int i = 0; i < 6; ++i){ v6[i] = tanhf(l1f * m1[i]); sv += (double)v6[i] * v6[i]; }
        double nv = normclip(wredsumd(sv));
        float e1f = (float)(tanh(nv) / nv);
        float cs1[6]; double scs = 0, sccd = 0;
        #pragma unroll
        for (int i = 0; i < 6; ++i){ cs1[i] = e1f * v6[i]; scs += (double)cs1[i] * cs1[i]; sccd -= (double)cs1[i] * cc6[i]; }
        double xnt = sqrt(fmax(384.0 * ts * ts, 1e-15));
        double swx = 0;
        #pragma unroll
        for (int i = 0; i < 6; ++i){ float w = cs1[i] * tsf; swx += (double)w * w; }
        double wxn1 = normclip(wredsumd(swx));
        double s2c = tanh(wxn1 / xnt * artanh_(xnt)) / wxn1;
        float s2f = (float)(s2c * ts);
        float cs2[6];
        #pragma unroll
        for (int i = 0; i < 6; ++i) cs2[i] = s2f * cs1[i];
        double x2a = wredsumd(scs);
        double xya = wredsumd(sccd);
        double y2a = cc2;
        double dA = fmax(1.0 + 2.0 * xya + x2a * y2a, 1e-15);
        float fXA = (float)((1.0 + 2.0 * xya + y2a) / dA);
        float fYA = (float)((1.0 - x2a) / dA);
        float A6[6]; double sA = 0, sAc = 0, sc2_ = 0;
        #pragma unroll
        for (int i = 0; i < 6; ++i){
          A6[i] = fXA * (-cs1[i]) + fYA * cc6[i];
          sA += (double)A6[i] * A6[i]; sAc += (double)A6[i] * cs2[i]; sc2_ += (double)cs2[i] * cs2[i];
        }
        double x2b = wredsumd(sA), xyb = wredsumd(sAc), y2b = wredsumd(sc2_);
        double dB = fmax(1.0 + 2.0 * xyb + x2b * y2b, 1e-15);
        float fXB = (float)((1.0 + 2.0 * xyb + y2b) / dB);
        float fYB = (float)((1.0 - x2b) / dB);
        #pragma unroll
        for (int i = 0; i < 6; ++i) cadj[i] = fXB * A6[i] + fYB * cs2[i];
      } else {
        double xn = XND[((size_t)b * NS + t) * 2];
        double art_xn = XND[((size_t)b * NS + t) * 2 + 1];
        const float* qp = Qp + ((size_t)b * NS + t) * 1536;
        float pg[6], qg[6], og[6];
        if (wr == 1){
          #pragma unroll
          for (int i = 0; i < 6; ++i){
            pg[i] = ldc(Zb + 0 * 384 + ln + 64 * i);
            qg[i] = qp[0 * 384 + ln + 64 * i];
          }
          gate_chain(pg, qg, hn, art_hn, xn, art_xn, og);
          #pragma unroll
          for (int i = 0; i < 6; ++i) sm.n.g[row][0 * 384 + ln + 64 * i] = og[i];
          #pragma unroll
          for (int i = 0; i < 6; ++i){
            pg[i] = ldc(Zb + 1 * 384 + ln + 64 * i);
            qg[i] = qp[1 * 384 + ln + 64 * i];
          }
          gate_chain(pg, qg, hn, art_hn, xn, art_xn, og);
          #pragma unroll
          for (int i = 0; i < 6; ++i) sm.n.g[row][1 * 384 + ln + 64 * i] = og[i];
        } else if (wr == 2){
          #pragma unroll
          for (int i = 0; i < 6; ++i){
            pg[i] = ldc(Zb + 2 * 384 + ln + 64 * i);
            qg[i] = qp[2 * 384 + ln + 64 * i];
          }
          gate_chain(pg, qg, hn, art_hn, xn, art_xn, og);
          #pragma unroll
          for (int i = 0; i < 6; ++i){
            int rr = ln + 64 * i;
            sm.n.g[row][2 * 384 + rr] = og[i];
            stc(ctx + ((size_t)b * NS + t) * NH + rr, og[i]);   // o-gate is the context
          }
        } else {
          #pragma unroll
          for (int i = 0; i < 6; ++i){
            pg[i] = ldc(Zb + 3 * 384 + ln + 64 * i);
            qg[i] = qp[3 * 384 + ln + 64 * i];
          }
          gate_chain(pg, qg, hn, art_hn, xn, art_xn, og);
          #pragma unroll
          for (int i = 0; i < 6; ++i) sm.n.g[row][3 * 384 + ln + 64 * i] = og[i];
        }
      }
      __syncthreads();                                   // B1: gates ready
      if (wr == 0){
        float g0[6], g1[6], g2[6], g3[6];
        #pragma unroll
        for (int i = 0; i < 6; ++i){
          int rr = ln + 64 * i;
          g0[i] = sm.n.g[row][0 * 384 + rr]; g1[i] = sm.n.g[row][1 * 384 + rr];
          g2[i] = sm.n.g[row][2 * 384 + rr]; g3[i] = sm.n.g[row][3 * 384 + rr];
        }
        double sct = 0, sict = 0; float wP[6];
        #pragma unroll
        for (int i = 0; i < 6; ++i){ float ct = g3[i]; sct += (double)ct * ct; wP[i] = g1[i] * ct; sict += (double)wP[i] * wP[i]; }
        double ctn = normclip(wredsumd(sct));
        double wPn = normclip(wredsumd(sict));
        float sPf = (float)(tanh(wPn / ctn * artanh_(ctn)) / wPn);
        float P6[6]; double sPP = 0;
        #pragma unroll
        for (int i = 0; i < 6; ++i){ P6[i] = sPf * wP[i]; sPP += (double)P6[i] * P6[i]; }
        double sca = 0, sfca = 0; float wQ[6];
        #pragma unroll
        for (int i = 0; i < 6; ++i){ sca += (double)cadj[i] * cadj[i]; wQ[i] = g0[i] * cadj[i]; sfca += (double)wQ[i] * wQ[i]; }
        double can = normclip(wredsumd(sca));
        double wQn = normclip(wredsumd(sfca));
        float sQf = (float)(tanh(wQn / can * artanh_(can)) / wQn);
        float Q6[6]; double sQQ = 0, sPQ = 0;
        #pragma unroll
        for (int i = 0; i < 6; ++i){ Q6[i] = sQf * wQ[i]; sQQ += (double)Q6[i] * Q6[i]; sPQ += (double)P6[i] * Q6[i]; }
        double x2c = wredsumd(sPP), y2c = wredsumd(sQQ), xyc = wredsumd(sPQ);
        double dC = fmax(1.0 + 2.0 * xyc + x2c * y2c, 1e-15);
        float fXC = (float)((1.0 + 2.0 * xyc + y2c) / dC);
        float fYC = (float)((1.0 - x2c) / dC);
        float ccn6[6], w6[6]; double sw_ = 0;
        #pragma unroll
        for (int i = 0; i < 6; ++i){ ccn6[i] = fXC * P6[i] + fYC * Q6[i]; w6[i] = tanhf(ccn6[i]); sw_ += (double)w6[i] * w6[i]; }
        double nw = normclip(wredsumd(sw_));
        float eef = (float)(tanh(nw) / nw);
        float e6[6], wH[6]; double se = 0, soe = 0;
        #pragma unroll
        for (int i = 0; i < 6; ++i){ e6[i] = eef * w6[i]; se += (double)e6[i] * e6[i]; wH[i] = g2[i] * e6[i]; soe += (double)wH[i] * wH[i]; }
        double en = normclip(wredsumd(se));
        double wHn = normclip(wredsumd(soe));
        float sHf = (float)(tanh(wHn / en * artanh_(en)) / wHn);
        float hv[6]; double sh2 = 0, scc2 = 0;
        #pragma unroll
        for (int i = 0; i < 6; ++i){
          hv[i] = sHf * wH[i];
          sh2 += (double)hv[i] * hv[i];
          scc2 += (double)ccn6[i] * ccn6[i];
        }
        double hn_next = normclip(wredsumd(sh2));
        cc2 = wredsumd(scc2);
        #pragma unroll
        for (int i = 0; i < 6; ++i){
          int rr = ln + 64 * i;
          cc6[i] = ccn6[i];
          stc(HST + (size_t)b * 384 + rr, hv[i]);
          stc(CCT + (size_t)b * 384 + rr, ccn6[i]);
        }
        if (ln == 0){
          sm.n.hn[row] = hn_next;
          sm.n.arthn[row] = artanh_(hn_next);
        }
        if (t == NS - 1){
          #pragma unroll
          for (int i = 0; i < 6; ++i) HS[(size_t)b * 384 + ln + 64 * i] = hv[i];
        }
        if (ln == 0)   // wave-level vmcnt in the release add covers this wave's stores
          __hip_atomic_fetch_add(&FA[(t + 1) * 4 + rg], 1u, __ATOMIC_RELEASE, __HIP_MEMORY_SCOPE_AGENT);
      }
      __syncthreads();                                   // B2: hn/arthn visible next step
    }
  }
}

// ================= fallback (no Qp workspace): round-3 row-local recurrence =================
template<int NW, int QPRE>
__global__ __launch_bounds__(512, 1) void krow(
    const float* __restrict__ WTP, const float* __restrict__ xin,
    const float* __restrict__ tst, const double* __restrict__ XND,
    const float* __restrict__ Qp, float* __restrict__ ctx, float* __restrict__ HsOut)
{
  constexpr int NF4 = NW / 1024;
  constexpr int D = (QPRE ? 4 : 2);
  const int tid = threadIdx.x;
  const int grp = tid >> 8;
  const int t256 = tid & 255;
  const int wv = t256 >> 6;
  const int ln = tid & 63;
  const int b = (blockIdx.x << 1) | grp;

  __shared__ __align__(16) float Zrow[2][NW];
  __shared__ f32x2 ALd[2][384][5];
  __shared__ float g384[2][4][384];
  __shared__ double sc[2][2];

  for (int i = tid; i < 2 * 384 * 5; i += 512) ((f32x2*)ALd)[i] = f32x2{0.f, 0.f};
  if (tid < 2){ sc[tid][0] = normclip(0.0); sc[tid][1] = 0.0; }
  __syncthreads();
  if (!QPRE){
    for (int i = t256; i < 384; i += 256){
      float xv = xin[(size_t)b * NS * NH + i];
      ALd[grp][i][2] = f32x2{xv, xv};
    }
    __syncthreads();
  }
  const int col0 = t256 * (NF4 * 4);
  int sel;
  if (col0 < 1536) sel = 0;
  else if (col0 < 1920) sel = 1;
  else if (QPRE) sel = 3;
  else if (col0 < 2048) sel = 3;
  else if (col0 < 3584) sel = 2;
  else sel = 3;
  float qreg[12];
  float xr[6];
  for (int t = 0; t < NS; ++t){
    double ts = 0.0, xn = 0.0, art_xn = 0.0;
    if (wv == 0) ts = (double)tst[b * NS + t];
    else { xn = XND[((size_t)b * NS + t) * 2]; art_xn = XND[((size_t)b * NS + t) * 2 + 1]; }
    if (QPRE){
      const float* qp = Qp + ((size_t)b * NS + t) * 1536;
      if (wv == 1){
        #pragma unroll
        for (int i = 0; i < 12; ++i) qreg[i] = qp[ln + 64 * i];
      } else if (wv == 2){
        #pragma unroll
        for (int i = 0; i < 6; ++i) qreg[i] = qp[768 + ln + 64 * i];
      } else if (wv == 3){
        #pragma unroll
        for (int i = 0; i < 6; ++i) qreg[i] = qp[1152 + ln + 64 * i];
      }
    } else {
      if (wv == 3 && t + 1 < NS){
        #pragma unroll
        for (int i = 0; i < 6; ++i) xr[i] = xin[((size_t)b * NS + t + 1) * NH + ln + 64 * i];
      }
    }
    {
      const float* pt[D];
      #pragma unroll
      for (int d = 0; d < D; ++d) pt[d] = WTP + (size_t)d * NW + col0;
      float4 wb[D][NF4];
      #pragma unroll
      for (int d = 0; d < D; ++d){
        #pragma unroll
        for (int k = 0; k < NF4; ++k) wb[d][k] = *(const float4*)(pt[d] + 4 * k);
        pt[d] += (size_t)D * NW;
      }
      f32x2 acc[NF4 * 2];
      double accd[NF4 * 4];
      #pragma unroll
      for (int k = 0; k < NF4 * 4; ++k) accd[k] = 0.0;
      for (int c0 = 0; c0 < 384; c0 += 96){
        #pragma unroll
        for (int k = 0; k < NF4 * 2; ++k) acc[k] = f32x2{0.f, 0.f};
        for (int cc = 0; cc < 96; cc += D){
          #pragma unroll
          for (int d = 0; d < D; ++d){
            const int c = c0 + cc + d;
            f32x2 aa = ALd[grp][c][sel];
            #pragma unroll
            for (int k = 0; k < NF4; ++k){
              f32x2 w0 = f32x2{wb[d][k].x, wb[d][k].y};
              f32x2 w1 = f32x2{wb[d][k].z, wb[d][k].w};
              acc[2 * k + 0] += w0 * aa;
              acc[2 * k + 1] += w1 * aa;
            }
            #pragma unroll
            for (int k = 0; k < NF4; ++k) wb[d][k] = *(const float4*)(pt[d] + 4 * k);
            pt[d] += (size_t)D * NW;
          }
        }
        #pragma unroll
        for (int k = 0; k < NF4 * 2; ++k){
          accd[2 * k]     += (double)acc[k].x;
          accd[2 * k + 1] += (double)acc[k].y;
        }
      }
      #pragma unroll
      for (int k = 0; k < NF4; ++k){
        float4 o;
        o.x = (float)accd[4 * k + 0]; o.y = (float)accd[4 * k + 1];
        o.z = (float)accd[4 * k + 2]; o.w = (float)accd[4 * k + 3];
        *(float4*)&Zrow[grp][col0 + 4 * k] = o;
      }
    }
    __syncthreads();
    double hn  = sc[grp][0];
    double cc2 = sc[grp][1];
    float cadj[6];
    if (wv == 0){
      double cn = normclip(cc2);
      float cc6[6], mv6[6]; double s_mv = 0;
      #pragma unroll
      for (int i = 0; i < 6; ++i){
        int r = ln + 64 * i;
        cc6[i] = ALd[grp][r][1].x;
        mv6[i] = Zrow[grp][1536 + r];
        s_mv += (double)mv6[i] * mv6[i];
      }
      double mvn = normclip(wredsumd(s_mv));
      double s1 = tanh(mvn / cn * artanh_(cn));
      float c1f = (float)(s1 / mvn);
      float m1[6]; double sm1 = 0;
      #pragma unroll
      for (int i = 0; i < 6; ++i){ m1[i] = c1f * mv6[i]; sm1 += (double)m1[i] * m1[i]; }
      double n1 = normclip(wredsumd(sm1));
      float l1f = (float)(artanh_(n1) / n1);
      float v6[6]; double sv = 0;
      #pragma unroll
      for (int i = 0; i < 6; ++i){ v6[i] = tanhf(l1f * m1[i]); sv += (double)v6[i] * v6[i]; }
      double nv = normclip(wredsumd(sv));
      float e1f = (float)(tanh(nv) / nv);
      float cs1[6]; double scs = 0, sccd = 0;
      #pragma unroll
      for (int i = 0; i < 6; ++i){ cs1[i] = e1f * v6[i]; scs += (double)cs1[i] * cs1[i]; sccd -= (double)cs1[i] * cc6[i]; }
      float tsf = (float)ts;
      double xnt = sqrt(fmax(384.0 * ts * ts, 1e-15));
      double swx = 0;
      #pragma unroll
      for (int i = 0; i < 6; ++i){ float w = cs1[i] * tsf; swx += (double)w * w; }
      double wxn1 = normclip(wredsumd(swx));
      double s2c = tanh(wxn1 / xnt * artanh_(xnt)) / wxn1;
      float s2f = (float)(s2c * ts);
      float cs2[6];
      #pragma unroll
      for (int i = 0; i < 6; ++i) cs2[i] = s2f * cs1[i];
      double x2a = wredsumd(scs);
      double xya = wredsumd(sccd);
      double y2a = cc2;
      double dA = fmax(1.0 + 2.0 * xya + x2a * y2a, 1e-15);
      float fXA = (float)((1.0 + 2.0 * xya + y2a) / dA);
      float fYA = (float)((1.0 - x2a) / dA);
      float A6[6]; double sA = 0, sAc = 0, sc2_ = 0;
      #pragma unroll
      for (int i = 0; i < 6; ++i){
        A6[i] = fXA * (-cs1[i]) + fYA * cc6[i];
        sA += (double)A6[i] * A6[i]; sAc += (double)A6[i] * cs2[i]; sc2_ += (double)cs2[i] * cs2[i];
      }
      double x2b = wredsumd(sA), xyb = wredsumd(sAc), y2b = wredsumd(sc2_);
      double dB = fmax(1.0 + 2.0 * xyb + x2b * y2b, 1e-15);
      float fXB = (float)((1.0 + 2.0 * xyb + y2b) / dB);
      float fYB = (float)((1.0 - x2b) / dB);
      #pragma unroll
      for (int i = 0; i < 6; ++i) cadj[i] = fXB * A6[i] + fYB * cs2[i];
    } else if (wv == 1){
      double art_hn = artanh_(hn);
      float pg[6], qg[6], out[6];
      #pragma unroll
      for (int i = 0; i < 6; ++i){
        int r = ln + 64 * i;
        pg[i] = Zrow[grp][r];
        qg[i] = QPRE ? qreg[i] : Zrow[grp][2048 + r];
      }
      gate_chain(pg, qg, hn, art_hn, xn, art_xn, out);
      #pragma unroll
      for (int i = 0; i < 6; ++i) g384[grp][0][ln + 64 * i] = out[i];
      #pragma unroll
      for (int i = 0; i < 6; ++i){
        int r = ln + 64 * i;
        pg[i] = Zrow[grp][384 + r];
        qg[i] = QPRE ? qreg[6 + i] : Zrow[grp][2048 + 384 + r];
      }
      gate_chain(pg, qg, hn, art_hn, xn, art_xn, out);
      #pragma unroll
      for (int i = 0; i < 6; ++i) g384[grp][1][ln + 64 * i] = out[i];
    } else if (wv == 2){
      double art_hn = artanh_(hn);
      float pg[6], qg[6], out[6];
      #pragma unroll
      for (int i = 0; i < 6; ++i){
        int r = ln + 64 * i;
        pg[i] = Zrow[grp][768 + r];
        qg[i] = QPRE ? qreg[i] : Zrow[grp][2048 + 768 + r];
      }
      gate_chain(pg, qg, hn, art_hn, xn, art_xn, out);
      #pragma unroll
      for (int i = 0; i < 6; ++i){
        int r = ln + 64 * i;
        g384[grp][2][r] = out[i];
        ctx[((size_t)b * NS + t) * NH + r] = out[i];
      }
    } else {
      double art_hn = artanh_(hn);
      float pg[6], qg[6], out[6];
      #pragma unroll
      for (int i = 0; i < 6; ++i){
        int r = ln + 64 * i;
        pg[i] = Zrow[grp][1152 + r];
        qg[i] = QPRE ? qreg[i] : Zrow[grp][2048 + 1152 + r];
      }
      gate_chain(pg, qg, hn, art_hn, xn, art_xn, out);
      #pragma unroll
      for (int i = 0; i < 6; ++i) g384[grp][3][ln + 64 * i] = out[i];
    }
    __syncthreads();
    if (wv == 0){
      float g0[6], g1[6], g2[6], g3[6];
      #pragma unroll
      for (int i = 0; i < 6; ++i){
        int r = ln + 64 * i;
        g0[i] = g384[grp][0][r]; g1[i] = g384[grp][1][r];
        g2[i] = g384[grp][2][r]; g3[i] = g384[grp][3][r];
      }
      double sct = 0, sict = 0; float wP[6];
      #pragma unroll
      for (int i = 0; i < 6; ++i){ float ct = g3[i]; sct += (double)ct * ct; wP[i] = g1[i] * ct; sict += (double)wP[i] * wP[i]; }
      double ctn = normclip(wredsumd(sct));
      double wPn = normclip(wredsumd(sict));
      float sPf = (float)(tanh(wPn / ctn * artanh_(ctn)) / wPn);
      float P6[6]; double sPP = 0;
      #pragma unroll
      for (int i = 0; i < 6; ++i){ P6[i] = sPf * wP[i]; sPP += (double)P6[i] * P6[i]; }
      double sca = 0, sfca = 0; float wQ[6];
      #pragma unroll
      for (int i = 0; i < 6; ++i){ sca += (double)cadj[i] * cadj[i]; wQ[i] = g0[i] * cadj[i]; sfca += (double)wQ[i] * wQ[i]; }
      double can = normclip(wredsumd(sca));
      double wQn = normclip(wredsumd(sfca));
      float sQf = (float)(tanh(wQn / can * artanh_(can)) / wQn);
      float Q6[6]; double sQQ = 0, sPQ = 0;
      #pragma unroll
      for (int i = 0; i < 6; ++i){ Q6[i] = sQf * wQ[i]; sQQ += (double)Q6[i] * Q6[i]; sPQ += (double)P6[i] * Q6[i]; }
      double x2c = wredsumd(sPP), y2c = wredsumd(sQQ), xyc = wredsumd(sPQ);
      double dC = fmax(1.0 + 2.0 * xyc + x2c * y2c, 1e-15);
      float fXC = (float)((1.0 + 2.0 * xyc + y2c) / dC);
      float fYC = (float)((1.0 - x2c) / dC);
      float ccn6[6], w6[6]; double sw_ = 0;
      #pragma unroll
      for (int i = 0; i < 6; ++i){ ccn6[i] = fXC * P6[i] + fYC * Q6[i]; w6[i] = tanhf(ccn6[i]); sw_ += (double)w6[i] * w6[i]; }
      double nw = normclip(wredsumd(sw_));
      float eef = (float)(tanh(nw) / nw);
      float e6[6], wH[6]; double se = 0, soe = 0;
      #pragma unroll
      for (int i = 0; i < 6; ++i){ e6[i] = eef * w6[i]; se += (double)e6[i] * e6[i]; wH[i] = g2[i] * e6[i]; soe += (double)wH[i] * wH[i]; }
      double en = normclip(wredsumd(se));
      double wHn = normclip(wredsumd(soe));
      float sHf = (float)(tanh(wHn / en * artanh_(en)) / wHn);
      float hv[6]; double sh2 = 0, scc2 = 0;
      #pragma unroll
      for (int i = 0; i < 6; ++i){
        hv[i] = sHf * wH[i];
        sh2 += (double)hv[i] * hv[i];
        scc2 += (double)ccn6[i] * ccn6[i];
      }
      double hn_next = normclip(wredsumd(sh2));
      double cc2_next = wredsumd(scc2);
      #pragma unroll
      for (int i = 0; i < 6; ++i){
        int r = ln + 64 * i;
        ALd[grp][r][0] = f32x2{hv[i], hv[i]};
        ALd[grp][r][1] = f32x2{ccn6[i], ccn6[i]};
      }
      if (ln == 0){ sc[grp][0] = hn_next; sc[grp][1] = cc2_next; }
      if (t == NS - 1){
        #pragma unroll
        for (int i = 0; i < 6; ++i) HsOut[b * NH + ln + 64 * i] = hv[i];
      }
    }
    if (!QPRE && wv == 3 && t + 1 < NS){
      #pragma unroll
      for (int i = 0; i < 6; ++i) ALd[grp][ln + 64 * i][2] = f32x2{xr[i], xr[i]};
    }
    __syncthreads();
  }
}

// ---------------- block reduce helpers ----------------
__device__ __forceinline__ double blocksumd(double v, double* red){
  v = wredsumd(v);
  __syncthreads();
  if ((threadIdx.x & 63) == 0) red[threadIdx.x >> 6] = v;
  __syncthreads();
  return red[0] + red[1] + red[2] + red[3];
}
__device__ __forceinline__ double blockmaxd(double v, double* red){
  #pragma unroll
  for (int off = 32; off; off >>= 1) v = fmax(v, __shfl_xor(v, off, 64));
  __syncthreads();
  if ((threadIdx.x & 63) == 0) red[threadIdx.x >> 6] = v;
  __syncthreads();
  return fmax(fmax(red[0], red[1]), fmax(red[2], red[3]));
}

// ---------------- query / scores / softmax / aw / bt ----------------
__global__ __launch_bounds__(256) void kattn1(const float* __restrict__ Hs,
    const float* __restrict__ Win, const float* __restrict__ ctx,
    const float* __restrict__ dt, const float* __restrict__ ab,
    double* __restrict__ query, double* __restrict__ aw, double* __restrict__ bt)
{
  int b = blockIdx.x; int tid = threadIdx.x;
  __shared__ double hL[NH], qL[NH], scs[NS];
  __shared__ double red[4];
  for (int r = tid; r < NH; r += 256) hL[r] = (double)Hs[b * NH + r];
  __syncthreads();
  for (int r = tid; r < NH; r += 256){
    double s = 0;
    const float* wr = Win + (size_t)r * NH;
    for (int c = 0; c < NH; ++c) s += hL[c] * (double)wr[c];
    qL[r] = s; query[b * NH + r] = s;
  }
  __syncthreads();
  int wv = tid >> 6, ln = tid & 63;
  for (int s_ = wv; s_ < NS; s_ += 4){
    const float* crow = ctx + ((size_t)b * NS + s_) * NH;
    double par = 0;
    #pragma unroll
    for (int i = 0; i < 6; ++i){ int d = ln + 64 * i; par += qL[d] * (double)crow[d]; }
    par = wredsumd(par);
    if (ln == 0) scs[s_] = par;
  }
  __syncthreads();
  double v0 = scs[tid];
  double v1 = (tid + 256 < NS) ? scs[tid + 256] : -1e300;
  double mx = blockmaxd(fmax(v0, v1), red);
  double e0 = exp(v0 - mx);
  double e1 = (tid + 256 < NS) ? exp(v1 - mx) : 0.0;
  double tot = blocksumd(e0 + e1, red);
  double a0 = e0 / tot, a1 = e1 / tot;
  double n = normclip(blocksumd(a0 * a0 + a1 * a1, red));
  double s1 = tanh(n) / n;
  double w0 = s1 * a0, w1 = s1 * a1;
  double pn = normclip(blocksumd(w0 * w0 + w1 * w1, red));
  if (pn > 0.999){ double f = 0.999 / pn; w0 *= f; w1 *= f; }
  aw[b * NS + tid] = w0;
  if (tid + 256 < NS) aw[b * NS + tid + 256] = w1;
  double abv = (double)ab[b];
  double b0 = exp(-abv * (double)dt[b * NS + tid]);
  double b1v = (tid + 256 < NS) ? exp(-abv * (double)dt[b * NS + tid + 256]) : 0.0;
  double nb = normclip(blocksumd(b0 * b0 + b1v * b1v, red));
  double sb = tanh(nb) / nb;
  double c0 = sb * b0, c1 = sb * b1v;
  double pnb = normclip(blocksumd(c0 * c0 + c1 * c1, red));
  if (pnb > 0.999){ double f = 0.999 / pnb; c0 *= f; c1 *= f; }
  bt[b * NS + tid] = c0;
  if (tid + 256 < NS) bt[b * NS + tid + 256] = c1;
}

// ---------------- hyperbolic attention mixing ----------------
__global__ __launch_bounds__(256) void kmix(const float* __restrict__ ctx,
    const double* __restrict__ aw, const double* __restrict__ bt,
    const float* __restrict__ ae, double* __restrict__ nom, double* __restrict__ den)
{
  int b = blockIdx.y; int h0 = blockIdx.x * 32;
  __shared__ float T[32][385];
  int tid = threadIdx.x;
  for (int idx = tid; idx < NS * 32; idx += 256){
    int s = idx >> 5, hh = idx & 31;
    T[hh][s] = ctx[((size_t)b * NS + s) * NH + h0 + hh];
  }
  __syncthreads();
  int wv = tid >> 6, ln = tid & 63;
  double aev = (double)ae[b];
  double aw6[6], bt6[6]; double sbt = 0;
  #pragma unroll
  for (int i = 0; i < 6; ++i){
    aw6[i] = aw[b * NS + ln + 64 * i];
    bt6[i] = bt[b * NS + ln + 64 * i];
    sbt += bt6[i] * bt6[i];
  }
  double xnb = normclip(wredsumd(sbt));
  double art_xnb = artanh_(xnb);
  double denacc = 0.0;
  for (int k = 0; k < 8; ++k){
    int hh = wv * 8 + k;
    double v[6]; double sx = 0;
    #pragma unroll
    for (int i = 0; i < 6; ++i){ v[i] = (double)T[hh][ln + 64 * i]; sx += v[i] * v[i]; }
    double xnv = normclip(wredsumd(sx));
    double wx[6]; double swx = 0;
    #pragma unroll
    for (int i = 0; i < 6; ++i){ wx[i] = aw6[i] * v[i]; swx += wx[i] * wx[i]; }
    double wxn = normclip(wredsumd(swx));
    double s1 = tanh(wxn / xnv * artanh_(xnv)) / wxn;
    double mix[6]; double sm = 0;
    #pragma unroll
    for (int i = 0; i < 6; ++i){ mix[i] = s1 * wx[i]; sm += mix[i] * mix[i]; }
    double n1 = normclip(wredsumd(sm));
    if (n1 > 0.999){ double f = 0.999 / n1;
      #pragma unroll
      for (int i = 0; i < 6; ++i) mix[i] *= f; }
    double sm2 = 0;
    #pragma unroll
    for (int i = 0; i < 6; ++i) sm2 += mix[i] * mix[i];
    double xn2 = normclip(wredsumd(sm2));
    double wx2[6]; double sw2 = 0;
    #pragma unroll
    for (int i = 0; i < 6; ++i){ wx2[i] = aev * mix[i]; sw2 += wx2[i] * wx2[i]; }
    double wxn2 = normclip(wredsumd(sw2));
    double s2 = tanh(wxn2 / xn2 * artanh_(xn2)) / wxn2;
    double tmp[6]; double st = 0;
    #pragma unroll
    for (int i = 0; i < 6; ++i){ tmp[i] = s2 * wx2[i]; st += tmp[i] * tmp[i]; }
    double n2 = normclip(wredsumd(st));
    if (n2 > 0.999){ double f = 0.999 / n2;
      #pragma unroll
      for (int i = 0; i < 6; ++i) tmp[i] *= f; }
    double wx3[6]; double sw3 = 0;
    #pragma unroll
    for (int i = 0; i < 6; ++i){ wx3[i] = tmp[i] * bt6[i]; sw3 += wx3[i] * wx3[i]; }
    double wxn3 = normclip(wredsumd(sw3));
    double s3 = tanh(wxn3 / xnb * art_xnb) / wxn3;
    double t2[6]; double st2 = 0;
    #pragma unroll
    for (int i = 0; i < 6; ++i){ t2[i] = s3 * wx3[i]; st2 += t2[i] * t2[i]; }
    double n3 = normclip(wredsumd(st2));
    if (n3 > 0.999){ double f = 0.999 / n3;
      #pragma unroll
      for (int i = 0; i < 6; ++i) t2[i] *= f; }
    #pragma unroll
    for (int i = 0; i < 6; ++i) t2[i] = fmax(t2[i], 0.0);
    double sxx = 0, syy = 0, sxy = 0;
    #pragma unroll
    for (int i = 0; i < 6; ++i){ sxx += mix[i] * mix[i]; syy += t2[i] * t2[i]; sxy += mix[i] * t2[i]; }
    sxx = wredsumd(sxx); syy = wredsumd(syy); sxy = wredsumd(sxy);
    double dn = fmax(1.0 + 2.0 * sxy + sxx * syy, 1e-15);
    double ca = (1.0 + 2.0 * sxy + syy) / dn, cb = (1.0 - sxx) / dn;
    double m2[6]; double sm3 = 0;
    #pragma unroll
    for (int i = 0; i < 6; ++i){ m2[i] = ca * mix[i] + cb * t2[i]; sm3 += m2[i] * m2[i]; }
    double n4 = normclip(wredsumd(sm3));
    if (n4 > 0.999){ double f = 0.999 / n4;
      #pragma unroll
      for (int i = 0; i < 6; ++i) m2[i] *= f; }
    double snn = 0;
    #pragma unroll
    for (int i = 0; i < 6; ++i) snn += m2[i] * m2[i];
    snn = wredsumd(snn);
    double lam = 2.0 / fmax(1.0 - snn, 1e-15);
    #pragma unroll
    for (int i = 0; i < 6; ++i) atomicAdd(&nom[b * NS + ln + 64 * i], lam * m2[i]);
    if (ln == 0) denacc += lam - 1.0;
  }
  if (ln == 0) atomicAdd(&den[b], denacc);
}

// ---------------- midpoint + logmap0 + output head ----------------
__global__ __launch_bounds__(256) void kfinal(const double* __restrict__ nom,
    const double* __restrict__ den, const double* __restrict__ query,
    const float* __restrict__ Wout, const float* __restrict__ W1,
    const float* __restrict__ b1, const float* __restrict__ W2,
    const float* __restrict__ b2, float* __restrict__ out)
{
  int b = blockIdx.x; int tid = threadIdx.x;
  __shared__ double comb[768];
  __shared__ double att[NH];
  __shared__ double x1[NH];
  __shared__ double red[4];
  double dnb = fmax(den[b], 1e-10);
  double u0 = nom[b * NS + tid] / dnb;
  double u1 = (tid + 256 < NS) ? nom[b * NS + tid + 256] / dnb : 0.0;
  double n = normclip(blocksumd(u0 * u0 + u1 * u1, red));
  double sf = tanh(0.5 * artanh_(n)) / n;
  double f0 = sf * u0, f1 = sf * u1;
  double n2 = normclip(blocksumd(f0 * f0 + f1 * f1, red));
  double sl = artanh_(n2) / n2;
  comb[tid] = sl * f0;
  if (tid + 256 < NS) comb[tid + 256] = sl * f1;
  for (int r = tid; r < NH; r += 256) comb[NH + r] = query[b * NH + r];
  __syncthreads();
  for (int r = tid; r < NH; r += 256){
    double s = 0;
    const float* wr = Wout + (size_t)r * 768;
    for (int c = 0; c < 768; ++c) s += comb[c] * (double)wr[c];
    att[r] = tanh(s);
  }
  __syncthreads();
  for (int r = tid; r < NH; r += 256){
    double s = (double)b1[r];
    const float* wr = W1 + (size_t)r * NH;
    for (int c = 0; c < NH; ++c) s += att[c] * (double)wr[c];
    x1[r] = fmax(s, 0.0);
  }
  __syncthreads();
  double p0 = 0, p1 = 0;
  for (int c = tid; c < NH; c += 256){ p0 += x1[c] * (double)W2[c]; p1 += x1[c] * (double)W2[NH + c]; }
  p0 = blocksumd(p0, red);
  p1 = blocksumd(p1, red);
  if (tid == 0){ out[b * 2 + 0] = (float)(p0 + (double)b2[0]); out[b * 2 + 1] = (float)(p1 + (double)b2[1]); }
}

extern "C" void kernel_launch(void* const* d_in, const int* in_sizes, int n_in,
                              void* d_out, int out_size, void* d_ws, size_t ws_size,
                              hipStream_t stream)
{
  (void)in_sizes; (void)n_in; (void)out_size;
  const float* inputs  = (const float*)d_in[0];
  const float* tstamps = (const float*)d_in[1];
  const float* delta_t = (const float*)d_in[2];
  const float* W_all   = (const float*)d_in[3];
  const float* U_all   = (const float*)d_in[4];
  const float* W_d     = (const float*)d_in[5];
  const float* Win     = (const float*)d_in[6];
  const float* Wout    = (const float*)d_in[7];
  const float* ae      = (const float*)d_in[8];
  const float* ab      = (const float*)d_in[9];
  const float* W1      = (const float*)d_in[10];
  const float* b1      = (const float*)d_in[11];
  const float* W2      = (const float*)d_in[12];
  const float* b2      = (const float*)d_in[13];
  float* out = (float*)d_out;

  // double region
  double* wd = (double*)d_ws;
  size_t od = 0;
  double* NOMD  = wd + od; od += (size_t)NB * NS;
  double* DEND  = wd + od; od += (size_t)NB;
  double* QUERY = wd + od; od += (size_t)NB * NH;
  double* AW    = wd + od; od += (size_t)NB * NS;
  double* BT    = wd + od; od += (size_t)NB * NS;
  double* XND   = wd + od; od += (size_t)NB * NS * 2;
  // flags (4096 dwords reserved)
  unsigned* FLG = (unsigned*)(wd + od);
  const int NFLAG = (NS + 1) * 4 + NS * 4;
  unsigned* FA = FLG;
  unsigned* FZ = FLG + (NS + 1) * 4;
  // float region
  float* wf = (float*)((char*)FLG + 4096 * 4);
  size_t of = 0;
  float* WTP  = wf + of; of += (size_t)392 * 4096;     // shared: k-major pack / legacy pack
  float* UT   = wf + of; of += (size_t)384 * 1536;
  float* CTX  = wf + of; of += (size_t)NB * NS * NH;
  float* HS   = wf + of; of += (size_t)NB * NH;
  float* HST  = wf + of; of += (size_t)NB * NH;        // coherent h state
  float* CCT  = wf + of; of += (size_t)NB * NH;        // coherent cc state
  float* Zbuf = wf + of; of += (size_t)NB * 1920;      // coherent Z
  float* Qp   = wf + of;                               // 302 MB

  size_t base_bytes = od * 8 + 4096 * 4 + of * 4;
  size_t q_bytes = (size_t)NB * NS * 1536 * 4;
  bool usePre = (ws_size >= base_bytes + q_bytes);

  // zero midpoint accumulators
  int nzd = NB * NS + NB;
  hipLaunchKernelGGL(kzerod, dim3((nzd + 255) / 256), dim3(256), 0, stream, NOMD, nzd);
  hipLaunchKernelGGL(kxn, dim3(768), dim3(256), 0, stream, inputs, XND);

  if (usePre){
    // flags + state init
    hipLaunchKernelGGL(kinit, dim3((NFLAG + 255) / 256), dim3(256), 0, stream, FLG, NFLAG);
    hipLaunchKernelGGL(kzerof, dim3((2 * NB * NH + 255) / 256), dim3(256), 0, stream, HST, 2 * NB * NH);
    // weights + Qp
    hipLaunchKernelGGL(kprepW2, dim3((384 * 1920 + 255) / 256), dim3(256), 0, stream, W_all, W_d, WTP);
    hipLaunchKernelGGL(kprepU, dim3((384 * 1536 + 255) / 256), dim3(256), 0, stream, U_all, UT);
    hipLaunchKernelGGL(kqgemm2, dim3(24, 768), dim3(256), 0, stream, inputs, UT, Qp);
    // fused recurrence: 120 GEMM blocks + 64 NL blocks, flag-synced
    hipLaunchKernelGGL(kstep, dim3(184), dim3(512), 0, stream,
                       WTP, tstamps, XND, Qp, Zbuf, HST, CCT, CTX, HS, FA, FZ);
  } else {
    hipLaunchKernelGGL(kprepW, dim3((392 * 4096 + 255) / 256), dim3(256), 0, stream,
                       W_all, W_d, U_all, WTP, 4096);
    hipLaunchKernelGGL(HIP_KERNEL_NAME(krow<4096, 0>), dim3(64), dim3(512), 0, stream,
                       WTP, inputs, tstamps, XND, WTP /*unused*/, CTX, HS);
  }

  hipLaunchKernelGGL(kattn1, dim3(128), dim3(256), 0, stream,
                     HS, Win, CTX, delta_t, ab, QUERY, AW, BT);
  hipLaunchKernelGGL(kmix, dim3(12, 128), dim3(256), 0, stream, CTX, AW, BT, ae, NOMD, DEND);
  hipLaunchKernelGGL(kfinal, dim3(128), dim3(256), 0, stream,
                     NOMD, DEND, QUERY, Wout, W1, b1, W2, b2, out);
}

// Round 5
// 29156.006 us; speedup vs baseline: 2.5245x; 2.5245x over previous
//
#include <hip/hip_runtime.h>
#include <cmath>

constexpr int NB = 128;     // batch
constexpr int NS = 384;     // seq len
constexpr int NH = 384;     // hidden = input dim

typedef __attribute__((ext_vector_type(2))) float f32x2;

__device__ __forceinline__ double clampd(double x, double lo, double hi){ return fmin(fmax(x,lo),hi); }
__device__ __forceinline__ double artanh_(double x){ return atanh(clampd(x, -1.0 + 1e-7, 1.0 - 1e-7)); }
__device__ __forceinline__ double normclip(double s){ return sqrt(fmax(s, 1e-15)); }
__device__ __forceinline__ double wredsumd(double v){
  #pragma unroll
  for (int off = 32; off; off >>= 1) v += __shfl_xor(v, off, 64);
  return v;
}

// ---------------- zero ----------------
__global__ void kzerod(double* p, int n){
  int i = blockIdx.x * 256 + threadIdx.x;
  if (i < n) p[i] = 0.0;
}

// ---------------- weight pack: WTP[c][j] over NW cols ----------------
// j<1536: gate W (4 gates x 384); [1536,1920): W_d; [2048,3584) (NW=4096 only): U gates; else 0.
// 392 rows (8 pad rows for prefetch over-read).
__global__ void kprepW(const float* __restrict__ W_all, const float* __restrict__ W_d,
                       const float* __restrict__ U_all, float* __restrict__ WTP, int NW)
{
  int i = blockIdx.x * 256 + threadIdx.x;
  int total = 392 * NW;
  if (i >= total) return;
  int c = i / NW, j = i % NW;
  float v = 0.f;
  if (c < 384){
    if (j < 1536){ int g = j / 384, r = j % 384; v = W_all[r * 1536 + g * 384 + c]; }
    else if (j < 1920){ int r = j - 1536; v = W_d[r * 384 + c]; }
    else if (NW == 4096 && j >= 2048 && j < 3584){
      int jj = j - 2048; int g = jj / 384, r = jj % 384; v = U_all[(g * 384 + r) * 384 + c];
    }
  }
  WTP[i] = v;
}

// UT[c][jj] = U_g[r][c], stride 1536 (for the Qp precompute GEMM)
__global__ void kprepU(const float* __restrict__ U_all, float* __restrict__ UT)
{
  int i = blockIdx.x * 256 + threadIdx.x;
  if (i >= 384 * 1536) return;
  int c = i / 1536, jj = i % 1536;
  int g = jj / 384, r = jj % 384;
  UT[i] = U_all[(g * 384 + r) * 384 + c];
}

// ---------------- xn precompute: XND[b*NS+t] = {xn, artanh(xn)} ----------------
__global__ void kxn(const float* __restrict__ xin, double* __restrict__ XND)
{
  int w = (blockIdx.x * 256 + threadIdx.x) >> 6;
  int ln = threadIdx.x & 63;
  int nw = (gridDim.x * 256) >> 6;
  for (int idx = w; idx < NB * NS; idx += nw){
    double s = 0;
    #pragma unroll
    for (int i = 0; i < 6; ++i){
      float v = xin[(size_t)idx * NH + ln + 64 * i];
      s += (double)v * v;
    }
    s = wredsumd(s);
    if (ln == 0){
      double xn = normclip(s);
      XND[idx * 2] = xn;
      XND[idx * 2 + 1] = artanh_(xn);
    }
  }
}

// ---------------- chunked Q GEMM: Q[rloc][jj] = sum_c X[b(rloc)][t0+tt(rloc)][c] * UT[c][jj] ----
// rloc = b*CH + tt, chunk-local. grid (24, 2*CH), block 256.
__global__ __launch_bounds__(256) void kqgemmc(const float* __restrict__ X,
    const float* __restrict__ Bw, float* __restrict__ Q, int t0, int CH)
{
  int j0 = blockIdx.x * 64, i0 = blockIdx.y * 64;
  __shared__ __align__(16) float As[32][68];
  __shared__ __align__(16) float Bs[32][64];
  int tid = threadIdx.x;
  int tn = tid & 15, tm = tid >> 4;
  int slm = tid >> 2;
  int slc = (tid & 3) * 8;
  int blk = tid >> 3;
  int bln = (tid & 7) * 8;
  double accd[4][4] = {{0.0}};
  int rloc = i0 + slm;
  int bb = rloc / CH, tt = rloc - bb * CH;
  const float* arow = X + ((size_t)bb * NS + t0 + tt) * NH;
  for (int c0 = 0; c0 < NH; c0 += 32){
    float4 a4 = *(const float4*)(arow + c0 + slc);
    float4 a4b = *(const float4*)(arow + c0 + slc + 4);
    As[slc+0][slm] = a4.x;  As[slc+1][slm] = a4.y;
    As[slc+2][slm] = a4.z;  As[slc+3][slm] = a4.w;
    As[slc+4][slm] = a4b.x; As[slc+5][slm] = a4b.y;
    As[slc+6][slm] = a4b.z; As[slc+7][slm] = a4b.w;
    const float* bp = Bw + (size_t)(c0 + blk) * 1536 + j0 + bln;
    float4 b4a = *(const float4*)bp;
    float4 b4b = *(const float4*)(bp + 4);
    *(float4*)&Bs[blk][bln] = b4a;
    *(float4*)&Bs[blk][bln+4] = b4b;
    __syncthreads();
    float acc[4][4] = {{0.f}};
    #pragma unroll 8
    for (int c = 0; c < 32; ++c){
      float4 av = *(const float4*)&As[c][tm*4];
      float4 bv = *(const float4*)&Bs[c][tn*4];
      float a[4] = {av.x, av.y, av.z, av.w};
      float bb2[4] = {bv.x, bv.y, bv.z, bv.w};
      #pragma unroll
      for (int mm = 0; mm < 4; ++mm)
        #pragma unroll
        for (int jj = 0; jj < 4; ++jj)
          acc[mm][jj] += a[mm] * bb2[jj];
    }
    __syncthreads();
    #pragma unroll
    for (int mm = 0; mm < 4; ++mm)
      #pragma unroll
      for (int jj = 0; jj < 4; ++jj) accd[mm][jj] += (double)acc[mm][jj];
  }
  #pragma unroll
  for (int mm = 0; mm < 4; ++mm){
    float4 o; o.x = (float)accd[mm][0]; o.y = (float)accd[mm][1];
    o.z = (float)accd[mm][2]; o.w = (float)accd[mm][3];
    *(float4*)(Q + (size_t)(i0 + tm*4 + mm) * 1536 + j0 + tn*4) = o;
  }
}

// ---------------- gate chain (identical math to the verified knl) ----------------
__device__ __forceinline__ void gate_chain(const float* __restrict__ pg, const float* __restrict__ qg,
    double hn, double art_hn, double xn, double art_xn, float* __restrict__ out)
{
  double s_p = 0, s_q = 0;
  #pragma unroll
  for (int i = 0; i < 6; ++i){ s_p += (double)pg[i] * pg[i]; s_q += (double)qg[i] * qg[i]; }
  double pn = normclip(wredsumd(s_p));
  double qn = normclip(wredsumd(s_q));
  float saf = (float)(tanh(pn / hn * art_hn) / pn);
  float sbf = (float)(tanh(qn / xn * art_xn) / qn);
  float a6[6], b6[6]; double sx2 = 0, sy2 = 0, sxy = 0;
  #pragma unroll
  for (int i = 0; i < 6; ++i){
    a6[i] = saf * pg[i]; b6[i] = sbf * qg[i];
    sx2 += (double)a6[i] * a6[i]; sy2 += (double)b6[i] * b6[i]; sxy += (double)a6[i] * b6[i];
  }
  sx2 = wredsumd(sx2); sy2 = wredsumd(sy2); sxy = wredsumd(sxy);
  double dd = fmax(1.0 + 2.0 * sxy + sx2 * sy2, 1e-15);
  float fX = (float)((1.0 + 2.0 * sxy + sy2) / dd);
  float fY = (float)((1.0 - sx2) / dd);
  float m6[6]; double smm = 0;
  #pragma unroll
  for (int i = 0; i < 6; ++i){ m6[i] = fX * a6[i] + fY * b6[i]; smm += (double)m6[i] * m6[i]; }
  double nm = normclip(wredsumd(smm));
  float slf = (float)(artanh_(nm) / nm);
  #pragma unroll
  for (int i = 0; i < 6; ++i) out[i] = 1.f / (1.f + expf(-slf * m6[i]));
}

// ================= row-local fused recurrence (chunked): NO inter-block sync =================
// 64 blocks x 512 threads. Block owns rows 2*bid, 2*bid+1 (row-group = 256 threads, 4 waves).
// Steps [t0,t1); state persisted in HSV/CCV/SCV across chunk launches.
template<int NW, int QPRE>
__global__ __launch_bounds__(512, 1) void krow(
    const float* __restrict__ WTP, const float* __restrict__ xin,
    const float* __restrict__ tst, const double* __restrict__ XND,
    const float* __restrict__ Qp, int CH, int t0, int t1,
    float* __restrict__ ctx, float* __restrict__ HsOut,
    float* __restrict__ HSV, float* __restrict__ CCV, double* __restrict__ SCV)
{
  constexpr int NF4 = NW / 1024;        // float4 per thread per c: 2 or 4
  constexpr int D = (QPRE ? 4 : 2);     // prefetch depth
  const int tid = threadIdx.x;
  const int grp = tid >> 8;             // row-group 0/1
  const int t256 = tid & 255;
  const int wv = t256 >> 6;             // wave within group
  const int ln = tid & 63;
  const int b = (blockIdx.x << 1) | grp;

  __shared__ __align__(16) float Zrow[2][NW];
  __shared__ f32x2 ALd[2][384][5];      // slots: 0=h, 1=cc, 2=x, 3=zero (5 pads banks)
  __shared__ float g384[2][4][384];
  __shared__ double sc[2][2];           // {hn, cc2}

  // init / restore state
  for (int i = tid; i < 2 * 384 * 5; i += 512) ((f32x2*)ALd)[i] = f32x2{0.f, 0.f};
  __syncthreads();
  if (t0 == 0){
    if (tid < 2){ sc[tid][0] = normclip(0.0); sc[tid][1] = 0.0; }
  } else {
    for (int i = t256; i < 384; i += 256){
      float hv_ = HSV[(size_t)b * 384 + i];
      float cv_ = CCV[(size_t)b * 384 + i];
      ALd[grp][i][0] = f32x2{hv_, hv_};
      ALd[grp][i][1] = f32x2{cv_, cv_};
    }
    if (t256 == 0){ sc[grp][0] = SCV[b * 2]; sc[grp][1] = SCV[b * 2 + 1]; }
  }
  __syncthreads();
  if (!QPRE){
    for (int i = t256; i < 384; i += 256){
      float xv = xin[((size_t)b * NS + t0) * NH + i];
      ALd[grp][i][2] = f32x2{xv, xv};
    }
    __syncthreads();
  }

  const int col0 = t256 * (NF4 * 4);
  int sel;
  if (col0 < 1536) sel = 0;
  else if (col0 < 1920) sel = 1;
  else if (QPRE) sel = 3;
  else if (col0 < 2048) sel = 3;
  else if (col0 < 3584) sel = 2;
  else sel = 3;

  float qreg[12];
  float xr[6];

  for (int t = t0; t < t1; ++t){
    // ---- prefetches (latency hidden under GEMM) ----
    double ts = 0.0, xn = 0.0, art_xn = 0.0;
    if (wv == 0) ts = (double)tst[b * NS + t];
    else { xn = XND[((size_t)b * NS + t) * 2]; art_xn = XND[((size_t)b * NS + t) * 2 + 1]; }
    if (QPRE){
      const float* qp = Qp + ((size_t)b * CH + (t - t0)) * 1536;
      if (wv == 1){
        #pragma unroll
        for (int i = 0; i < 12; ++i) qreg[i] = qp[ln + 64 * i];
      } else if (wv == 2){
        #pragma unroll
        for (int i = 0; i < 6; ++i) qreg[i] = qp[768 + ln + 64 * i];
      } else if (wv == 3){
        #pragma unroll
        for (int i = 0; i < 6; ++i) qreg[i] = qp[1152 + ln + 64 * i];
      }
    } else {
      if (wv == 3 && t + 1 < t1){
        #pragma unroll
        for (int i = 0; i < 6; ++i) xr[i] = xin[((size_t)b * NS + t + 1) * NH + ln + 64 * i];
      }
    }

    // ---- GEMM: matvec over K=384, fp32 packed FMA + fp64 flush each 96 ----
    {
      const float* pt[D];
      #pragma unroll
      for (int d = 0; d < D; ++d) pt[d] = WTP + (size_t)d * NW + col0;
      float4 wb[D][NF4];
      #pragma unroll
      for (int d = 0; d < D; ++d){
        #pragma unroll
        for (int k = 0; k < NF4; ++k) wb[d][k] = *(const float4*)(pt[d] + 4 * k);
        pt[d] += (size_t)D * NW;
      }
      f32x2 acc[NF4 * 2];
      double accd[NF4 * 4];
      #pragma unroll
      for (int k = 0; k < NF4 * 4; ++k) accd[k] = 0.0;
      for (int c0 = 0; c0 < 384; c0 += 96){
        #pragma unroll
        for (int k = 0; k < NF4 * 2; ++k) acc[k] = f32x2{0.f, 0.f};
        for (int cc = 0; cc < 96; cc += D){
          #pragma unroll
          for (int d = 0; d < D; ++d){
            const int c = c0 + cc + d;
            f32x2 aa = ALd[grp][c][sel];
            #pragma unroll
            for (int k = 0; k < NF4; ++k){
              f32x2 w0 = f32x2{wb[d][k].x, wb[d][k].y};
              f32x2 w1 = f32x2{wb[d][k].z, wb[d][k].w};
              acc[2 * k + 0] += w0 * aa;
              acc[2 * k + 1] += w1 * aa;
            }
            #pragma unroll
            for (int k = 0; k < NF4; ++k) wb[d][k] = *(const float4*)(pt[d] + 4 * k);
            pt[d] += (size_t)D * NW;
          }
        }
        #pragma unroll
        for (int k = 0; k < NF4 * 2; ++k){
          accd[2 * k]     += (double)acc[k].x;
          accd[2 * k + 1] += (double)acc[k].y;
        }
      }
      #pragma unroll
      for (int k = 0; k < NF4; ++k){
        float4 o;
        o.x = (float)accd[4 * k + 0]; o.y = (float)accd[4 * k + 1];
        o.z = (float)accd[4 * k + 2]; o.w = (float)accd[4 * k + 3];
        *(float4*)&Zrow[grp][col0 + 4 * k] = o;
      }
    }
    __syncthreads();   // B1: Zrow ready

    // ---- NL ----
    double hn  = sc[grp][0];
    double cc2 = sc[grp][1];
    float cadj[6];
    if (wv == 0){
      // c-path
      double cn = normclip(cc2);
      float cc6[6], mv6[6]; double s_mv = 0;
      #pragma unroll
      for (int i = 0; i < 6; ++i){
        int r = ln + 64 * i;
        cc6[i] = ALd[grp][r][1].x;
        mv6[i] = Zrow[grp][1536 + r];
        s_mv += (double)mv6[i] * mv6[i];
      }
      double mvn = normclip(wredsumd(s_mv));
      double s1 = tanh(mvn / cn * artanh_(cn));
      float c1f = (float)(s1 / mvn);
      float m1[6]; double sm1 = 0;
      #pragma unroll
      for (int i = 0; i < 6; ++i){ m1[i] = c1f * mv6[i]; sm1 += (double)m1[i] * m1[i]; }
      double n1 = normclip(wredsumd(sm1));
      float l1f = (float)(artanh_(n1) / n1);
      float v6[6]; double sv = 0;
      #pragma unroll
      for (int i = 0; i < 6; ++i){ v6[i] = tanhf(l1f * m1[i]); sv += (double)v6[i] * v6[i]; }
      double nv = normclip(wredsumd(sv));
      float e1f = (float)(tanh(nv) / nv);
      float cs1[6]; double scs = 0, sccd = 0;
      #pragma unroll
      for (int i = 0; i < 6; ++i){ cs1[i] = e1f * v6[i]; scs += (double)cs1[i] * cs1[i]; sccd -= (double)cs1[i] * cc6[i]; }
      float tsf = (float)ts;
      double xnt = sqrt(fmax(384.0 * ts * ts, 1e-15));
      double swx = 0;
      #pragma unroll
      for (int i = 0; i < 6; ++i){ float w = cs1[i] * tsf; swx += (double)w * w; }
      double wxn1 = normclip(wredsumd(swx));
      double s2c = tanh(wxn1 / xnt * artanh_(xnt)) / wxn1;
      float s2f = (float)(s2c * ts);
      float cs2[6];
      #pragma unroll
      for (int i = 0; i < 6; ++i) cs2[i] = s2f * cs1[i];
      double x2a = wredsumd(scs);
      double xya = wredsumd(sccd);
      double y2a = cc2;
      double dA = fmax(1.0 + 2.0 * xya + x2a * y2a, 1e-15);
      float fXA = (float)((1.0 + 2.0 * xya + y2a) / dA);
      float fYA = (float)((1.0 - x2a) / dA);
      float A6[6]; double sA = 0, sAc = 0, sc2_ = 0;
      #pragma unroll
      for (int i = 0; i < 6; ++i){
        A6[i] = fXA * (-cs1[i]) + fYA * cc6[i];
        sA += (double)A6[i] * A6[i]; sAc += (double)A6[i] * cs2[i]; sc2_ += (double)cs2[i] * cs2[i];
      }
      double x2b = wredsumd(sA), xyb = wredsumd(sAc), y2b = wredsumd(sc2_);
      double dB = fmax(1.0 + 2.0 * xyb + x2b * y2b, 1e-15);
      float fXB = (float)((1.0 + 2.0 * xyb + y2b) / dB);
      float fYB = (float)((1.0 - x2b) / dB);
      #pragma unroll
      for (int i = 0; i < 6; ++i) cadj[i] = fXB * A6[i] + fYB * cs2[i];
    } else if (wv == 1){
      double art_hn = artanh_(hn);
      float pg[6], qg[6], out[6];
      #pragma unroll
      for (int i = 0; i < 6; ++i){
        int r = ln + 64 * i;
        pg[i] = Zrow[grp][r];
        qg[i] = QPRE ? qreg[i] : Zrow[grp][2048 + r];
      }
      gate_chain(pg, qg, hn, art_hn, xn, art_xn, out);
      #pragma unroll
      for (int i = 0; i < 6; ++i) g384[grp][0][ln + 64 * i] = out[i];
      #pragma unroll
      for (int i = 0; i < 6; ++i){
        int r = ln + 64 * i;
        pg[i] = Zrow[grp][384 + r];
        qg[i] = QPRE ? qreg[6 + i] : Zrow[grp][2048 + 384 + r];
      }
      gate_chain(pg, qg, hn, art_hn, xn, art_xn, out);
      #pragma unroll
      for (int i = 0; i < 6; ++i) g384[grp][1][ln + 64 * i] = out[i];
    } else if (wv == 2){
      double art_hn = artanh_(hn);
      float pg[6], qg[6], out[6];
      #pragma unroll
      for (int i = 0; i < 6; ++i){
        int r = ln + 64 * i;
        pg[i] = Zrow[grp][768 + r];
        qg[i] = QPRE ? qreg[i] : Zrow[grp][2048 + 768 + r];
      }
      gate_chain(pg, qg, hn, art_hn, xn, art_xn, out);
      #pragma unroll
      for (int i = 0; i < 6; ++i){
        int r = ln + 64 * i;
        g384[grp][2][r] = out[i];
        ctx[((size_t)b * NS + t) * NH + r] = out[i];   // o-gate is the context
      }
    } else {
      double art_hn = artanh_(hn);
      float pg[6], qg[6], out[6];
      #pragma unroll
      for (int i = 0; i < 6; ++i){
        int r = ln + 64 * i;
        pg[i] = Zrow[grp][1152 + r];
        qg[i] = QPRE ? qreg[i] : Zrow[grp][2048 + 1152 + r];
      }
      gate_chain(pg, qg, hn, art_hn, xn, art_xn, out);
      #pragma unroll
      for (int i = 0; i < 6; ++i) g384[grp][3][ln + 64 * i] = out[i];
    }
    __syncthreads();   // B2: gates ready

    if (wv == 0){
      // combine: cc_n = mobius_add(pw(i,ct), pw(f,c_adj)); h_n = pw(o, expmap0(tanh(cc_n)))
      float g0[6], g1[6], g2[6], g3[6];
      #pragma unroll
      for (int i = 0; i < 6; ++i){
        int r = ln + 64 * i;
        g0[i] = g384[grp][0][r]; g1[i] = g384[grp][1][r];
        g2[i] = g384[grp][2][r]; g3[i] = g384[grp][3][r];
      }
      double sct = 0, sict = 0; float wP[6];
      #pragma unroll
      for (int i = 0; i < 6; ++i){ float ct = g3[i]; sct += (double)ct * ct; wP[i] = g1[i] * ct; sict += (double)wP[i] * wP[i]; }
      double ctn = normclip(wredsumd(sct));
      double wPn = normclip(wredsumd(sict));
      float sPf = (float)(tanh(wPn / ctn * artanh_(ctn)) / wPn);
      float P6[6]; double sPP = 0;
      #pragma unroll
      for (int i = 0; i < 6; ++i){ P6[i] = sPf * wP[i]; sPP += (double)P6[i] * P6[i]; }
      double sca = 0, sfca = 0; float wQ[6];
      #pragma unroll
      for (int i = 0; i < 6; ++i){ sca += (double)cadj[i] * cadj[i]; wQ[i] = g0[i] * cadj[i]; sfca += (double)wQ[i] * wQ[i]; }
      double can = normclip(wredsumd(sca));
      double wQn = normclip(wredsumd(sfca));
      float sQf = (float)(tanh(wQn / can * artanh_(can)) / wQn);
      float Q6[6]; double sQQ = 0, sPQ = 0;
      #pragma unroll
      for (int i = 0; i < 6; ++i){ Q6[i] = sQf * wQ[i]; sQQ += (double)Q6[i] * Q6[i]; sPQ += (double)P6[i] * Q6[i]; }
      double x2c = wredsumd(sPP), y2c = wredsumd(sQQ), xyc = wredsumd(sPQ);
      double dC = fmax(1.0 + 2.0 * xyc + x2c * y2c, 1e-15);
      float fXC = (float)((1.0 + 2.0 * xyc + y2c) / dC);
      float fYC = (float)((1.0 - x2c) / dC);
      float ccn6[6], w6[6]; double sw_ = 0;
      #pragma unroll
      for (int i = 0; i < 6; ++i){ ccn6[i] = fXC * P6[i] + fYC * Q6[i]; w6[i] = tanhf(ccn6[i]); sw_ += (double)w6[i] * w6[i]; }
      double nw = normclip(wredsumd(sw_));
      float eef = (float)(tanh(nw) / nw);
      float e6[6], wH[6]; double se = 0, soe = 0;
      #pragma unroll
      for (int i = 0; i < 6; ++i){ e6[i] = eef * w6[i]; se += (double)e6[i] * e6[i]; wH[i] = g2[i] * e6[i]; soe += (double)wH[i] * wH[i]; }
      double en = normclip(wredsumd(se));
      double wHn = normclip(wredsumd(soe));
      float sHf = (float)(tanh(wHn / en * artanh_(en)) / wHn);
      float hv[6]; double sh2 = 0, scc2 = 0;
      #pragma unroll
      for (int i = 0; i < 6; ++i){
        hv[i] = sHf * wH[i];
        sh2 += (double)hv[i] * hv[i];
        scc2 += (double)ccn6[i] * ccn6[i];
      }
      double hn_next = normclip(wredsumd(sh2));
      double cc2_next = wredsumd(scc2);
      #pragma unroll
      for (int i = 0; i < 6; ++i){
        int r = ln + 64 * i;
        ALd[grp][r][0] = f32x2{hv[i], hv[i]};
        ALd[grp][r][1] = f32x2{ccn6[i], ccn6[i]};
      }
      if (ln == 0){ sc[grp][0] = hn_next; sc[grp][1] = cc2_next; }
      if (t == t1 - 1){
        #pragma unroll
        for (int i = 0; i < 6; ++i){
          int r = ln + 64 * i;
          HSV[(size_t)b * 384 + r] = hv[i];
          CCV[(size_t)b * 384 + r] = ccn6[i];
        }
        if (ln == 0){ SCV[b * 2] = hn_next; SCV[b * 2 + 1] = cc2_next; }
      }
      if (t == NS - 1){
        #pragma unroll
        for (int i = 0; i < 6; ++i) HsOut[b * NH + ln + 64 * i] = hv[i];
      }
    }
    if (!QPRE && wv == 3 && t + 1 < t1){
      #pragma unroll
      for (int i = 0; i < 6; ++i) ALd[grp][ln + 64 * i][2] = f32x2{xr[i], xr[i]};
    }
    __syncthreads();   // B3: ALd state ready for next t
  }
}

// ---------------- block reduce helpers ----------------
__device__ __forceinline__ double blocksumd(double v, double* red){
  v = wredsumd(v);
  __syncthreads();
  if ((threadIdx.x & 63) == 0) red[threadIdx.x >> 6] = v;
  __syncthreads();
  return red[0] + red[1] + red[2] + red[3];
}
__device__ __forceinline__ double blockmaxd(double v, double* red){
  #pragma unroll
  for (int off = 32; off; off >>= 1) v = fmax(v, __shfl_xor(v, off, 64));
  __syncthreads();
  if ((threadIdx.x & 63) == 0) red[threadIdx.x >> 6] = v;
  __syncthreads();
  return fmax(fmax(red[0], red[1]), fmax(red[2], red[3]));
}

// ---------------- query / scores / softmax / aw / bt ----------------
__global__ __launch_bounds__(256) void kattn1(const float* __restrict__ Hs,
    const float* __restrict__ Win, const float* __restrict__ ctx,
    const float* __restrict__ dt, const float* __restrict__ ab,
    double* __restrict__ query, double* __restrict__ aw, double* __restrict__ bt)
{
  int b = blockIdx.x; int tid = threadIdx.x;
  __shared__ double hL[NH], qL[NH], scs[NS];
  __shared__ double red[4];
  for (int r = tid; r < NH; r += 256) hL[r] = (double)Hs[b * NH + r];
  __syncthreads();
  for (int r = tid; r < NH; r += 256){
    double s = 0;
    const float* wr = Win + (size_t)r * NH;
    for (int c = 0; c < NH; ++c) s += hL[c] * (double)wr[c];
    qL[r] = s; query[b * NH + r] = s;
  }
  __syncthreads();
  int wv = tid >> 6, ln = tid & 63;
  for (int s_ = wv; s_ < NS; s_ += 4){
    const float* crow = ctx + ((size_t)b * NS + s_) * NH;
    double par = 0;
    #pragma unroll
    for (int i = 0; i < 6; ++i){ int d = ln + 64 * i; par += qL[d] * (double)crow[d]; }
    par = wredsumd(par);
    if (ln == 0) scs[s_] = par;
  }
  __syncthreads();
  double v0 = scs[tid];
  double v1 = (tid + 256 < NS) ? scs[tid + 256] : -1e300;
  double mx = blockmaxd(fmax(v0, v1), red);
  double e0 = exp(v0 - mx);
  double e1 = (tid + 256 < NS) ? exp(v1 - mx) : 0.0;
  double tot = blocksumd(e0 + e1, red);
  double a0 = e0 / tot, a1 = e1 / tot;
  double n = normclip(blocksumd(a0 * a0 + a1 * a1, red));
  double s1 = tanh(n) / n;
  double w0 = s1 * a0, w1 = s1 * a1;
  double pn = normclip(blocksumd(w0 * w0 + w1 * w1, red));
  if (pn > 0.999){ double f = 0.999 / pn; w0 *= f; w1 *= f; }
  aw[b * NS + tid] = w0;
  if (tid + 256 < NS) aw[b * NS + tid + 256] = w1;
  double abv = (double)ab[b];
  double b0 = exp(-abv * (double)dt[b * NS + tid]);
  double b1v = (tid + 256 < NS) ? exp(-abv * (double)dt[b * NS + tid + 256]) : 0.0;
  double nb = normclip(blocksumd(b0 * b0 + b1v * b1v, red));
  double sb = tanh(nb) / nb;
  double c0 = sb * b0, c1 = sb * b1v;
  double pnb = normclip(blocksumd(c0 * c0 + c1 * c1, red));
  if (pnb > 0.999){ double f = 0.999 / pnb; c0 *= f; c1 *= f; }
  bt[b * NS + tid] = c0;
  if (tid + 256 < NS) bt[b * NS + tid + 256] = c1;
}

// ---------------- hyperbolic attention mixing ----------------
__global__ __launch_bounds__(256) void kmix(const float* __restrict__ ctx,
    const double* __restrict__ aw, const double* __restrict__ bt,
    const float* __restrict__ ae, double* __restrict__ nom, double* __restrict__ den)
{
  int b = blockIdx.y; int h0 = blockIdx.x * 32;
  __shared__ float T[32][385];
  int tid = threadIdx.x;
  for (int idx = tid; idx < NS * 32; idx += 256){
    int s = idx >> 5, hh = idx & 31;
    T[hh][s] = ctx[((size_t)b * NS + s) * NH + h0 + hh];
  }
  __syncthreads();
  int wv = tid >> 6, ln = tid & 63;
  double aev = (double)ae[b];
  double aw6[6], bt6[6]; double sbt = 0;
  #pragma unroll
  for (int i = 0; i < 6; ++i){
    aw6[i] = aw[b * NS + ln + 64 * i];
    bt6[i] = bt[b * NS + ln + 64 * i];
    sbt += bt6[i] * bt6[i];
  }
  double xnb = normclip(wredsumd(sbt));
  double art_xnb = artanh_(xnb);
  double denacc = 0.0;
  for (int k = 0; k < 8; ++k){
    int hh = wv * 8 + k;
    double v[6]; double sx = 0;
    #pragma unroll
    for (int i = 0; i < 6; ++i){ v[i] = (double)T[hh][ln + 64 * i]; sx += v[i] * v[i]; }
    double xnv = normclip(wredsumd(sx));
    double wx[6]; double swx = 0;
    #pragma unroll
    for (int i = 0; i < 6; ++i){ wx[i] = aw6[i] * v[i]; swx += wx[i] * wx[i]; }
    double wxn = normclip(wredsumd(swx));
    double s1 = tanh(wxn / xnv * artanh_(xnv)) / wxn;
    double mix[6]; double sm = 0;
    #pragma unroll
    for (int i = 0; i < 6; ++i){ mix[i] = s1 * wx[i]; sm += mix[i] * mix[i]; }
    double n1 = normclip(wredsumd(sm));
    if (n1 > 0.999){ double f = 0.999 / n1;
      #pragma unroll
      for (int i = 0; i < 6; ++i) mix[i] *= f; }
    double sm2 = 0;
    #pragma unroll
    for (int i = 0; i < 6; ++i) sm2 += mix[i] * mix[i];
    double xn2 = normclip(wredsumd(sm2));
    double wx2[6]; double sw2 = 0;
    #pragma unroll
    for (int i = 0; i < 6; ++i){ wx2[i] = aev * mix[i]; sw2 += wx2[i] * wx2[i]; }
    double wxn2 = normclip(wredsumd(sw2));
    double s2 = tanh(wxn2 / xn2 * artanh_(xn2)) / wxn2;
    double tmp[6]; double st = 0;
    #pragma unroll
    for (int i = 0; i < 6; ++i){ tmp[i] = s2 * wx2[i]; st += tmp[i] * tmp[i]; }
    double n2 = normclip(wredsumd(st));
    if (n2 > 0.999){ double f = 0.999 / n2;
      #pragma unroll
      for (int i = 0; i < 6; ++i) tmp[i] *= f; }
    double wx3[6]; double sw3 = 0;
    #pragma unroll
    for (int i = 0; i < 6; ++i){ wx3[i] = tmp[i] * bt6[i]; sw3 += wx3[i] * wx3[i]; }
    double wxn3 = normclip(wredsumd(sw3));
    double s3 = tanh(wxn3 / xnb * art_xnb) / wxn3;
    double t2[6]; double st2 = 0;
    #pragma unroll
    for (int i = 0; i < 6; ++i){ t2[i] = s3 * wx3[i]; st2 += t2[i] * t2[i]; }
    double n3 = normclip(wredsumd(st2));
    if (n3 > 0.999){ double f = 0.999 / n3;
      #pragma unroll
      for (int i = 0; i < 6; ++i) t2[i] *= f; }
    #pragma unroll
    for (int i = 0; i < 6; ++i) t2[i] = fmax(t2[i], 0.0);
    double sxx = 0, syy = 0, sxy = 0;
    #pragma unroll
    for (int i = 0; i < 6; ++i){ sxx += mix[i] * mix[i]; syy += t2[i] * t2[i]; sxy += mix[i] * t2[i]; }
    sxx = wredsumd(sxx); syy = wredsumd(syy); sxy = wredsumd(sxy);
    double dn = fmax(1.0 + 2.0 * sxy + sxx * syy, 1e-15);
    double ca = (1.0 + 2.0 * sxy + syy) / dn, cb = (1.0 - sxx) / dn;
    double m2[6]; double sm3 = 0;
    #pragma unroll
    for (int i = 0; i < 6; ++i){ m2[i] = ca * mix[i] + cb * t2[i]; sm3 += m2[i] * m2[i]; }
    double n4 = normclip(wredsumd(sm3));
    if (n4 > 0.999){ double f = 0.999 / n4;
      #pragma unroll
      for (int i = 0; i < 6; ++i) m2[i] *= f; }
    double snn = 0;
    #pragma unroll
    for (int i = 0; i < 6; ++i) snn += m2[i] * m2[i];
    snn = wredsumd(snn);
    double lam = 2.0 / fmax(1.0 - snn, 1e-15);
    #pragma unroll
    for (int i = 0; i < 6; ++i) atomicAdd(&nom[b * NS + ln + 64 * i], lam * m2[i]);
    if (ln == 0) denacc += lam - 1.0;
  }
  if (ln == 0) atomicAdd(&den[b], denacc);
}

// ---------------- midpoint + logmap0 + output head ----------------
__global__ __launch_bounds__(256) void kfinal(const double* __restrict__ nom,
    const double* __restrict__ den, const double* __restrict__ query,
    const float* __restrict__ Wout, const float* __restrict__ W1,
    const float* __restrict__ b1, const float* __restrict__ W2,
    const float* __restrict__ b2, float* __restrict__ out)
{
  int b = blockIdx.x; int tid = threadIdx.x;
  __shared__ double comb[768];
  __shared__ double att[NH];
  __shared__ double x1[NH];
  __shared__ double red[4];
  double dnb = fmax(den[b], 1e-10);
  double u0 = nom[b * NS + tid] / dnb;
  double u1 = (tid + 256 < NS) ? nom[b * NS + tid + 256] / dnb : 0.0;
  double n = normclip(blocksumd(u0 * u0 + u1 * u1, red));
  double sf = tanh(0.5 * artanh_(n)) / n;
  double f0 = sf * u0, f1 = sf * u1;
  double n2 = normclip(blocksumd(f0 * f0 + f1 * f1, red));
  double sl = artanh_(n2) / n2;
  comb[tid] = sl * f0;
  if (tid + 256 < NS) comb[tid + 256] = sl * f1;
  for (int r = tid; r < NH; r += 256) comb[NH + r] = query[b * NH + r];
  __syncthreads();
  for (int r = tid; r < NH; r += 256){
    double s = 0;
    const float* wr = Wout + (size_t)r * 768;
    for (int c = 0; c < 768; ++c) s += comb[c] * (double)wr[c];
    att[r] = tanh(s);
  }
  __syncthreads();
  for (int r = tid; r < NH; r += 256){
    double s = (double)b1[r];
    const float* wr = W1 + (size_t)r * NH;
    for (int c = 0; c < NH; ++c) s += att[c] * (double)wr[c];
    x1[r] = fmax(s, 0.0);
  }
  __syncthreads();
  double p0 = 0, p1 = 0;
  for (int c = tid; c < NH; c += 256){ p0 += x1[c] * (double)W2[c]; p1 += x1[c] * (double)W2[NH + c]; }
  p0 = blocksumd(p0, red);
  p1 = blocksumd(p1, red);
  if (tid == 0){ out[b * 2 + 0] = (float)(p0 + (double)b2[0]); out[b * 2 + 1] = (float)(p1 + (double)b2[1]); }
}

extern "C" void kernel_launch(void* const* d_in, const int* in_sizes, int n_in,
                              void* d_out, int out_size, void* d_ws, size_t ws_size,
                              hipStream_t stream)
{
  (void)in_sizes; (void)n_in; (void)out_size;
  const float* inputs  = (const float*)d_in[0];
  const float* tstamps = (const float*)d_in[1];
  const float* delta_t = (const float*)d_in[2];
  const float* W_all   = (const float*)d_in[3];
  const float* U_all   = (const float*)d_in[4];
  const float* W_d     = (const float*)d_in[5];
  const float* Win     = (const float*)d_in[6];
  const float* Wout    = (const float*)d_in[7];
  const float* ae      = (const float*)d_in[8];
  const float* ab      = (const float*)d_in[9];
  const float* W1      = (const float*)d_in[10];
  const float* b1      = (const float*)d_in[11];
  const float* W2      = (const float*)d_in[12];
  const float* b2      = (const float*)d_in[13];
  float* out = (float*)d_out;

  // double region
  double* wd = (double*)d_ws;
  size_t od = 0;
  double* NOMD  = wd + od; od += (size_t)NB * NS;
  double* DEND  = wd + od; od += (size_t)NB;
  double* QUERY = wd + od; od += (size_t)NB * NH;
  double* AW    = wd + od; od += (size_t)NB * NS;
  double* BT    = wd + od; od += (size_t)NB * NS;
  double* XND   = wd + od; od += (size_t)NB * NS * 2;
  double* SCV   = wd + od; od += (size_t)NB * 2;
  // float region
  float* wf = (float*)(wd + od);
  size_t of = 0;
  float* WTP  = wf + of; of += (size_t)392 * 4096;     // shared weight pack (max layout)
  float* UT   = wf + of; of += (size_t)384 * 1536;
  float* CTX  = wf + of; of += (size_t)NB * NS * NH;
  float* HS   = wf + of; of += (size_t)NB * NH;
  float* HSV  = wf + of; of += (size_t)NB * NH;        // chunk-boundary h state
  float* CCV  = wf + of; of += (size_t)NB * NH;        // chunk-boundary cc state
  float* Qp   = wf + of;                               // Qp chunk buffer (sized by CH)

  size_t base_bytes = od * 8 + of * 4;

  // pick the largest time-chunk whose Qp buffer fits the workspace
  int CH = 0;
  const int chs[7] = {384, 192, 96, 48, 24, 12, 6};
  for (int ci = 0; ci < 7; ++ci){
    size_t need = base_bytes + (size_t)NB * chs[ci] * 1536 * 4;
    if (ws_size >= need){ CH = chs[ci]; break; }
  }

  // zero midpoint accumulators + xn precompute
  int nzd = NB * NS + NB;
  hipLaunchKernelGGL(kzerod, dim3((nzd + 255) / 256), dim3(256), 0, stream, NOMD, nzd);
  hipLaunchKernelGGL(kxn, dim3(768), dim3(256), 0, stream, inputs, XND);

  if (CH > 0){
    // 1920-col panel (3.2 MB < 4 MB/XCD L2 -> weight stream stays L2-resident)
    hipLaunchKernelGGL(kprepW, dim3((392 * 2048 + 255) / 256), dim3(256), 0, stream,
                       W_all, W_d, U_all, WTP, 2048);
    hipLaunchKernelGGL(kprepU, dim3((384 * 1536 + 255) / 256), dim3(256), 0, stream, U_all, UT);
    for (int t0 = 0; t0 < NS; t0 += CH){
      hipLaunchKernelGGL(kqgemmc, dim3(24, 2 * CH), dim3(256), 0, stream,
                         inputs, UT, Qp, t0, CH);
      hipLaunchKernelGGL(HIP_KERNEL_NAME(krow<2048, 1>), dim3(64), dim3(512), 0, stream,
                         WTP, inputs, tstamps, XND, Qp, CH, t0, t0 + CH,
                         CTX, HS, HSV, CCV, SCV);
    }
  } else {
    // workspace too small even for CH=6: single-launch fallback (U columns in-panel)
    hipLaunchKernelGGL(kprepW, dim3((392 * 4096 + 255) / 256), dim3(256), 0, stream,
                       W_all, W_d, U_all, WTP, 4096);
    hipLaunchKernelGGL(HIP_KERNEL_NAME(krow<4096, 0>), dim3(64), dim3(512), 0, stream,
                       WTP, inputs, tstamps, XND, WTP /*unused*/, 1, 0, NS,
                       CTX, HS, HSV, CCV, SCV);
  }

  hipLaunchKernelGGL(kattn1, dim3(128), dim3(256), 0, stream,
                     HS, Win, CTX, delta_t, ab, QUERY, AW, BT);
  hipLaunchKernelGGL(kmix, dim3(12, 128), dim3(256), 0, stream, CTX, AW, BT, ae, NOMD, DEND);
  hipLaunchKernelGGL(kfinal, dim3(128), dim3(256), 0, stream,
                     NOMD, DEND, QUERY, Wout, W1, b1, W2, b2, out);
}

// Round 7
// 16975.993 us; speedup vs baseline: 4.3359x; 1.7175x over previous
//
#include <hip/hip_runtime.h>
#include <cmath>

constexpr int NB = 128;     // batch
constexpr int NS = 384;     // seq len
constexpr int NH = 384;     // hidden = input dim

typedef __attribute__((ext_vector_type(2))) float f32x2;

__device__ __forceinline__ double clampd(double x, double lo, double hi){ return fmin(fmax(x,lo),hi); }
__device__ __forceinline__ double artanh_(double x){ return atanh(clampd(x, -1.0 + 1e-7, 1.0 - 1e-7)); }
__device__ __forceinline__ double normclip(double s){ return sqrt(fmax(s, 1e-15)); }
__device__ __forceinline__ float clampf_(float x, float lo, float hi){ return fminf(fmaxf(x,lo),hi); }
__device__ __forceinline__ float artanhf_(float x){ return atanhf(clampf_(x, -1.f + 1e-7f, 1.f - 1e-7f)); }
__device__ __forceinline__ double wredsumd(double v){
  #pragma unroll
  for (int off = 32; off; off >>= 1) v += __shfl_xor(v, off, 64);
  return v;
}
// norm from a double sum, fp32 result
__device__ __forceinline__ float ncf(double s){ return sqrtf(fmaxf((float)s, 1e-15f)); }

// ---------------- zero ----------------
__global__ void kzerod(double* p, int n){
  int i = blockIdx.x * 256 + threadIdx.x;
  if (i < n) p[i] = 0.0;
}

// ---------------- weight pack: WTP[c][j] over NW cols ----------------
// j<1536: gate W (4 gates x 384); [1536,1920): W_d; [2048,3584) (NW=4096 only): U gates; else 0.
// 392 rows (8 pad rows for prefetch over-read).
__global__ void kprepW(const float* __restrict__ W_all, const float* __restrict__ W_d,
                       const float* __restrict__ U_all, float* __restrict__ WTP, int NW)
{
  int i = blockIdx.x * 256 + threadIdx.x;
  int total = 392 * NW;
  if (i >= total) return;
  int c = i / NW, j = i % NW;
  float v = 0.f;
  if (c < 384){
    if (j < 1536){ int g = j / 384, r = j % 384; v = W_all[r * 1536 + g * 384 + c]; }
    else if (j < 1920){ int r = j - 1536; v = W_d[r * 384 + c]; }
    else if (NW == 4096 && j >= 2048 && j < 3584){
      int jj = j - 2048; int g = jj / 384, r = jj % 384; v = U_all[(g * 384 + r) * 384 + c];
    }
  }
  WTP[i] = v;
}

// UT[c][jj] = U_g[r][c], stride 1536 (for the Qp precompute GEMM)
__global__ void kprepU(const float* __restrict__ U_all, float* __restrict__ UT)
{
  int i = blockIdx.x * 256 + threadIdx.x;
  if (i >= 384 * 1536) return;
  int c = i / 1536, jj = i % 1536;
  int g = jj / 384, r = jj % 384;
  UT[i] = U_all[(g * 384 + r) * 384 + c];
}

// ---------------- per-(b,t) scalar precompute (double math, fp32 storage) ----------------
// XNF[idx] = {xn, artanh(xn), artanh(xnt)/xnt, ts}
__global__ void kxn(const float* __restrict__ xin, const float* __restrict__ tst,
                    float* __restrict__ XNF)
{
  int w = (blockIdx.x * 256 + threadIdx.x) >> 6;
  int ln = threadIdx.x & 63;
  int nw = (gridDim.x * 256) >> 6;
  for (int idx = w; idx < NB * NS; idx += nw){
    double s = 0;
    #pragma unroll
    for (int i = 0; i < 6; ++i){
      float v = xin[(size_t)idx * NH + ln + 64 * i];
      s += (double)v * v;
    }
    s = wredsumd(s);
    if (ln == 0){
      double xn = normclip(s);
      double ts = (double)tst[idx];
      double xnt = sqrt(fmax(384.0 * ts * ts, 1e-15));
      float4 o;
      o.x = (float)xn;
      o.y = (float)artanh_(xn);
      o.z = (float)(artanh_(xnt) / xnt);
      o.w = (float)ts;
      *(float4*)&XNF[(size_t)idx * 4] = o;
    }
  }
}

// ---------------- chunked Q GEMM: Q[rloc][jj] = sum_c X[b(rloc)][t0+tt(rloc)][c] * UT[c][jj] ----
__global__ __launch_bounds__(256) void kqgemmc(const float* __restrict__ X,
    const float* __restrict__ Bw, float* __restrict__ Q, int t0, int CH)
{
  int j0 = blockIdx.x * 64, i0 = blockIdx.y * 64;
  __shared__ __align__(16) float As[32][68];
  __shared__ __align__(16) float Bs[32][64];
  int tid = threadIdx.x;
  int tn = tid & 15, tm = tid >> 4;
  int slm = tid >> 2;
  int slc = (tid & 3) * 8;
  int blk = tid >> 3;
  int bln = (tid & 7) * 8;
  double accd[4][4] = {{0.0}};
  int rloc = i0 + slm;
  int bb = rloc / CH, tt = rloc - bb * CH;
  const float* arow = X + ((size_t)bb * NS + t0 + tt) * NH;
  for (int c0 = 0; c0 < NH; c0 += 32){
    float4 a4 = *(const float4*)(arow + c0 + slc);
    float4 a4b = *(const float4*)(arow + c0 + slc + 4);
    As[slc+0][slm] = a4.x;  As[slc+1][slm] = a4.y;
    As[slc+2][slm] = a4.z;  As[slc+3][slm] = a4.w;
    As[slc+4][slm] = a4b.x; As[slc+5][slm] = a4b.y;
    As[slc+6][slm] = a4b.z; As[slc+7][slm] = a4b.w;
    const float* bp = Bw + (size_t)(c0 + blk) * 1536 + j0 + bln;
    float4 b4a = *(const float4*)bp;
    float4 b4b = *(const float4*)(bp + 4);
    *(float4*)&Bs[blk][bln] = b4a;
    *(float4*)&Bs[blk][bln+4] = b4b;
    __syncthreads();
    float acc[4][4] = {{0.f}};
    #pragma unroll 8
    for (int c = 0; c < 32; ++c){
      float4 av = *(const float4*)&As[c][tm*4];
      float4 bv = *(const float4*)&Bs[c][tn*4];
      float a[4] = {av.x, av.y, av.z, av.w};
      float bb2[4] = {bv.x, bv.y, bv.z, bv.w};
      #pragma unroll
      for (int mm = 0; mm < 4; ++mm)
        #pragma unroll
        for (int jj = 0; jj < 4; ++jj)
          acc[mm][jj] += a[mm] * bb2[jj];
    }
    __syncthreads();
    #pragma unroll
    for (int mm = 0; mm < 4; ++mm)
      #pragma unroll
      for (int jj = 0; jj < 4; ++jj) accd[mm][jj] += (double)acc[mm][jj];
  }
  #pragma unroll
  for (int mm = 0; mm < 4; ++mm){
    float4 o; o.x = (float)accd[mm][0]; o.y = (float)accd[mm][1];
    o.z = (float)accd[mm][2]; o.w = (float)accd[mm][3];
    *(float4*)(Q + (size_t)(i0 + tm*4 + mm) * 1536 + j0 + tn*4) = o;
  }
}

// ---------------- fp32 gate chain (sums in double, scalars in fp32) ----------------
__device__ __forceinline__ void gatef(const float* __restrict__ pg, const float* __restrict__ qg,
    float hn, float art_hn, float xn, float art_xn, float* __restrict__ out)
{
  double sp = 0, sq = 0;
  #pragma unroll
  for (int i = 0; i < 6; ++i){ sp += (double)pg[i] * pg[i]; sq += (double)qg[i] * qg[i]; }
  float pn = ncf(wredsumd(sp));
  float qn = ncf(wredsumd(sq));
  float saf = tanhf(pn / hn * art_hn) / pn;
  float sbf = tanhf(qn / xn * art_xn) / qn;
  float a6[6], b6[6]; double sx2 = 0, sy2 = 0, sxy = 0;
  #pragma unroll
  for (int i = 0; i < 6; ++i){
    a6[i] = saf * pg[i]; b6[i] = sbf * qg[i];
    sx2 += (double)a6[i] * a6[i]; sy2 += (double)b6[i] * b6[i]; sxy += (double)a6[i] * b6[i];
  }
  float x2 = (float)wredsumd(sx2);
  float y2 = (float)wredsumd(sy2);
  float xy = (float)wredsumd(sxy);
  float dd = fmaxf(1.f + 2.f * xy + x2 * y2, 1e-15f);
  float fX = (1.f + 2.f * xy + y2) / dd;
  float fY = (1.f - x2) / dd;
  float m6[6]; double smm = 0;
  #pragma unroll
  for (int i = 0; i < 6; ++i){ m6[i] = fX * a6[i] + fY * b6[i]; smm += (double)m6[i] * m6[i]; }
  float nm = ncf(wredsumd(smm));
  float slf = artanhf_(nm) / nm;
  #pragma unroll
  for (int i = 0; i < 6; ++i) out[i] = 1.f / (1.f + expf(-slf * m6[i]));
}

// two interleaved gate chains (independent -> transcendentals pipeline)
__device__ __forceinline__ void gate2f(
    const float* __restrict__ pgA, const float* __restrict__ qgA,
    const float* __restrict__ pgB, const float* __restrict__ qgB,
    float hn, float art_hn, float xn, float art_xn,
    float* __restrict__ outA, float* __restrict__ outB)
{
  double spA = 0, sqA = 0, spB = 0, sqB = 0;
  #pragma unroll
  for (int i = 0; i < 6; ++i){
    spA += (double)pgA[i] * pgA[i]; sqA += (double)qgA[i] * qgA[i];
    spB += (double)pgB[i] * pgB[i]; sqB += (double)qgB[i] * qgB[i];
  }
  float pnA = ncf(wredsumd(spA)), qnA = ncf(wredsumd(sqA));
  float pnB = ncf(wredsumd(spB)), qnB = ncf(wredsumd(sqB));
  float safA = tanhf(pnA / hn * art_hn) / pnA;
  float sbfA = tanhf(qnA / xn * art_xn) / qnA;
  float safB = tanhf(pnB / hn * art_hn) / pnB;
  float sbfB = tanhf(qnB / xn * art_xn) / qnB;
  float aA[6], bA[6], aB[6], bB[6];
  double sxA = 0, syA = 0, sxyA = 0, sxB = 0, syB = 0, sxyB = 0;
  #pragma unroll
  for (int i = 0; i < 6; ++i){
    aA[i] = safA * pgA[i]; bA[i] = sbfA * qgA[i];
    aB[i] = safB * pgB[i]; bB[i] = sbfB * qgB[i];
    sxA += (double)aA[i] * aA[i]; syA += (double)bA[i] * bA[i]; sxyA += (double)aA[i] * bA[i];
    sxB += (double)aB[i] * aB[i]; syB += (double)bB[i] * bB[i]; sxyB += (double)aB[i] * bB[i];
  }
  float x2A = (float)wredsumd(sxA), y2A = (float)wredsumd(syA), xyA = (float)wredsumd(sxyA);
  float x2B = (float)wredsumd(sxB), y2B = (float)wredsumd(syB), xyB = (float)wredsumd(sxyB);
  float ddA = fmaxf(1.f + 2.f * xyA + x2A * y2A, 1e-15f);
  float ddB = fmaxf(1.f + 2.f * xyB + x2B * y2B, 1e-15f);
  float fXA = (1.f + 2.f * xyA + y2A) / ddA, fYA = (1.f - x2A) / ddA;
  float fXB = (1.f + 2.f * xyB + y2B) / ddB, fYB = (1.f - x2B) / ddB;
  float mA[6], mB[6]; double smA = 0, smB = 0;
  #pragma unroll
  for (int i = 0; i < 6; ++i){
    mA[i] = fXA * aA[i] + fYA * bA[i]; smA += (double)mA[i] * mA[i];
    mB[i] = fXB * aB[i] + fYB * bB[i]; smB += (double)mB[i] * mB[i];
  }
  float nmA = ncf(wredsumd(smA)), nmB = ncf(wredsumd(smB));
  float slfA = artanhf_(nmA) / nmA;
  float slfB = artanhf_(nmB) / nmB;
  #pragma unroll
  for (int i = 0; i < 6; ++i){
    outA[i] = 1.f / (1.f + expf(-slfA * mA[i]));
    outB[i] = 1.f / (1.f + expf(-slfB * mB[i]));
  }
}

// ================= row-local fused recurrence (chunked, cols-once GEMM, fp32 NL) =============
// 64 blocks x 512 threads. Block owns batch rows 2*bid, 2*bid+1.
// GEMM: all 512 threads cover the NW columns once (NF_C float4 each), computing BOTH rows per
//       weight load (panel traffic halved). Z fp ordering identical to prior rounds.
// NL: 8 waves = 2 rows x {c-path+combine, gates f+i, gate o(+ctx), gate ct}. Scalar chain fp32.
template<int NW, int QPRE>
__global__ __launch_bounds__(512, 1) void krow(
    const float* __restrict__ WTP, const float* __restrict__ xin,
    const float* __restrict__ XNF, const float* __restrict__ Qp,
    int CH, int t0, int t1,
    float* __restrict__ ctx, float* __restrict__ HsOut,
    float* __restrict__ HSV, float* __restrict__ CCV, double* __restrict__ SCV)
{
  constexpr int NF_C = NW / 2048;       // float4 per thread: 1 (QPRE) or 2 (fallback)
  constexpr int D = 6;                  // prefetch depth (rows 384..389 pad-covered)
  const int tid = threadIdx.x;
  const int wv = tid >> 6, ln = tid & 63;
  const int row = wv >> 2, wr = wv & 3; // NL role
  const int bb0 = blockIdx.x << 1;
  const int b = bb0 | row;              // this wave's batch row

  __shared__ __align__(16) float Zrow[2][NW];
  __shared__ f32x2 ALd[2][384][5];      // slots: 0=h, 1=cc, 2=x, 3=zero
  __shared__ float g384[2][4][384];
  __shared__ float sc[2][4];            // {hn, cc2, artanh(hn), pad}

  // ---- init / restore state ----
  for (int i = tid; i < 2 * 384 * 5; i += 512) ((f32x2*)ALd)[i] = f32x2{0.f, 0.f};
  __syncthreads();
  if (t0 > 0){
    for (int i = tid; i < 768; i += 512){
      int rg = i / 384, k = i - rg * 384;
      float hv_ = HSV[(size_t)(bb0 + rg) * 384 + k];
      float cv_ = CCV[(size_t)(bb0 + rg) * 384 + k];
      ALd[rg][k][0] = f32x2{hv_, hv_};
      ALd[rg][k][1] = f32x2{cv_, cv_};
    }
  }
  if (!QPRE){
    for (int i = tid; i < 768; i += 512){
      int rg = i / 384, k = i - rg * 384;
      float xv = xin[((size_t)(bb0 + rg) * NS + t0) * NH + k];
      ALd[rg][k][2] = f32x2{xv, xv};
    }
  }
  float cc6[6], hnf = 0.f, cc2f = 0.f;
  if (wr == 0){
    if (t0 == 0){
      #pragma unroll
      for (int i = 0; i < 6; ++i) cc6[i] = 0.f;
      hnf = sqrtf(1e-15f); cc2f = 0.f;
    } else {
      #pragma unroll
      for (int i = 0; i < 6; ++i) cc6[i] = CCV[(size_t)b * 384 + ln + 64 * i];
      hnf = (float)SCV[b * 2]; cc2f = (float)SCV[b * 2 + 1];
    }
    if (ln == 0){ sc[row][0] = hnf; sc[row][1] = cc2f; sc[row][2] = artanhf_(hnf); }
  }
  __syncthreads();

  // column assignment (cols-once)
  const int col0 = tid * (NF_C * 4);
  int sel;
  if (col0 < 1536) sel = 0;
  else if (col0 < 1920) sel = 1;
  else if (QPRE) sel = 3;
  else if (col0 < 2048) sel = 3;
  else if (col0 < 3584) sel = 2;
  else sel = 3;

  float qreg[12];
  float xr[6];

  for (int t = t0; t < t1; ++t){
    // ---- per-wave row scalars + prefetches (latency hidden under GEMM) ----
    float4 xf = *(const float4*)&XNF[((size_t)b * NS + t) * 4]; // {xn, art_xn, axnt, ts}
    if (QPRE){
      const float* qp = Qp + ((size_t)b * CH + (t - t0)) * 1536;
      if (wr == 1){
        #pragma unroll
        for (int i = 0; i < 12; ++i) qreg[i] = qp[ln + 64 * i];
      } else if (wr == 2){
        #pragma unroll
        for (int i = 0; i < 6; ++i) qreg[i] = qp[768 + ln + 64 * i];
      } else if (wr == 3){
        #pragma unroll
        for (int i = 0; i < 6; ++i) qreg[i] = qp[1152 + ln + 64 * i];
      }
    } else {
      if (wr == 3 && t + 1 < t1){
        #pragma unroll
        for (int i = 0; i < 6; ++i) xr[i] = xin[((size_t)b * NS + t + 1) * NH + ln + 64 * i];
      }
    }

    // ---- GEMM: cols-once, both rows; fp32 packed FMA + fp64 flush each 96 ----
    {
      const float* pt[D];
      #pragma unroll
      for (int d = 0; d < D; ++d) pt[d] = WTP + (size_t)d * NW + col0;
      float4 wb[D][NF_C];
      #pragma unroll
      for (int d = 0; d < D; ++d){
        #pragma unroll
        for (int k = 0; k < NF_C; ++k) wb[d][k] = *(const float4*)(pt[d] + 4 * k);
        pt[d] += (size_t)D * NW;
      }
      double ad0[NF_C * 4], ad1[NF_C * 4];
      #pragma unroll
      for (int k = 0; k < NF_C * 4; ++k){ ad0[k] = 0.0; ad1[k] = 0.0; }
      for (int c0 = 0; c0 < 384; c0 += 96){
        f32x2 a0[NF_C * 2], a1[NF_C * 2];
        #pragma unroll
        for (int k = 0; k < NF_C * 2; ++k){ a0[k] = f32x2{0.f, 0.f}; a1[k] = f32x2{0.f, 0.f}; }
        for (int cc = 0; cc < 96; cc += D){
          #pragma unroll
          for (int d = 0; d < D; ++d){
            const int c = c0 + cc + d;
            f32x2 v0 = ALd[0][c][sel];
            f32x2 v1 = ALd[1][c][sel];
            #pragma unroll
            for (int k = 0; k < NF_C; ++k){
              f32x2 wlo = f32x2{wb[d][k].x, wb[d][k].y};
              f32x2 whi = f32x2{wb[d][k].z, wb[d][k].w};
              a0[2 * k + 0] += wlo * v0;
              a0[2 * k + 1] += whi * v0;
              a1[2 * k + 0] += wlo * v1;
              a1[2 * k + 1] += whi * v1;
            }
            #pragma unroll
            for (int k = 0; k < NF_C; ++k) wb[d][k] = *(const float4*)(pt[d] + 4 * k);
            pt[d] += (size_t)D * NW;
          }
        }
        #pragma unroll
        for (int k = 0; k < NF_C * 2; ++k){
          ad0[2 * k]     += (double)a0[k].x;
          ad0[2 * k + 1] += (double)a0[k].y;
          ad1[2 * k]     += (double)a1[k].x;
          ad1[2 * k + 1] += (double)a1[k].y;
        }
      }
      #pragma unroll
      for (int k = 0; k < NF_C; ++k){
        float4 o0, o1;
        o0.x = (float)ad0[4 * k + 0]; o0.y = (float)ad0[4 * k + 1];
        o0.z = (float)ad0[4 * k + 2]; o0.w = (float)ad0[4 * k + 3];
        o1.x = (float)ad1[4 * k + 0]; o1.y = (float)ad1[4 * k + 1];
        o1.z = (float)ad1[4 * k + 2]; o1.w = (float)ad1[4 * k + 3];
        *(float4*)&Zrow[0][col0 + 4 * k] = o0;
        *(float4*)&Zrow[1][col0 + 4 * k] = o1;
      }
    }
    __syncthreads();   // B1: Zrow ready

    // ---- NL (fp32 scalar chain, double reduces) ----
    float hn_s = sc[row][0];
    float art_hn = sc[row][2];
    float cadj[6];
    if (wr == 0){
      float tsf = xf.w, axnt = xf.z;
      float cnf = sqrtf(fmaxf(cc2f, 1e-15f));
      float mv6[6]; double s_mv = 0;
      #pragma unroll
      for (int i = 0; i < 6; ++i){
        mv6[i] = Zrow[row][1536 + ln + 64 * i];
        s_mv += (double)mv6[i] * mv6[i];
      }
      float mvn = ncf(wredsumd(s_mv));
      float s1 = tanhf(mvn / cnf * artanhf_(cnf));
      float c1f = s1 / mvn;
      float m1[6]; double sm1 = 0;
      #pragma unroll
      for (int i = 0; i < 6; ++i){ m1[i] = c1f * mv6[i]; sm1 += (double)m1[i] * m1[i]; }
      float n1 = ncf(wredsumd(sm1));
      float l1f = artanhf_(n1) / n1;
      float v6[6]; double sv = 0;
      #pragma unroll
      for (int i = 0; i < 6; ++i){ v6[i] = tanhf(l1f * m1[i]); sv += (double)v6[i] * v6[i]; }
      float nv = ncf(wredsumd(sv));
      float e1f = tanhf(nv) / nv;
      float cs1[6]; double scs = 0, sccd = 0;
      #pragma unroll
      for (int i = 0; i < 6; ++i){ cs1[i] = e1f * v6[i]; scs += (double)cs1[i] * cs1[i]; sccd -= (double)cs1[i] * cc6[i]; }
      double swx = 0;
      #pragma unroll
      for (int i = 0; i < 6; ++i){ float w = cs1[i] * tsf; swx += (double)w * w; }
      float wxn1 = ncf(wredsumd(swx));
      float s2f = tanhf(wxn1 * axnt) / wxn1 * tsf;
      float cs2[6];
      #pragma unroll
      for (int i = 0; i < 6; ++i) cs2[i] = s2f * cs1[i];
      float x2a = (float)wredsumd(scs);
      float xya = (float)wredsumd(sccd);
      float y2a = cc2f;
      float dA = fmaxf(1.f + 2.f * xya + x2a * y2a, 1e-15f);
      float fXA = (1.f + 2.f * xya + y2a) / dA;
      float fYA = (1.f - x2a) / dA;
      float A6[6]; double sA = 0, sAc = 0, sc2_ = 0;
      #pragma unroll
      for (int i = 0; i < 6; ++i){
        A6[i] = fXA * (-cs1[i]) + fYA * cc6[i];
        sA += (double)A6[i] * A6[i]; sAc += (double)A6[i] * cs2[i]; sc2_ += (double)cs2[i] * cs2[i];
      }
      float x2b = (float)wredsumd(sA);
      float xyb = (float)wredsumd(sAc);
      float y2b = (float)wredsumd(sc2_);
      float dB = fmaxf(1.f + 2.f * xyb + x2b * y2b, 1e-15f);
      float fXB = (1.f + 2.f * xyb + y2b) / dB;
      float fYB = (1.f - x2b) / dB;
      #pragma unroll
      for (int i = 0; i < 6; ++i) cadj[i] = fXB * A6[i] + fYB * cs2[i];
    } else if (wr == 1){
      float pgA[6], qgA[6], pgB[6], qgB[6], outA[6], outB[6];
      #pragma unroll
      for (int i = 0; i < 6; ++i){
        int r = ln + 64 * i;
        pgA[i] = Zrow[row][r];
        qgA[i] = QPRE ? qreg[i] : Zrow[row][2048 + r];
        pgB[i] = Zrow[row][384 + r];
        qgB[i] = QPRE ? qreg[6 + i] : Zrow[row][2048 + 384 + r];
      }
      gate2f(pgA, qgA, pgB, qgB, hn_s, art_hn, xf.x, xf.y, outA, outB);
      #pragma unroll
      for (int i = 0; i < 6; ++i){
        g384[row][0][ln + 64 * i] = outA[i];
        g384[row][1][ln + 64 * i] = outB[i];
      }
    } else if (wr == 2){
      float pg[6], qg[6], og[6];
      #pragma unroll
      for (int i = 0; i < 6; ++i){
        int r = ln + 64 * i;
        pg[i] = Zrow[row][768 + r];
        qg[i] = QPRE ? qreg[i] : Zrow[row][2048 + 768 + r];
      }
      gatef(pg, qg, hn_s, art_hn, xf.x, xf.y, og);
      #pragma unroll
      for (int i = 0; i < 6; ++i){
        int r = ln + 64 * i;
        g384[row][2][r] = og[i];
        ctx[((size_t)b * NS + t) * NH + r] = og[i];   // o-gate is the context
      }
    } else {
      float pg[6], qg[6], og[6];
      #pragma unroll
      for (int i = 0; i < 6; ++i){
        int r = ln + 64 * i;
        pg[i] = Zrow[row][1152 + r];
        qg[i] = QPRE ? qreg[i] : Zrow[row][2048 + 1152 + r];
      }
      gatef(pg, qg, hn_s, art_hn, xf.x, xf.y, og);
      #pragma unroll
      for (int i = 0; i < 6; ++i) g384[row][3][ln + 64 * i] = og[i];
    }
    __syncthreads();   // B2: gates ready

    if (wr == 0){
      float g0[6], g1[6], g2[6], g3[6];
      #pragma unroll
      for (int i = 0; i < 6; ++i){
        int r = ln + 64 * i;
        g0[i] = g384[row][0][r]; g1[i] = g384[row][1][r];
        g2[i] = g384[row][2][r]; g3[i] = g384[row][3][r];
      }
      double sct = 0, sict = 0; float wP[6];
      #pragma unroll
      for (int i = 0; i < 6; ++i){ float ct = g3[i]; sct += (double)ct * ct; wP[i] = g1[i] * ct; sict += (double)wP[i] * wP[i]; }
      float ctn = ncf(wredsumd(sct));
      float wPn = ncf(wredsumd(sict));
      float sPf = tanhf(wPn / ctn * artanhf_(ctn)) / wPn;
      float P6[6]; double sPP = 0;
      #pragma unroll
      for (int i = 0; i < 6; ++i){ P6[i] = sPf * wP[i]; sPP += (double)P6[i] * P6[i]; }
      double sca = 0, sfca = 0; float wQ[6];
      #pragma unroll
      for (int i = 0; i < 6; ++i){ sca += (double)cadj[i] * cadj[i]; wQ[i] = g0[i] * cadj[i]; sfca += (double)wQ[i] * wQ[i]; }
      float can = ncf(wredsumd(sca));
      float wQn = ncf(wredsumd(sfca));
      float sQf = tanhf(wQn / can * artanhf_(can)) / wQn;
      float Q6[6]; double sQQ = 0, sPQ = 0;
      #pragma unroll
      for (int i = 0; i < 6; ++i){ Q6[i] = sQf * wQ[i]; sQQ += (double)Q6[i] * Q6[i]; sPQ += (double)P6[i] * Q6[i]; }
      float x2c = (float)wredsumd(sPP);
      float y2c = (float)wredsumd(sQQ);
      float xyc = (float)wredsumd(sPQ);
      float dC = fmaxf(1.f + 2.f * xyc + x2c * y2c, 1e-15f);
      float fXC = (1.f + 2.f * xyc + y2c) / dC;
      float fYC = (1.f - x2c) / dC;
      float ccn6[6], w6[6]; double sw_ = 0;
      #pragma unroll
      for (int i = 0; i < 6; ++i){ ccn6[i] = fXC * P6[i] + fYC * Q6[i]; w6[i] = tanhf(ccn6[i]); sw_ += (double)w6[i] * w6[i]; }
      float nw = ncf(wredsumd(sw_));
      float eef = tanhf(nw) / nw;
      float e6[6], wH[6]; double se = 0, soe = 0;
      #pragma unroll
      for (int i = 0; i < 6; ++i){ e6[i] = eef * w6[i]; se += (double)e6[i] * e6[i]; wH[i] = g2[i] * e6[i]; soe += (double)wH[i] * wH[i]; }
      float en = ncf(wredsumd(se));
      float wHn = ncf(wredsumd(soe));
      float sHf = tanhf(wHn / en * artanhf_(en)) / wHn;
      float hv[6]; double sh2 = 0, scc2 = 0;
      #pragma unroll
      for (int i = 0; i < 6; ++i){
        hv[i] = sHf * wH[i];
        sh2 += (double)hv[i] * hv[i];
        scc2 += (double)ccn6[i] * ccn6[i];
      }
      float hn_next = ncf(wredsumd(sh2));
      float cc2_next = (float)wredsumd(scc2);
      #pragma unroll
      for (int i = 0; i < 6; ++i){
        int r = ln + 64 * i;
        cc6[i] = ccn6[i];
        ALd[row][r][0] = f32x2{hv[i], hv[i]};
        ALd[row][r][1] = f32x2{ccn6[i], ccn6[i]};
      }
      hnf = hn_next; cc2f = cc2_next;
      if (ln == 0){ sc[row][0] = hn_next; sc[row][1] = cc2_next; sc[row][2] = artanhf_(hn_next); }
      if (t == t1 - 1){
        #pragma unroll
        for (int i = 0; i < 6; ++i){
          int r = ln + 64 * i;
          HSV[(size_t)b * 384 + r] = hv[i];
          CCV[(size_t)b * 384 + r] = ccn6[i];
        }
        if (ln == 0){ SCV[b * 2] = (double)hn_next; SCV[b * 2 + 1] = (double)cc2_next; }
      }
      if (t == NS - 1){
        #pragma unroll
        for (int i = 0; i < 6; ++i) HsOut[b * NH + ln + 64 * i] = hv[i];
      }
    }
    if (!QPRE && wr == 3 && t + 1 < t1){
      #pragma unroll
      for (int i = 0; i < 6; ++i) ALd[row][ln + 64 * i][2] = f32x2{xr[i], xr[i]};
    }
    __syncthreads();   // B3: state ready for next t
  }
}

// ---------------- block reduce helpers ----------------
__device__ __forceinline__ double blocksumd(double v, double* red){
  v = wredsumd(v);
  __syncthreads();
  if ((threadIdx.x & 63) == 0) red[threadIdx.x >> 6] = v;
  __syncthreads();
  return red[0] + red[1] + red[2] + red[3];
}
__device__ __forceinline__ double blockmaxd(double v, double* red){
  #pragma unroll
  for (int off = 32; off; off >>= 1) v = fmax(v, __shfl_xor(v, off, 64));
  __syncthreads();
  if ((threadIdx.x & 63) == 0) red[threadIdx.x >> 6] = v;
  __syncthreads();
  return fmax(fmax(red[0], red[1]), fmax(red[2], red[3]));
}

// ---------------- query / scores / softmax / aw / bt ----------------
__global__ __launch_bounds__(256) void kattn1(const float* __restrict__ Hs,
    const float* __restrict__ Win, const float* __restrict__ ctx,
    const float* __restrict__ dt, const float* __restrict__ ab,
    double* __restrict__ query, double* __restrict__ aw, double* __restrict__ bt)
{
  int b = blockIdx.x; int tid = threadIdx.x;
  __shared__ double hL[NH], qL[NH], scs[NS];
  __shared__ double red[4];
  for (int r = tid; r < NH; r += 256) hL[r] = (double)Hs[b * NH + r];
  __syncthreads();
  for (int r = tid; r < NH; r += 256){
    double s = 0;
    const float* wr = Win + (size_t)r * NH;
    for (int c = 0; c < NH; ++c) s += hL[c] * (double)wr[c];
    qL[r] = s; query[b * NH + r] = s;
  }
  __syncthreads();
  int wv = tid >> 6, ln = tid & 63;
  for (int s_ = wv; s_ < NS; s_ += 4){
    const float* crow = ctx + ((size_t)b * NS + s_) * NH;
    double par = 0;
    #pragma unroll
    for (int i = 0; i < 6; ++i){ int d = ln + 64 * i; par += qL[d] * (double)crow[d]; }
    par = wredsumd(par);
    if (ln == 0) scs[s_] = par;
  }
  __syncthreads();
  double v0 = scs[tid];
  double v1 = (tid + 256 < NS) ? scs[tid + 256] : -1e300;
  double mx = blockmaxd(fmax(v0, v1), red);
  double e0 = exp(v0 - mx);
  double e1 = (tid + 256 < NS) ? exp(v1 - mx) : 0.0;
  double tot = blocksumd(e0 + e1, red);
  double a0 = e0 / tot, a1 = e1 / tot;
  double n = normclip(blocksumd(a0 * a0 + a1 * a1, red));
  double s1 = tanh(n) / n;
  double w0 = s1 * a0, w1 = s1 * a1;
  double pn = normclip(blocksumd(w0 * w0 + w1 * w1, red));
  if (pn > 0.999){ double f = 0.999 / pn; w0 *= f; w1 *= f; }
  aw[b * NS + tid] = w0;
  if (tid + 256 < NS) aw[b * NS + tid + 256] = w1;
  double abv = (double)ab[b];
  double b0 = exp(-abv * (double)dt[b * NS + tid]);
  double b1v = (tid + 256 < NS) ? exp(-abv * (double)dt[b * NS + tid + 256]) : 0.0;
  double nb = normclip(blocksumd(b0 * b0 + b1v * b1v, red));
  double sb = tanh(nb) / nb;
  double c0 = sb * b0, c1 = sb * b1v;
  double pnb = normclip(blocksumd(c0 * c0 + c1 * c1, red));
  if (pnb > 0.999){ double f = 0.999 / pnb; c0 *= f; c1 *= f; }
  bt[b * NS + tid] = c0;
  if (tid + 256 < NS) bt[b * NS + tid + 256] = c1;
}

// ---------------- hyperbolic attention mixing ----------------
__global__ __launch_bounds__(256) void kmix(const float* __restrict__ ctx,
    const double* __restrict__ aw, const double* __restrict__ bt,
    const float* __restrict__ ae, double* __restrict__ nom, double* __restrict__ den)
{
  int b = blockIdx.y; int h0 = blockIdx.x * 32;
  __shared__ float T[32][385];
  int tid = threadIdx.x;
  for (int idx = tid; idx < NS * 32; idx += 256){
    int s = idx >> 5, hh = idx & 31;
    T[hh][s] = ctx[((size_t)b * NS + s) * NH + h0 + hh];
  }
  __syncthreads();
  int wv = tid >> 6, ln = tid & 63;
  double aev = (double)ae[b];
  double aw6[6], bt6[6]; double sbt = 0;
  #pragma unroll
  for (int i = 0; i < 6; ++i){
    aw6[i] = aw[b * NS + ln + 64 * i];
    bt6[i] = bt[b * NS + ln + 64 * i];
    sbt += bt6[i] * bt6[i];
  }
  double xnb = normclip(wredsumd(sbt));
  double art_xnb = artanh_(xnb);
  double denacc = 0.0;
  for (int k = 0; k < 8; ++k){
    int hh = wv * 8 + k;
    double v[6]; double sx = 0;
    #pragma unroll
    for (int i = 0; i < 6; ++i){ v[i] = (double)T[hh][ln + 64 * i]; sx += v[i] * v[i]; }
    double xnv = normclip(wredsumd(sx));
    double wx[6]; double swx = 0;
    #pragma unroll
    for (int i = 0; i < 6; ++i){ wx[i] = aw6[i] * v[i]; swx += wx[i] * wx[i]; }
    double wxn = normclip(wredsumd(swx));
    double s1 = tanh(wxn / xnv * artanh_(xnv)) / wxn;
    double mix[6]; double sm = 0;
    #pragma unroll
    for (int i = 0; i < 6; ++i){ mix[i] = s1 * wx[i]; sm += mix[i] * mix[i]; }
    double n1 = normclip(wredsumd(sm));
    if (n1 > 0.999){ double f = 0.999 / n1;
      #pragma unroll
      for (int i = 0; i < 6; ++i) mix[i] *= f; }
    double sm2 = 0;
    #pragma unroll
    for (int i = 0; i < 6; ++i) sm2 += mix[i] * mix[i];
    double xn2 = normclip(wredsumd(sm2));
    double wx2[6]; double sw2 = 0;
    #pragma unroll
    for (int i = 0; i < 6; ++i){ wx2[i] = aev * mix[i]; sw2 += wx2[i] * wx2[i]; }
    double wxn2 = normclip(wredsumd(sw2));
    double s2 = tanh(wxn2 / xn2 * artanh_(xn2)) / wxn2;
    double tmp[6]; double st = 0;
    #pragma unroll
    for (int i = 0; i < 6; ++i){ tmp[i] = s2 * wx2[i]; st += tmp[i] * tmp[i]; }
    double n2 = normclip(wredsumd(st));
    if (n2 > 0.999){ double f = 0.999 / n2;
      #pragma unroll
      for (int i = 0; i < 6; ++i) tmp[i] *= f; }
    double wx3[6]; double sw3 = 0;
    #pragma unroll
    for (int i = 0; i < 6; ++i){ wx3[i] = tmp[i] * bt6[i]; sw3 += wx3[i] * wx3[i]; }
    double wxn3 = normclip(wredsumd(sw3));
    double s3 = tanh(wxn3 / xnb * art_xnb) / wxn3;
    double t2[6]; double st2 = 0;
    #pragma unroll
    for (int i = 0; i < 6; ++i){ t2[i] = s3 * wx3[i]; st2 += t2[i] * t2[i]; }
    double n3 = normclip(wredsumd(st2));
    if (n3 > 0.999){ double f = 0.999 / n3;
      #pragma unroll
      for (int i = 0; i < 6; ++i) t2[i] *= f; }
    #pragma unroll
    for (int i = 0; i < 6; ++i) t2[i] = fmax(t2[i], 0.0);
    double sxx = 0, syy = 0, sxy = 0;
    #pragma unroll
    for (int i = 0; i < 6; ++i){ sxx += mix[i] * mix[i]; syy += t2[i] * t2[i]; sxy += mix[i] * t2[i]; }
    sxx = wredsumd(sxx); syy = wredsumd(syy); sxy = wredsumd(sxy);
    double dn = fmax(1.0 + 2.0 * sxy + sxx * syy, 1e-15);
    double ca = (1.0 + 2.0 * sxy + syy) / dn, cb = (1.0 - sxx) / dn;
    double m2[6]; double sm3 = 0;
    #pragma unroll
    for (int i = 0; i < 6; ++i){ m2[i] = ca * mix[i] + cb * t2[i]; sm3 += m2[i] * m2[i]; }
    double n4 = normclip(wredsumd(sm3));
    if (n4 > 0.999){ double f = 0.999 / n4;
      #pragma unroll
      for (int i = 0; i < 6; ++i) m2[i] *= f; }
    double snn = 0;
    #pragma unroll
    for (int i = 0; i < 6; ++i) snn += m2[i] * m2[i];
    snn = wredsumd(snn);
    double lam = 2.0 / fmax(1.0 - snn, 1e-15);
    #pragma unroll
    for (int i = 0; i < 6; ++i) atomicAdd(&nom[b * NS + ln + 64 * i], lam * m2[i]);
    if (ln == 0) denacc += lam - 1.0;
  }
  if (ln == 0) atomicAdd(&den[b], denacc);
}

// ---------------- midpoint + logmap0 + output head ----------------
__global__ __launch_bounds__(256) void kfinal(const double* __restrict__ nom,
    const double* __restrict__ den, const double* __restrict__ query,
    const float* __restrict__ Wout, const float* __restrict__ W1,
    const float* __restrict__ b1, const float* __restrict__ W2,
    const float* __restrict__ b2, float* __restrict__ out)
{
  int b = blockIdx.x; int tid = threadIdx.x;
  __shared__ double comb[768];
  __shared__ double att[NH];
  __shared__ double x1[NH];
  __shared__ double red[4];
  double dnb = fmax(den[b], 1e-10);
  double u0 = nom[b * NS + tid] / dnb;
  double u1 = (tid + 256 < NS) ? nom[b * NS + tid + 256] / dnb : 0.0;
  double n = normclip(blocksumd(u0 * u0 + u1 * u1, red));
  double sf = tanh(0.5 * artanh_(n)) / n;
  double f0 = sf * u0, f1 = sf * u1;
  double n2 = normclip(blocksumd(f0 * f0 + f1 * f1, red));
  double sl = artanh_(n2) / n2;
  comb[tid] = sl * f0;
  if (tid + 256 < NS) comb[tid + 256] = sl * f1;
  for (int r = tid; r < NH; r += 256) comb[NH + r] = query[b * NH + r];
  __syncthreads();
  for (int r = tid; r < NH; r += 256){
    double s = 0;
    const float* wr = Wout + (size_t)r * 768;
    for (int c = 0; c < 768; ++c) s += comb[c] * (double)wr[c];
    att[r] = tanh(s);
  }
  __syncthreads();
  for (int r = tid; r < NH; r += 256){
    double s = (double)b1[r];
    const float* wr = W1 + (size_t)r * NH;
    for (int c = 0; c < NH; ++c) s += att[c] * (double)wr[c];
    x1[r] = fmax(s, 0.0);
  }
  __syncthreads();
  double p0 = 0, p1 = 0;
  for (int c = tid; c < NH; c += 256){ p0 += x1[c] * (double)W2[c]; p1 += x1[c] * (double)W2[NH + c]; }
  p0 = blocksumd(p0, red);
  p1 = blocksumd(p1, red);
  if (tid == 0){ out[b * 2 + 0] = (float)(p0 + (double)b2[0]); out[b * 2 + 1] = (float)(p1 + (double)b2[1]); }
}

extern "C" void kernel_launch(void* const* d_in, const int* in_sizes, int n_in,
                              void* d_out, int out_size, void* d_ws, size_t ws_size,
                              hipStream_t stream)
{
  (void)in_sizes; (void)n_in; (void)out_size;
  const float* inputs  = (const float*)d_in[0];
  const float* tstamps = (const float*)d_in[1];
  const float* delta_t = (const float*)d_in[2];
  const float* W_all   = (const float*)d_in[3];
  const float* U_all   = (const float*)d_in[4];
  const float* W_d     = (const float*)d_in[5];
  const float* Win     = (const float*)d_in[6];
  const float* Wout    = (const float*)d_in[7];
  const float* ae      = (const float*)d_in[8];
  const float* ab      = (const float*)d_in[9];
  const float* W1      = (const float*)d_in[10];
  const float* b1      = (const float*)d_in[11];
  const float* W2      = (const float*)d_in[12];
  const float* b2      = (const float*)d_in[13];
  float* out = (float*)d_out;

  // double region
  double* wd = (double*)d_ws;
  size_t od = 0;
  double* NOMD  = wd + od; od += (size_t)NB * NS;
  double* DEND  = wd + od; od += (size_t)NB;
  double* QUERY = wd + od; od += (size_t)NB * NH;
  double* AW    = wd + od; od += (size_t)NB * NS;
  double* BT    = wd + od; od += (size_t)NB * NS;
  double* SCV   = wd + od; od += (size_t)NB * 2;
  // float region
  float* wf = (float*)(wd + od);
  size_t of = 0;
  float* WTP  = wf + of; of += (size_t)392 * 4096;     // shared weight pack (max layout)
  float* UT   = wf + of; of += (size_t)384 * 1536;
  float* CTX  = wf + of; of += (size_t)NB * NS * NH;
  float* HS   = wf + of; of += (size_t)NB * NH;
  float* HSV  = wf + of; of += (size_t)NB * NH;        // chunk-boundary h state
  float* CCV  = wf + of; of += (size_t)NB * NH;        // chunk-boundary cc state
  float* XNF  = wf + of; of += (size_t)NB * NS * 4;    // {xn, art_xn, axnt, ts}
  float* Qp   = wf + of;                               // Qp chunk buffer (sized by CH)

  size_t base_bytes = od * 8 + of * 4;

  // pick the largest time-chunk whose Qp buffer fits the workspace
  int CH = 0;
  const int chs[7] = {384, 192, 96, 48, 24, 12, 6};
  for (int ci = 0; ci < 7; ++ci){
    size_t need = base_bytes + (size_t)NB * chs[ci] * 1536 * 4;
    if (ws_size >= need){ CH = chs[ci]; break; }
  }

  // zero midpoint accumulators + per-(b,t) scalar precompute
  int nzd = NB * NS + NB;
  hipLaunchKernelGGL(kzerod, dim3((nzd + 255) / 256), dim3(256), 0, stream, NOMD, nzd);
  hipLaunchKernelGGL(kxn, dim3(768), dim3(256), 0, stream, inputs, tstamps, XNF);

  if (CH > 0){
    // 1920-col panel (3.2 MB < 4 MB/XCD L2 -> weight stream stays L2-resident)
    hipLaunchKernelGGL(kprepW, dim3((392 * 2048 + 255) / 256), dim3(256), 0, stream,
                       W_all, W_d, U_all, WTP, 2048);
    hipLaunchKernelGGL(kprepU, dim3((384 * 1536 + 255) / 256), dim3(256), 0, stream, U_all, UT);
    for (int t0 = 0; t0 < NS; t0 += CH){
      hipLaunchKernelGGL(kqgemmc, dim3(24, 2 * CH), dim3(256), 0, stream,
                         inputs, UT, Qp, t0, CH);
      hipLaunchKernelGGL(HIP_KERNEL_NAME(krow<2048, 1>), dim3(64), dim3(512), 0, stream,
                         WTP, inputs, XNF, Qp, CH, t0, t0 + CH,
                         CTX, HS, HSV, CCV, SCV);
    }
  } else {
    // workspace too small even for CH=6: single-launch fallback (U columns in-panel)
    hipLaunchKernelGGL(kprepW, dim3((392 * 4096 + 255) / 256), dim3(256), 0, stream,
                       W_all, W_d, U_all, WTP, 4096);
    hipLaunchKernelGGL(HIP_KERNEL_NAME(krow<4096, 0>), dim3(64), dim3(512), 0, stream,
                       WTP, inputs, XNF, WTP /*unused*/, 1, 0, NS,
                       CTX, HS, HSV, CCV, SCV);
  }

  hipLaunchKernelGGL(kattn1, dim3(128), dim3(256), 0, stream,
                     HS, Win, CTX, delta_t, ab, QUERY, AW, BT);
  hipLaunchKernelGGL(kmix, dim3(12, 128), dim3(256), 0, stream, CTX, AW, BT, ae, NOMD, DEND);
  hipLaunchKernelGGL(kfinal, dim3(128), dim3(256), 0, stream,
                     NOMD, DEND, QUERY, Wout, W1, b1, W2, b2, out);
}

// Round 8
// 14828.519 us; speedup vs baseline: 4.9638x; 1.1448x over previous
//
#include <hip/hip_runtime.h>
#include <cmath>

constexpr int NB = 128;     // batch
constexpr int NS = 384;     // seq len
constexpr int NH = 384;     // hidden = input dim

typedef __attribute__((ext_vector_type(2))) float f32x2;
typedef _Float16 h16;
typedef __attribute__((ext_vector_type(4))) _Float16 h16x4;

__device__ __forceinline__ double clampd(double x, double lo, double hi){ return fmin(fmax(x,lo),hi); }
__device__ __forceinline__ double artanh_(double x){ return atanh(clampd(x, -1.0 + 1e-7, 1.0 - 1e-7)); }
__device__ __forceinline__ double normclip(double s){ return sqrt(fmax(s, 1e-15)); }
__device__ __forceinline__ float clampf_(float x, float lo, float hi){ return fminf(fmaxf(x,lo),hi); }
__device__ __forceinline__ float artanhf_(float x){ return atanhf(clampf_(x, -1.f + 1e-7f, 1.f - 1e-7f)); }
__device__ __forceinline__ double wredsumd(double v){
  #pragma unroll
  for (int off = 32; off; off >>= 1) v += __shfl_xor(v, off, 64);
  return v;
}
// norm from a double sum, fp32 result
__device__ __forceinline__ float ncf(double s){ return sqrtf(fmaxf((float)s, 1e-15f)); }

// ---------------- zero ----------------
__global__ void kzerod(double* p, int n){
  int i = blockIdx.x * 256 + threadIdx.x;
  if (i < n) p[i] = 0.0;
}

// ---------------- weight pack (fp16): WTPH[c][j] over NW cols ----------------
// j<1536: gate W (4 gates x 384); [1536,1920): W_d; [2048,3584) (NW=4096 only): U gates; else 0.
// 392 rows (8 pad rows for prefetch over-read).
__global__ void kprepWH(const float* __restrict__ W_all, const float* __restrict__ W_d,
                        const float* __restrict__ U_all, h16* __restrict__ WTPH, int NW)
{
  int i = blockIdx.x * 256 + threadIdx.x;
  int total = 392 * NW;
  if (i >= total) return;
  int c = i / NW, j = i % NW;
  float v = 0.f;
  if (c < 384){
    if (j < 1536){ int g = j / 384, r = j % 384; v = W_all[r * 1536 + g * 384 + c]; }
    else if (j < 1920){ int r = j - 1536; v = W_d[r * 384 + c]; }
    else if (NW == 4096 && j >= 2048 && j < 3584){
      int jj = j - 2048; int g = jj / 384, r = jj % 384; v = U_all[(g * 384 + r) * 384 + c];
    }
  }
  WTPH[i] = (h16)v;
}

// UT[c][jj] = U_g[r][c], stride 1536 (for the Qp precompute GEMM)
__global__ void kprepU(const float* __restrict__ U_all, float* __restrict__ UT)
{
  int i = blockIdx.x * 256 + threadIdx.x;
  if (i >= 384 * 1536) return;
  int c = i / 1536, jj = i % 1536;
  int g = jj / 384, r = jj % 384;
  UT[i] = U_all[(g * 384 + r) * 384 + c];
}

// ---------------- per-(b,t) scalar precompute (double math, fp32 storage) ----------------
// XNF[idx] = {xn, artanh(xn), artanh(xnt)/xnt, ts}
__global__ void kxn(const float* __restrict__ xin, const float* __restrict__ tst,
                    float* __restrict__ XNF)
{
  int w = (blockIdx.x * 256 + threadIdx.x) >> 6;
  int ln = threadIdx.x & 63;
  int nw = (gridDim.x * 256) >> 6;
  for (int idx = w; idx < NB * NS; idx += nw){
    double s = 0;
    #pragma unroll
    for (int i = 0; i < 6; ++i){
      float v = xin[(size_t)idx * NH + ln + 64 * i];
      s += (double)v * v;
    }
    s = wredsumd(s);
    if (ln == 0){
      double xn = normclip(s);
      double ts = (double)tst[idx];
      double xnt = sqrt(fmax(384.0 * ts * ts, 1e-15));
      float4 o;
      o.x = (float)xn;
      o.y = (float)artanh_(xn);
      o.z = (float)(artanh_(xnt) / xnt);
      o.w = (float)ts;
      *(float4*)&XNF[(size_t)idx * 4] = o;
    }
  }
}

// ---------------- chunked Q GEMM: Q[rloc][jj] = sum_c X[b(rloc)][t0+tt(rloc)][c] * UT[c][jj] ----
__global__ __launch_bounds__(256) void kqgemmc(const float* __restrict__ X,
    const float* __restrict__ Bw, float* __restrict__ Q, int t0, int CH)
{
  int j0 = blockIdx.x * 64, i0 = blockIdx.y * 64;
  __shared__ __align__(16) float As[32][68];
  __shared__ __align__(16) float Bs[32][64];
  int tid = threadIdx.x;
  int tn = tid & 15, tm = tid >> 4;
  int slm = tid >> 2;
  int slc = (tid & 3) * 8;
  int blk = tid >> 3;
  int bln = (tid & 7) * 8;
  double accd[4][4] = {{0.0}};
  int rloc = i0 + slm;
  int bb = rloc / CH, tt = rloc - bb * CH;
  const float* arow = X + ((size_t)bb * NS + t0 + tt) * NH;
  for (int c0 = 0; c0 < NH; c0 += 32){
    float4 a4 = *(const float4*)(arow + c0 + slc);
    float4 a4b = *(const float4*)(arow + c0 + slc + 4);
    As[slc+0][slm] = a4.x;  As[slc+1][slm] = a4.y;
    As[slc+2][slm] = a4.z;  As[slc+3][slm] = a4.w;
    As[slc+4][slm] = a4b.x; As[slc+5][slm] = a4b.y;
    As[slc+6][slm] = a4b.z; As[slc+7][slm] = a4b.w;
    const float* bp = Bw + (size_t)(c0 + blk) * 1536 + j0 + bln;
    float4 b4a = *(const float4*)bp;
    float4 b4b = *(const float4*)(bp + 4);
    *(float4*)&Bs[blk][bln] = b4a;
    *(float4*)&Bs[blk][bln+4] = b4b;
    __syncthreads();
    float acc[4][4] = {{0.f}};
    #pragma unroll 8
    for (int c = 0; c < 32; ++c){
      float4 av = *(const float4*)&As[c][tm*4];
      float4 bv = *(const float4*)&Bs[c][tn*4];
      float a[4] = {av.x, av.y, av.z, av.w};
      float bb2[4] = {bv.x, bv.y, bv.z, bv.w};
      #pragma unroll
      for (int mm = 0; mm < 4; ++mm)
        #pragma unroll
        for (int jj = 0; jj < 4; ++jj)
          acc[mm][jj] += a[mm] * bb2[jj];
    }
    __syncthreads();
    #pragma unroll
    for (int mm = 0; mm < 4; ++mm)
      #pragma unroll
      for (int jj = 0; jj < 4; ++jj) accd[mm][jj] += (double)acc[mm][jj];
  }
  #pragma unroll
  for (int mm = 0; mm < 4; ++mm){
    float4 o; o.x = (float)accd[mm][0]; o.y = (float)accd[mm][1];
    o.z = (float)accd[mm][2]; o.w = (float)accd[mm][3];
    *(float4*)(Q + (size_t)(i0 + tm*4 + mm) * 1536 + j0 + tn*4) = o;
  }
}

// ---------------- fp32 gate chain (sums in double, scalars in fp32) ----------------
__device__ __forceinline__ void gatef(const float* __restrict__ pg, const float* __restrict__ qg,
    float hn, float art_hn, float xn, float art_xn, float* __restrict__ out)
{
  double sp = 0, sq = 0;
  #pragma unroll
  for (int i = 0; i < 6; ++i){ sp += (double)pg[i] * pg[i]; sq += (double)qg[i] * qg[i]; }
  float pn = ncf(wredsumd(sp));
  float qn = ncf(wredsumd(sq));
  float saf = tanhf(pn / hn * art_hn) / pn;
  float sbf = tanhf(qn / xn * art_xn) / qn;
  float a6[6], b6[6]; double sx2 = 0, sy2 = 0, sxy = 0;
  #pragma unroll
  for (int i = 0; i < 6; ++i){
    a6[i] = saf * pg[i]; b6[i] = sbf * qg[i];
    sx2 += (double)a6[i] * a6[i]; sy2 += (double)b6[i] * b6[i]; sxy += (double)a6[i] * b6[i];
  }
  float x2 = (float)wredsumd(sx2);
  float y2 = (float)wredsumd(sy2);
  float xy = (float)wredsumd(sxy);
  float dd = fmaxf(1.f + 2.f * xy + x2 * y2, 1e-15f);
  float fX = (1.f + 2.f * xy + y2) / dd;
  float fY = (1.f - x2) / dd;
  float m6[6]; double smm = 0;
  #pragma unroll
  for (int i = 0; i < 6; ++i){ m6[i] = fX * a6[i] + fY * b6[i]; smm += (double)m6[i] * m6[i]; }
  float nm = ncf(wredsumd(smm));
  float slf = artanhf_(nm) / nm;
  #pragma unroll
  for (int i = 0; i < 6; ++i) out[i] = 1.f / (1.f + expf(-slf * m6[i]));
}

// two interleaved gate chains (independent -> transcendentals pipeline)
__device__ __forceinline__ void gate2f(
    const float* __restrict__ pgA, const float* __restrict__ qgA,
    const float* __restrict__ pgB, const float* __restrict__ qgB,
    float hn, float art_hn, float xn, float art_xn,
    float* __restrict__ outA, float* __restrict__ outB)
{
  double spA = 0, sqA = 0, spB = 0, sqB = 0;
  #pragma unroll
  for (int i = 0; i < 6; ++i){
    spA += (double)pgA[i] * pgA[i]; sqA += (double)qgA[i] * qgA[i];
    spB += (double)pgB[i] * pgB[i]; sqB += (double)qgB[i] * qgB[i];
  }
  float pnA = ncf(wredsumd(spA)), qnA = ncf(wredsumd(sqA));
  float pnB = ncf(wredsumd(spB)), qnB = ncf(wredsumd(sqB));
  float safA = tanhf(pnA / hn * art_hn) / pnA;
  float sbfA = tanhf(qnA / xn * art_xn) / qnA;
  float safB = tanhf(pnB / hn * art_hn) / pnB;
  float sbfB = tanhf(qnB / xn * art_xn) / qnB;
  float aA[6], bA[6], aB[6], bB[6];
  double sxA = 0, syA = 0, sxyA = 0, sxB = 0, syB = 0, sxyB = 0;
  #pragma unroll
  for (int i = 0; i < 6; ++i){
    aA[i] = safA * pgA[i]; bA[i] = sbfA * qgA[i];
    aB[i] = safB * pgB[i]; bB[i] = sbfB * qgB[i];
    sxA += (double)aA[i] * aA[i]; syA += (double)bA[i] * bA[i]; sxyA += (double)aA[i] * bA[i];
    sxB += (double)aB[i] * aB[i]; syB += (double)bB[i] * bB[i]; sxyB += (double)aB[i] * bB[i];
  }
  float x2A = (float)wredsumd(sxA), y2A = (float)wredsumd(syA), xyA = (float)wredsumd(sxyA);
  float x2B = (float)wredsumd(sxB), y2B = (float)wredsumd(syB), xyB = (float)wredsumd(sxyB);
  float ddA = fmaxf(1.f + 2.f * xyA + x2A * y2A, 1e-15f);
  float ddB = fmaxf(1.f + 2.f * xyB + x2B * y2B, 1e-15f);
  float fXA = (1.f + 2.f * xyA + y2A) / ddA, fYA = (1.f - x2A) / ddA;
  float fXB = (1.f + 2.f * xyB + y2B) / ddB, fYB = (1.f - x2B) / ddB;
  float mA[6], mB[6]; double smA = 0, smB = 0;
  #pragma unroll
  for (int i = 0; i < 6; ++i){
    mA[i] = fXA * aA[i] + fYA * bA[i]; smA += (double)mA[i] * mA[i];
    mB[i] = fXB * aB[i] + fYB * bB[i]; smB += (double)mB[i] * mB[i];
  }
  float nmA = ncf(wredsumd(smA)), nmB = ncf(wredsumd(smB));
  float slfA = artanhf_(nmA) / nmA;
  float slfB = artanhf_(nmB) / nmB;
  #pragma unroll
  for (int i = 0; i < 6; ++i){
    outA[i] = 1.f / (1.f + expf(-slfA * mA[i]));
    outB[i] = 1.f / (1.f + expf(-slfB * mB[i]));
  }
}

// ================= row-local fused recurrence (chunked, cols-once GEMM, fp16 panel) ==========
// 64 blocks x 512 threads. Block owns batch rows 2*bid, 2*bid+1.
// GEMM: all 512 threads cover the NW columns once (NF_C h16x4 each), computing BOTH rows per
//       weight load. fp16 panel halves the per-CU L2 stream (the measured bottleneck).
// NL: 8 waves = 2 rows x {c-path+combine, gates f+i, gate o(+ctx), gate ct}. Scalar chain fp32.
template<int NW, int QPRE>
__global__ __launch_bounds__(512, 1) void krow(
    const h16* __restrict__ WTP, const float* __restrict__ xin,
    const float* __restrict__ XNF, const float* __restrict__ Qp,
    int CH, int t0, int t1,
    float* __restrict__ ctx, float* __restrict__ HsOut,
    float* __restrict__ HSV, float* __restrict__ CCV, double* __restrict__ SCV)
{
  constexpr int NF_C = NW / 2048;       // h16x4 per thread: 1 (QPRE) or 2 (fallback)
  constexpr int D = 6;                  // prefetch depth (rows 384..389 pad-covered)
  const int tid = threadIdx.x;
  const int wv = tid >> 6, ln = tid & 63;
  const int row = wv >> 2, wr = wv & 3; // NL role
  const int bb0 = blockIdx.x << 1;
  const int b = bb0 | row;              // this wave's batch row

  __shared__ __align__(16) float Zrow[2][NW];
  __shared__ f32x2 ALd[2][384][5];      // slots: 0=h, 1=cc, 2=x, 3=zero
  __shared__ float g384[2][4][384];
  __shared__ float sc[2][4];            // {hn, cc2, artanh(hn), pad}

  // ---- init / restore state ----
  for (int i = tid; i < 2 * 384 * 5; i += 512) ((f32x2*)ALd)[i] = f32x2{0.f, 0.f};
  __syncthreads();
  if (t0 > 0){
    for (int i = tid; i < 768; i += 512){
      int rg = i / 384, k = i - rg * 384;
      float hv_ = HSV[(size_t)(bb0 + rg) * 384 + k];
      float cv_ = CCV[(size_t)(bb0 + rg) * 384 + k];
      ALd[rg][k][0] = f32x2{hv_, hv_};
      ALd[rg][k][1] = f32x2{cv_, cv_};
    }
  }
  if (!QPRE){
    for (int i = tid; i < 768; i += 512){
      int rg = i / 384, k = i - rg * 384;
      float xv = xin[((size_t)(bb0 + rg) * NS + t0) * NH + k];
      ALd[rg][k][2] = f32x2{xv, xv};
    }
  }
  float cc6[6], hnf = 0.f, cc2f = 0.f;
  if (wr == 0){
    if (t0 == 0){
      #pragma unroll
      for (int i = 0; i < 6; ++i) cc6[i] = 0.f;
      hnf = sqrtf(1e-15f); cc2f = 0.f;
    } else {
      #pragma unroll
      for (int i = 0; i < 6; ++i) cc6[i] = CCV[(size_t)b * 384 + ln + 64 * i];
      hnf = (float)SCV[b * 2]; cc2f = (float)SCV[b * 2 + 1];
    }
    if (ln == 0){ sc[row][0] = hnf; sc[row][1] = cc2f; sc[row][2] = artanhf_(hnf); }
  }
  __syncthreads();

  // column assignment (cols-once)
  const int col0 = tid * (NF_C * 4);
  int sel;
  if (col0 < 1536) sel = 0;
  else if (col0 < 1920) sel = 1;
  else if (QPRE) sel = 3;
  else if (col0 < 2048) sel = 3;
  else if (col0 < 3584) sel = 2;
  else sel = 3;

  float qreg[12];
  float xr[6];

  for (int t = t0; t < t1; ++t){
    // ---- per-wave row scalars + prefetches (latency hidden under GEMM) ----
    float4 xf = *(const float4*)&XNF[((size_t)b * NS + t) * 4]; // {xn, art_xn, axnt, ts}
    if (QPRE){
      const float* qp = Qp + ((size_t)b * CH + (t - t0)) * 1536;
      if (wr == 1){
        #pragma unroll
        for (int i = 0; i < 12; ++i) qreg[i] = qp[ln + 64 * i];
      } else if (wr == 2){
        #pragma unroll
        for (int i = 0; i < 6; ++i) qreg[i] = qp[768 + ln + 64 * i];
      } else if (wr == 3){
        #pragma unroll
        for (int i = 0; i < 6; ++i) qreg[i] = qp[1152 + ln + 64 * i];
      }
    } else {
      if (wr == 3 && t + 1 < t1){
        #pragma unroll
        for (int i = 0; i < 6; ++i) xr[i] = xin[((size_t)b * NS + t + 1) * NH + ln + 64 * i];
      }
    }

    // ---- GEMM: cols-once, both rows; fp16 weights -> fp32 FMA + fp64 flush each 96 ----
    {
      const h16* pt[D];
      #pragma unroll
      for (int d = 0; d < D; ++d) pt[d] = WTP + (size_t)d * NW + col0;
      h16x4 wb[D][NF_C];
      #pragma unroll
      for (int d = 0; d < D; ++d){
        #pragma unroll
        for (int k = 0; k < NF_C; ++k) wb[d][k] = *(const h16x4*)(pt[d] + 4 * k);
        pt[d] += (size_t)D * NW;
      }
      double ad0[NF_C * 4], ad1[NF_C * 4];
      #pragma unroll
      for (int k = 0; k < NF_C * 4; ++k){ ad0[k] = 0.0; ad1[k] = 0.0; }
      for (int c0 = 0; c0 < 384; c0 += 96){
        f32x2 a0[NF_C * 2], a1[NF_C * 2];
        #pragma unroll
        for (int k = 0; k < NF_C * 2; ++k){ a0[k] = f32x2{0.f, 0.f}; a1[k] = f32x2{0.f, 0.f}; }
        for (int cc = 0; cc < 96; cc += D){
          #pragma unroll
          for (int d = 0; d < D; ++d){
            const int c = c0 + cc + d;
            f32x2 v0 = ALd[0][c][sel];
            f32x2 v1 = ALd[1][c][sel];
            #pragma unroll
            for (int k = 0; k < NF_C; ++k){
              h16x4 w = wb[d][k];
              f32x2 wlo = f32x2{(float)w.x, (float)w.y};
              f32x2 whi = f32x2{(float)w.z, (float)w.w};
              a0[2 * k + 0] += wlo * v0;
              a0[2 * k + 1] += whi * v0;
              a1[2 * k + 0] += wlo * v1;
              a1[2 * k + 1] += whi * v1;
            }
            #pragma unroll
            for (int k = 0; k < NF_C; ++k) wb[d][k] = *(const h16x4*)(pt[d] + 4 * k);
            pt[d] += (size_t)D * NW;
          }
        }
        #pragma unroll
        for (int k = 0; k < NF_C * 2; ++k){
          ad0[2 * k]     += (double)a0[k].x;
          ad0[2 * k + 1] += (double)a0[k].y;
          ad1[2 * k]     += (double)a1[k].x;
          ad1[2 * k + 1] += (double)a1[k].y;
        }
      }
      #pragma unroll
      for (int k = 0; k < NF_C; ++k){
        float4 o0, o1;
        o0.x = (float)ad0[4 * k + 0]; o0.y = (float)ad0[4 * k + 1];
        o0.z = (float)ad0[4 * k + 2]; o0.w = (float)ad0[4 * k + 3];
        o1.x = (float)ad1[4 * k + 0]; o1.y = (float)ad1[4 * k + 1];
        o1.z = (float)ad1[4 * k + 2]; o1.w = (float)ad1[4 * k + 3];
        *(float4*)&Zrow[0][col0 + 4 * k] = o0;
        *(float4*)&Zrow[1][col0 + 4 * k] = o1;
      }
    }
    __syncthreads();   // B1: Zrow ready

    // ---- NL (fp32 scalar chain, double reduces) ----
    float hn_s = sc[row][0];
    float art_hn = sc[row][2];
    float cadj[6];
    if (wr == 0){
      float tsf = xf.w, axnt = xf.z;
      float cnf = sqrtf(fmaxf(cc2f, 1e-15f));
      float mv6[6]; double s_mv = 0;
      #pragma unroll
      for (int i = 0; i < 6; ++i){
        mv6[i] = Zrow[row][1536 + ln + 64 * i];
        s_mv += (double)mv6[i] * mv6[i];
      }
      float mvn = ncf(wredsumd(s_mv));
      float s1 = tanhf(mvn / cnf * artanhf_(cnf));
      float c1f = s1 / mvn;
      float m1[6]; double sm1 = 0;
      #pragma unroll
      for (int i = 0; i < 6; ++i){ m1[i] = c1f * mv6[i]; sm1 += (double)m1[i] * m1[i]; }
      float n1 = ncf(wredsumd(sm1));
      float l1f = artanhf_(n1) / n1;
      float v6[6]; double sv = 0;
      #pragma unroll
      for (int i = 0; i < 6; ++i){ v6[i] = tanhf(l1f * m1[i]); sv += (double)v6[i] * v6[i]; }
      float nv = ncf(wredsumd(sv));
      float e1f = tanhf(nv) / nv;
      float cs1[6]; double scs = 0, sccd = 0;
      #pragma unroll
      for (int i = 0; i < 6; ++i){ cs1[i] = e1f * v6[i]; scs += (double)cs1[i] * cs1[i]; sccd -= (double)cs1[i] * cc6[i]; }
      double swx = 0;
      #pragma unroll
      for (int i = 0; i < 6; ++i){ float w = cs1[i] * tsf; swx += (double)w * w; }
      float wxn1 = ncf(wredsumd(swx));
      float s2f = tanhf(wxn1 * axnt) / wxn1 * tsf;
      float cs2[6];
      #pragma unroll
      for (int i = 0; i < 6; ++i) cs2[i] = s2f * cs1[i];
      float x2a = (float)wredsumd(scs);
      float xya = (float)wredsumd(sccd);
      float y2a = cc2f;
      float dA = fmaxf(1.f + 2.f * xya + x2a * y2a, 1e-15f);
      float fXA = (1.f + 2.f * xya + y2a) / dA;
      float fYA = (1.f - x2a) / dA;
      float A6[6]; double sA = 0, sAc = 0, sc2_ = 0;
      #pragma unroll
      for (int i = 0; i < 6; ++i){
        A6[i] = fXA * (-cs1[i]) + fYA * cc6[i];
        sA += (double)A6[i] * A6[i]; sAc += (double)A6[i] * cs2[i]; sc2_ += (double)cs2[i] * cs2[i];
      }
      float x2b = (float)wredsumd(sA);
      float xyb = (float)wredsumd(sAc);
      float y2b = (float)wredsumd(sc2_);
      float dB = fmaxf(1.f + 2.f * xyb + x2b * y2b, 1e-15f);
      float fXB = (1.f + 2.f * xyb + y2b) / dB;
      float fYB = (1.f - x2b) / dB;
      #pragma unroll
      for (int i = 0; i < 6; ++i) cadj[i] = fXB * A6[i] + fYB * cs2[i];
    } else if (wr == 1){
      float pgA[6], qgA[6], pgB[6], qgB[6], outA[6], outB[6];
      #pragma unroll
      for (int i = 0; i < 6; ++i){
        int r = ln + 64 * i;
        pgA[i] = Zrow[row][r];
        qgA[i] = QPRE ? qreg[i] : Zrow[row][2048 + r];
        pgB[i] = Zrow[row][384 + r];
        qgB[i] = QPRE ? qreg[6 + i] : Zrow[row][2048 + 384 + r];
      }
      gate2f(pgA, qgA, pgB, qgB, hn_s, art_hn, xf.x, xf.y, outA, outB);
      #pragma unroll
      for (int i = 0; i < 6; ++i){
        g384[row][0][ln + 64 * i] = outA[i];
        g384[row][1][ln + 64 * i] = outB[i];
      }
    } else if (wr == 2){
      float pg[6], qg[6], og[6];
      #pragma unroll
      for (int i = 0; i < 6; ++i){
        int r = ln + 64 * i;
        pg[i] = Zrow[row][768 + r];
        qg[i] = QPRE ? qreg[i] : Zrow[row][2048 + 768 + r];
      }
      gatef(pg, qg, hn_s, art_hn, xf.x, xf.y, og);
      #pragma unroll
      for (int i = 0; i < 6; ++i){
        int r = ln + 64 * i;
        g384[row][2][r] = og[i];
        ctx[((size_t)b * NS + t) * NH + r] = og[i];   // o-gate is the context
      }
    } else {
      float pg[6], qg[6], og[6];
      #pragma unroll
      for (int i = 0; i < 6; ++i){
        int r = ln + 64 * i;
        pg[i] = Zrow[row][1152 + r];
        qg[i] = QPRE ? qreg[i] : Zrow[row][2048 + 1152 + r];
      }
      gatef(pg, qg, hn_s, art_hn, xf.x, xf.y, og);
      #pragma unroll
      for (int i = 0; i < 6; ++i) g384[row][3][ln + 64 * i] = og[i];
    }
    __syncthreads();   // B2: gates ready

    if (wr == 0){
      float g0[6], g1[6], g2[6], g3[6];
      #pragma unroll
      for (int i = 0; i < 6; ++i){
        int r = ln + 64 * i;
        g0[i] = g384[row][0][r]; g1[i] = g384[row][1][r];
        g2[i] = g384[row][2][r]; g3[i] = g384[row][3][r];
      }
      double sct = 0, sict = 0; float wP[6];
      #pragma unroll
      for (int i = 0; i < 6; ++i){ float ct = g3[i]; sct += (double)ct * ct; wP[i] = g1[i] * ct; sict += (double)wP[i] * wP[i]; }
      float ctn = ncf(wredsumd(sct));
      float wPn = ncf(wredsumd(sict));
      float sPf = tanhf(wPn / ctn * artanhf_(ctn)) / wPn;
      float P6[6]; double sPP = 0;
      #pragma unroll
      for (int i = 0; i < 6; ++i){ P6[i] = sPf * wP[i]; sPP += (double)P6[i] * P6[i]; }
      double sca = 0, sfca = 0; float wQ[6];
      #pragma unroll
      for (int i = 0; i < 6; ++i){ sca += (double)cadj[i] * cadj[i]; wQ[i] = g0[i] * cadj[i]; sfca += (double)wQ[i] * wQ[i]; }
      float can = ncf(wredsumd(sca));
      float wQn = ncf(wredsumd(sfca));
      float sQf = tanhf(wQn / can * artanhf_(can)) / wQn;
      float Q6[6]; double sQQ = 0, sPQ = 0;
      #pragma unroll
      for (int i = 0; i < 6; ++i){ Q6[i] = sQf * wQ[i]; sQQ += (double)Q6[i] * Q6[i]; sPQ += (double)P6[i] * Q6[i]; }
      float x2c = (float)wredsumd(sPP);
      float y2c = (float)wredsumd(sQQ);
      float xyc = (float)wredsumd(sPQ);
      float dC = fmaxf(1.f + 2.f * xyc + x2c * y2c, 1e-15f);
      float fXC = (1.f + 2.f * xyc + y2c) / dC;
      float fYC = (1.f - x2c) / dC;
      float ccn6[6], w6[6]; double sw_ = 0;
      #pragma unroll
      for (int i = 0; i < 6; ++i){ ccn6[i] = fXC * P6[i] + fYC * Q6[i]; w6[i] = tanhf(ccn6[i]); sw_ += (double)w6[i] * w6[i]; }
      float nw = ncf(wredsumd(sw_));
      float eef = tanhf(nw) / nw;
      float e6[6], wH[6]; double se = 0, soe = 0;
      #pragma unroll
      for (int i = 0; i < 6; ++i){ e6[i] = eef * w6[i]; se += (double)e6[i] * e6[i]; wH[i] = g2[i] * e6[i]; soe += (double)wH[i] * wH[i]; }
      float en = ncf(wredsumd(se));
      float wHn = ncf(wredsumd(soe));
      float sHf = tanhf(wHn / en * artanhf_(en)) / wHn;
      float hv[6]; double sh2 = 0, scc2 = 0;
      #pragma unroll
      for (int i = 0; i < 6; ++i){
        hv[i] = sHf * wH[i];
        sh2 += (double)hv[i] * hv[i];
        scc2 += (double)ccn6[i] * ccn6[i];
      }
      float hn_next = ncf(wredsumd(sh2));
      float cc2_next = (float)wredsumd(scc2);
      #pragma unroll
      for (int i = 0; i < 6; ++i){
        int r = ln + 64 * i;
        cc6[i] = ccn6[i];
        ALd[row][r][0] = f32x2{hv[i], hv[i]};
        ALd[row][r][1] = f32x2{ccn6[i], ccn6[i]};
      }
      hnf = hn_next; cc2f = cc2_next;
      if (ln == 0){ sc[row][0] = hn_next; sc[row][1] = cc2_next; sc[row][2] = artanhf_(hn_next); }
      if (t == t1 - 1){
        #pragma unroll
        for (int i = 0; i < 6; ++i){
          int r = ln + 64 * i;
          HSV[(size_t)b * 384 + r] = hv[i];
          CCV[(size_t)b * 384 + r] = ccn6[i];
        }
        if (ln == 0){ SCV[b * 2] = (double)hn_next; SCV[b * 2 + 1] = (double)cc2_next; }
      }
      if (t == NS - 1){
        #pragma unroll
        for (int i = 0; i < 6; ++i) HsOut[b * NH + ln + 64 * i] = hv[i];
      }
    }
    if (!QPRE && wr == 3 && t + 1 < t1){
      #pragma unroll
      for (int i = 0; i < 6; ++i) ALd[row][ln + 64 * i][2] = f32x2{xr[i], xr[i]};
    }
    __syncthreads();   // B3: state ready for next t
  }
}

// ---------------- block reduce helpers ----------------
__device__ __forceinline__ double blocksumd(double v, double* red){
  v = wredsumd(v);
  __syncthreads();
  if ((threadIdx.x & 63) == 0) red[threadIdx.x >> 6] = v;
  __syncthreads();
  return red[0] + red[1] + red[2] + red[3];
}
__device__ __forceinline__ double blockmaxd(double v, double* red){
  #pragma unroll
  for (int off = 32; off; off >>= 1) v = fmax(v, __shfl_xor(v, off, 64));
  __syncthreads();
  if ((threadIdx.x & 63) == 0) red[threadIdx.x >> 6] = v;
  __syncthreads();
  return fmax(fmax(red[0], red[1]), fmax(red[2], red[3]));
}

// ---------------- query / scores / softmax / aw / bt ----------------
__global__ __launch_bounds__(256) void kattn1(const float* __restrict__ Hs,
    const float* __restrict__ Win, const float* __restrict__ ctx,
    const float* __restrict__ dt, const float* __restrict__ ab,
    double* __restrict__ query, double* __restrict__ aw, double* __restrict__ bt)
{
  int b = blockIdx.x; int tid = threadIdx.x;
  __shared__ double hL[NH], qL[NH], scs[NS];
  __shared__ double red[4];
  for (int r = tid; r < NH; r += 256) hL[r] = (double)Hs[b * NH + r];
  __syncthreads();
  for (int r = tid; r < NH; r += 256){
    double s = 0;
    const float* wr = Win + (size_t)r * NH;
    for (int c = 0; c < NH; ++c) s += hL[c] * (double)wr[c];
    qL[r] = s; query[b * NH + r] = s;
  }
  __syncthreads();
  int wv = tid >> 6, ln = tid & 63;
  for (int s_ = wv; s_ < NS; s_ += 4){
    const float* crow = ctx + ((size_t)b * NS + s_) * NH;
    double par = 0;
    #pragma unroll
    for (int i = 0; i < 6; ++i){ int d = ln + 64 * i; par += qL[d] * (double)crow[d]; }
    par = wredsumd(par);
    if (ln == 0) scs[s_] = par;
  }
  __syncthreads();
  double v0 = scs[tid];
  double v1 = (tid + 256 < NS) ? scs[tid + 256] : -1e300;
  double mx = blockmaxd(fmax(v0, v1), red);
  double e0 = exp(v0 - mx);
  double e1 = (tid + 256 < NS) ? exp(v1 - mx) : 0.0;
  double tot = blocksumd(e0 + e1, red);
  double a0 = e0 / tot, a1 = e1 / tot;
  double n = normclip(blocksumd(a0 * a0 + a1 * a1, red));
  double s1 = tanh(n) / n;
  double w0 = s1 * a0, w1 = s1 * a1;
  double pn = normclip(blocksumd(w0 * w0 + w1 * w1, red));
  if (pn > 0.999){ double f = 0.999 / pn; w0 *= f; w1 *= f; }
  aw[b * NS + tid] = w0;
  if (tid + 256 < NS) aw[b * NS + tid + 256] = w1;
  double abv = (double)ab[b];
  double b0 = exp(-abv * (double)dt[b * NS + tid]);
  double b1v = (tid + 256 < NS) ? exp(-abv * (double)dt[b * NS + tid + 256]) : 0.0;
  double nb = normclip(blocksumd(b0 * b0 + b1v * b1v, red));
  double sb = tanh(nb) / nb;
  double c0 = sb * b0, c1 = sb * b1v;
  double pnb = normclip(blocksumd(c0 * c0 + c1 * c1, red));
  if (pnb > 0.999){ double f = 0.999 / pnb; c0 *= f; c1 *= f; }
  bt[b * NS + tid] = c0;
  if (tid + 256 < NS) bt[b * NS + tid + 256] = c1;
}

// ---------------- hyperbolic attention mixing ----------------
__global__ __launch_bounds__(256) void kmix(const float* __restrict__ ctx,
    const double* __restrict__ aw, const double* __restrict__ bt,
    const float* __restrict__ ae, double* __restrict__ nom, double* __restrict__ den)
{
  int b = blockIdx.y; int h0 = blockIdx.x * 32;
  __shared__ float T[32][385];
  int tid = threadIdx.x;
  for (int idx = tid; idx < NS * 32; idx += 256){
    int s = idx >> 5, hh = idx & 31;
    T[hh][s] = ctx[((size_t)b * NS + s) * NH + h0 + hh];
  }
  __syncthreads();
  int wv = tid >> 6, ln = tid & 63;
  double aev = (double)ae[b];
  double aw6[6], bt6[6]; double sbt = 0;
  #pragma unroll
  for (int i = 0; i < 6; ++i){
    aw6[i] = aw[b * NS + ln + 64 * i];
    bt6[i] = bt[b * NS + ln + 64 * i];
    sbt += bt6[i] * bt6[i];
  }
  double xnb = normclip(wredsumd(sbt));
  double art_xnb = artanh_(xnb);
  double denacc = 0.0;
  for (int k = 0; k < 8; ++k){
    int hh = wv * 8 + k;
    double v[6]; double sx = 0;
    #pragma unroll
    for (int i = 0; i < 6; ++i){ v[i] = (double)T[hh][ln + 64 * i]; sx += v[i] * v[i]; }
    double xnv = normclip(wredsumd(sx));
    double wx[6]; double swx = 0;
    #pragma unroll
    for (int i = 0; i < 6; ++i){ wx[i] = aw6[i] * v[i]; swx += wx[i] * wx[i]; }
    double wxn = normclip(wredsumd(swx));
    double s1 = tanh(wxn / xnv * artanh_(xnv)) / wxn;
    double mix[6]; double sm = 0;
    #pragma unroll
    for (int i = 0; i < 6; ++i){ mix[i] = s1 * wx[i]; sm += mix[i] * mix[i]; }
    double n1 = normclip(wredsumd(sm));
    if (n1 > 0.999){ double f = 0.999 / n1;
      #pragma unroll
      for (int i = 0; i < 6; ++i) mix[i] *= f; }
    double sm2 = 0;
    #pragma unroll
    for (int i = 0; i < 6; ++i) sm2 += mix[i] * mix[i];
    double xn2 = normclip(wredsumd(sm2));
    double wx2[6]; double sw2 = 0;
    #pragma unroll
    for (int i = 0; i < 6; ++i){ wx2[i] = aev * mix[i]; sw2 += wx2[i] * wx2[i]; }
    double wxn2 = normclip(wredsumd(sw2));
    double s2 = tanh(wxn2 / xn2 * artanh_(xn2)) / wxn2;
    double tmp[6]; double st = 0;
    #pragma unroll
    for (int i = 0; i < 6; ++i){ tmp[i] = s2 * wx2[i]; st += tmp[i] * tmp[i]; }
    double n2 = normclip(wredsumd(st));
    if (n2 > 0.999){ double f = 0.999 / n2;
      #pragma unroll
      for (int i = 0; i < 6; ++i) tmp[i] *= f; }
    double wx3[6]; double sw3 = 0;
    #pragma unroll
    for (int i = 0; i < 6; ++i){ wx3[i] = tmp[i] * bt6[i]; sw3 += wx3[i] * wx3[i]; }
    double wxn3 = normclip(wredsumd(sw3));
    double s3 = tanh(wxn3 / xnb * art_xnb) / wxn3;
    double t2[6]; double st2 = 0;
    #pragma unroll
    for (int i = 0; i < 6; ++i){ t2[i] = s3 * wx3[i]; st2 += t2[i] * t2[i]; }
    double n3 = normclip(wredsumd(st2));
    if (n3 > 0.999){ double f = 0.999 / n3;
      #pragma unroll
      for (int i = 0; i < 6; ++i) t2[i] *= f; }
    #pragma unroll
    for (int i = 0; i < 6; ++i) t2[i] = fmax(t2[i], 0.0);
    double sxx = 0, syy = 0, sxy = 0;
    #pragma unroll
    for (int i = 0; i < 6; ++i){ sxx += mix[i] * mix[i]; syy += t2[i] * t2[i]; sxy += mix[i] * t2[i]; }
    sxx = wredsumd(sxx); syy = wredsumd(syy); sxy = wredsumd(sxy);
    double dn = fmax(1.0 + 2.0 * sxy + sxx * syy, 1e-15);
    double ca = (1.0 + 2.0 * sxy + syy) / dn, cb = (1.0 - sxx) / dn;
    double m2[6]; double sm3 = 0;
    #pragma unroll
    for (int i = 0; i < 6; ++i){ m2[i] = ca * mix[i] + cb * t2[i]; sm3 += m2[i] * m2[i]; }
    double n4 = normclip(wredsumd(sm3));
    if (n4 > 0.999){ double f = 0.999 / n4;
      #pragma unroll
      for (int i = 0; i < 6; ++i) m2[i] *= f; }
    double snn = 0;
    #pragma unroll
    for (int i = 0; i < 6; ++i) snn += m2[i] * m2[i];
    snn = wredsumd(snn);
    double lam = 2.0 / fmax(1.0 - snn, 1e-15);
    #pragma unroll
    for (int i = 0; i < 6; ++i) atomicAdd(&nom[b * NS + ln + 64 * i], lam * m2[i]);
    if (ln == 0) denacc += lam - 1.0;
  }
  if (ln == 0) atomicAdd(&den[b], denacc);
}

// ---------------- midpoint + logmap0 + output head ----------------
__global__ __launch_bounds__(256) void kfinal(const double* __restrict__ nom,
    const double* __restrict__ den, const double* __restrict__ query,
    const float* __restrict__ Wout, const float* __restrict__ W1,
    const float* __restrict__ b1, const float* __restrict__ W2,
    const float* __restrict__ b2, float* __restrict__ out)
{
  int b = blockIdx.x; int tid = threadIdx.x;
  __shared__ double comb[768];
  __shared__ double att[NH];
  __shared__ double x1[NH];
  __shared__ double red[4];
  double dnb = fmax(den[b], 1e-10);
  double u0 = nom[b * NS + tid] / dnb;
  double u1 = (tid + 256 < NS) ? nom[b * NS + tid + 256] / dnb : 0.0;
  double n = normclip(blocksumd(u0 * u0 + u1 * u1, red));
  double sf = tanh(0.5 * artanh_(n)) / n;
  double f0 = sf * u0, f1 = sf * u1;
  double n2 = normclip(blocksumd(f0 * f0 + f1 * f1, red));
  double sl = artanh_(n2) / n2;
  comb[tid] = sl * f0;
  if (tid + 256 < NS) comb[tid + 256] = sl * f1;
  for (int r = tid; r < NH; r += 256) comb[NH + r] = query[b * NH + r];
  __syncthreads();
  for (int r = tid; r < NH; r += 256){
    double s = 0;
    const float* wr = Wout + (size_t)r * 768;
    for (int c = 0; c < 768; ++c) s += comb[c] * (double)wr[c];
    att[r] = tanh(s);
  }
  __syncthreads();
  for (int r = tid; r < NH; r += 256){
    double s = (double)b1[r];
    const float* wr = W1 + (size_t)r * NH;
    for (int c = 0; c < NH; ++c) s += att[c] * (double)wr[c];
    x1[r] = fmax(s, 0.0);
  }
  __syncthreads();
  double p0 = 0, p1 = 0;
  for (int c = tid; c < NH; c += 256){ p0 += x1[c] * (double)W2[c]; p1 += x1[c] * (double)W2[NH + c]; }
  p0 = blocksumd(p0, red);
  p1 = blocksumd(p1, red);
  if (tid == 0){ out[b * 2 + 0] = (float)(p0 + (double)b2[0]); out[b * 2 + 1] = (float)(p1 + (double)b2[1]); }
}

extern "C" void kernel_launch(void* const* d_in, const int* in_sizes, int n_in,
                              void* d_out, int out_size, void* d_ws, size_t ws_size,
                              hipStream_t stream)
{
  (void)in_sizes; (void)n_in; (void)out_size;
  const float* inputs  = (const float*)d_in[0];
  const float* tstamps = (const float*)d_in[1];
  const float* delta_t = (const float*)d_in[2];
  const float* W_all   = (const float*)d_in[3];
  const float* U_all   = (const float*)d_in[4];
  const float* W_d     = (const float*)d_in[5];
  const float* Win     = (const float*)d_in[6];
  const float* Wout    = (const float*)d_in[7];
  const float* ae      = (const float*)d_in[8];
  const float* ab      = (const float*)d_in[9];
  const float* W1      = (const float*)d_in[10];
  const float* b1      = (const float*)d_in[11];
  const float* W2      = (const float*)d_in[12];
  const float* b2      = (const float*)d_in[13];
  float* out = (float*)d_out;

  // double region
  double* wd = (double*)d_ws;
  size_t od = 0;
  double* NOMD  = wd + od; od += (size_t)NB * NS;
  double* DEND  = wd + od; od += (size_t)NB;
  double* QUERY = wd + od; od += (size_t)NB * NH;
  double* AW    = wd + od; od += (size_t)NB * NS;
  double* BT    = wd + od; od += (size_t)NB * NS;
  double* SCV   = wd + od; od += (size_t)NB * 2;
  // float region
  float* wf = (float*)(wd + od);
  size_t of = 0;
  h16* WTPH   = (h16*)(wf + of); of += (size_t)392 * 4096 / 2;  // fp16 weight panel (max layout)
  float* UT   = wf + of; of += (size_t)384 * 1536;
  float* CTX  = wf + of; of += (size_t)NB * NS * NH;
  float* HS   = wf + of; of += (size_t)NB * NH;
  float* HSV  = wf + of; of += (size_t)NB * NH;        // chunk-boundary h state
  float* CCV  = wf + of; of += (size_t)NB * NH;        // chunk-boundary cc state
  float* XNF  = wf + of; of += (size_t)NB * NS * 4;    // {xn, art_xn, axnt, ts}
  float* Qp   = wf + of;                               // Qp chunk buffer (sized by CH)

  size_t base_bytes = od * 8 + of * 4;

  // pick the largest time-chunk whose Qp buffer fits the workspace
  int CH = 0;
  const int chs[7] = {384, 192, 96, 48, 24, 12, 6};
  for (int ci = 0; ci < 7; ++ci){
    size_t need = base_bytes + (size_t)NB * chs[ci] * 1536 * 4;
    if (ws_size >= need){ CH = chs[ci]; break; }
  }

  // zero midpoint accumulators + per-(b,t) scalar precompute
  int nzd = NB * NS + NB;
  hipLaunchKernelGGL(kzerod, dim3((nzd + 255) / 256), dim3(256), 0, stream, NOMD, nzd);
  hipLaunchKernelGGL(kxn, dim3(768), dim3(256), 0, stream, inputs, tstamps, XNF);

  if (CH > 0){
    // 1920-col fp16 panel (1.6 MB): halves the per-CU L2 weight stream
    hipLaunchKernelGGL(kprepWH, dim3((392 * 2048 + 255) / 256), dim3(256), 0, stream,
                       W_all, W_d, U_all, WTPH, 2048);
    hipLaunchKernelGGL(kprepU, dim3((384 * 1536 + 255) / 256), dim3(256), 0, stream, U_all, UT);
    for (int t0 = 0; t0 < NS; t0 += CH){
      hipLaunchKernelGGL(kqgemmc, dim3(24, 2 * CH), dim3(256), 0, stream,
                         inputs, UT, Qp, t0, CH);
      hipLaunchKernelGGL(HIP_KERNEL_NAME(krow<2048, 1>), dim3(64), dim3(512), 0, stream,
                         WTPH, inputs, XNF, Qp, CH, t0, t0 + CH,
                         CTX, HS, HSV, CCV, SCV);
    }
  } else {
    // workspace too small even for CH=6: single-launch fallback (U columns in-panel)
    hipLaunchKernelGGL(kprepWH, dim3((392 * 4096 + 255) / 256), dim3(256), 0, stream,
                       W_all, W_d, U_all, WTPH, 4096);
    hipLaunchKernelGGL(HIP_KERNEL_NAME(krow<4096, 0>), dim3(64), dim3(512), 0, stream,
                       WTPH, inputs, XNF, Qp /*unused*/, 1, 0, NS,
                       CTX, HS, HSV, CCV, SCV);
  }

  hipLaunchKernelGGL(kattn1, dim3(128), dim3(256), 0, stream,
                     HS, Win, CTX, delta_t, ab, QUERY, AW, BT);
  hipLaunchKernelGGL(kmix, dim3(12, 128), dim3(256), 0, stream, CTX, AW, BT, ae, NOMD, DEND);
  hipLaunchKernelGGL(kfinal, dim3(128), dim3(256), 0, stream,
                     NOMD, DEND, QUERY, Wout, W1, b1, W2, b2, out);
}

// Round 9
// 9961.327 us; speedup vs baseline: 7.3891x; 1.4886x over previous
//
#include <hip/hip_runtime.h>
#include <cmath>

constexpr int NB = 128;     // batch
constexpr int NS = 384;     // seq len
constexpr int NH = 384;     // hidden = input dim

typedef __attribute__((ext_vector_type(2))) float f32x2;
typedef _Float16 h16;
typedef __attribute__((ext_vector_type(8))) _Float16 h16x8;

__device__ __forceinline__ double clampd(double x, double lo, double hi){ return fmin(fmax(x,lo),hi); }
__device__ __forceinline__ double artanh_(double x){ return atanh(clampd(x, -1.0 + 1e-7, 1.0 - 1e-7)); }
__device__ __forceinline__ double normclip(double s){ return sqrt(fmax(s, 1e-15)); }
__device__ __forceinline__ float clampf_(float x, float lo, float hi){ return fminf(fmaxf(x,lo),hi); }
__device__ __forceinline__ float artanhf_(float x){ return atanhf(clampf_(x, -1.f + 1e-7f, 1.f - 1e-7f)); }
__device__ __forceinline__ double wredsumd(double v){
  #pragma unroll
  for (int off = 32; off; off >>= 1) v += __shfl_xor(v, off, 64);
  return v;
}
// norm from a double sum, fp32 result
__device__ __forceinline__ float ncf(double s){ return sqrtf(fmaxf((float)s, 1e-15f)); }

// ---------------- zero ----------------
__global__ void kzerod(double* p, int n){
  int i = blockIdx.x * 256 + threadIdx.x;
  if (i < n) p[i] = 0.0;
}

// ---------------- weight pack (fp16, k-pair interleaved) ----------------
// WTI[cp][j*2 + (c&1)], c = 2*cp+(jj&1); 200 cp rows (>=196 needed for D=6 prefetch).
// j<1536: gate W (4 gates x 384); [1536,1920): W_d; [2048,3584) (NW=4096 only): U gates; else 0.
__global__ void kprepWI(const float* __restrict__ W_all, const float* __restrict__ W_d,
                        const float* __restrict__ U_all, h16* __restrict__ WTI, int NW)
{
  int i = blockIdx.x * 256 + threadIdx.x;
  int wrow = NW * 2;
  int total = 200 * wrow;
  if (i >= total) return;
  int cp = i / wrow, jj = i - cp * wrow;
  int j = jj >> 1, par = jj & 1;
  int c = cp * 2 + par;
  float v = 0.f;
  if (c < 384){
    if (j < 1536){ int g = j / 384, r = j % 384; v = W_all[r * 1536 + g * 384 + c]; }
    else if (j < 1920){ int r = j - 1536; v = W_d[r * 384 + c]; }
    else if (NW == 4096 && j >= 2048 && j < 3584){
      int jg = j - 2048; int g = jg / 384, r = jg % 384; v = U_all[(g * 384 + r) * 384 + c];
    }
  }
  WTI[i] = (h16)v;
}

// UT[c][jj] = U_g[r][c], stride 1536 (for the Qp precompute GEMM)
__global__ void kprepU(const float* __restrict__ U_all, float* __restrict__ UT)
{
  int i = blockIdx.x * 256 + threadIdx.x;
  if (i >= 384 * 1536) return;
  int c = i / 1536, jj = i % 1536;
  int g = jj / 384, r = jj % 384;
  UT[i] = U_all[(g * 384 + r) * 384 + c];
}

// ---------------- per-(b,t) scalar precompute (double math, fp32 storage) ----------------
// XNF[idx] = {xn, artanh(xn), artanh(xnt)/xnt, ts}
__global__ void kxn(const float* __restrict__ xin, const float* __restrict__ tst,
                    float* __restrict__ XNF)
{
  int w = (blockIdx.x * 256 + threadIdx.x) >> 6;
  int ln = threadIdx.x & 63;
  int nw = (gridDim.x * 256) >> 6;
  for (int idx = w; idx < NB * NS; idx += nw){
    double s = 0;
    #pragma unroll
    for (int i = 0; i < 6; ++i){
      float v = xin[(size_t)idx * NH + ln + 64 * i];
      s += (double)v * v;
    }
    s = wredsumd(s);
    if (ln == 0){
      double xn = normclip(s);
      double ts = (double)tst[idx];
      double xnt = sqrt(fmax(384.0 * ts * ts, 1e-15));
      float4 o;
      o.x = (float)xn;
      o.y = (float)artanh_(xn);
      o.z = (float)(artanh_(xnt) / xnt);
      o.w = (float)ts;
      *(float4*)&XNF[(size_t)idx * 4] = o;
    }
  }
}

// ---------------- chunked Q GEMM: Q[rloc][jj] = sum_c X[b(rloc)][t0+tt(rloc)][c] * UT[c][jj] ----
__global__ __launch_bounds__(256) void kqgemmc(const float* __restrict__ X,
    const float* __restrict__ Bw, float* __restrict__ Q, int t0, int CH)
{
  int j0 = blockIdx.x * 64, i0 = blockIdx.y * 64;
  __shared__ __align__(16) float As[32][68];
  __shared__ __align__(16) float Bs[32][64];
  int tid = threadIdx.x;
  int tn = tid & 15, tm = tid >> 4;
  int slm = tid >> 2;
  int slc = (tid & 3) * 8;
  int blk = tid >> 3;
  int bln = (tid & 7) * 8;
  double accd[4][4] = {{0.0}};
  int rloc = i0 + slm;
  int bb = rloc / CH, tt = rloc - bb * CH;
  const float* arow = X + ((size_t)bb * NS + t0 + tt) * NH;
  for (int c0 = 0; c0 < NH; c0 += 32){
    float4 a4 = *(const float4*)(arow + c0 + slc);
    float4 a4b = *(const float4*)(arow + c0 + slc + 4);
    As[slc+0][slm] = a4.x;  As[slc+1][slm] = a4.y;
    As[slc+2][slm] = a4.z;  As[slc+3][slm] = a4.w;
    As[slc+4][slm] = a4b.x; As[slc+5][slm] = a4b.y;
    As[slc+6][slm] = a4b.z; As[slc+7][slm] = a4b.w;
    const float* bp = Bw + (size_t)(c0 + blk) * 1536 + j0 + bln;
    float4 b4a = *(const float4*)bp;
    float4 b4b = *(const float4*)(bp + 4);
    *(float4*)&Bs[blk][bln] = b4a;
    *(float4*)&Bs[blk][bln+4] = b4b;
    __syncthreads();
    float acc[4][4] = {{0.f}};
    #pragma unroll 8
    for (int c = 0; c < 32; ++c){
      float4 av = *(const float4*)&As[c][tm*4];
      float4 bv = *(const float4*)&Bs[c][tn*4];
      float a[4] = {av.x, av.y, av.z, av.w};
      float bb2[4] = {bv.x, bv.y, bv.z, bv.w};
      #pragma unroll
      for (int mm = 0; mm < 4; ++mm)
        #pragma unroll
        for (int jj = 0; jj < 4; ++jj)
          acc[mm][jj] += a[mm] * bb2[jj];
    }
    __syncthreads();
    #pragma unroll
    for (int mm = 0; mm < 4; ++mm)
      #pragma unroll
      for (int jj = 0; jj < 4; ++jj) accd[mm][jj] += (double)acc[mm][jj];
  }
  #pragma unroll
  for (int mm = 0; mm < 4; ++mm){
    float4 o; o.x = (float)accd[mm][0]; o.y = (float)accd[mm][1];
    o.z = (float)accd[mm][2]; o.w = (float)accd[mm][3];
    *(float4*)(Q + (size_t)(i0 + tm*4 + mm) * 1536 + j0 + tn*4) = o;
  }
}

// ---------------- fp32 gate chain (sums in double, scalars in fp32) ----------------
__device__ __forceinline__ void gatef(const float* __restrict__ pg, const float* __restrict__ qg,
    float hn, float art_hn, float xn, float art_xn, float* __restrict__ out)
{
  double sp = 0, sq = 0;
  #pragma unroll
  for (int i = 0; i < 6; ++i){ sp += (double)pg[i] * pg[i]; sq += (double)qg[i] * qg[i]; }
  float pn = ncf(wredsumd(sp));
  float qn = ncf(wredsumd(sq));
  float saf = tanhf(pn / hn * art_hn) / pn;
  float sbf = tanhf(qn / xn * art_xn) / qn;
  float a6[6], b6[6]; double sx2 = 0, sy2 = 0, sxy = 0;
  #pragma unroll
  for (int i = 0; i < 6; ++i){
    a6[i] = saf * pg[i]; b6[i] = sbf * qg[i];
    sx2 += (double)a6[i] * a6[i]; sy2 += (double)b6[i] * b6[i]; sxy += (double)a6[i] * b6[i];
  }
  float x2 = (float)wredsumd(sx2);
  float y2 = (float)wredsumd(sy2);
  float xy = (float)wredsumd(sxy);
  float dd = fmaxf(1.f + 2.f * xy + x2 * y2, 1e-15f);
  float fX = (1.f + 2.f * xy + y2) / dd;
  float fY = (1.f - x2) / dd;
  float m6[6]; double smm = 0;
  #pragma unroll
  for (int i = 0; i < 6; ++i){ m6[i] = fX * a6[i] + fY * b6[i]; smm += (double)m6[i] * m6[i]; }
  float nm = ncf(wredsumd(smm));
  float slf = artanhf_(nm) / nm;
  #pragma unroll
  for (int i = 0; i < 6; ++i) out[i] = 1.f / (1.f + expf(-slf * m6[i]));
}

// ================= row-local fused recurrence: 1 row/block x 128 blocks ======================
// GEMM: all 512 threads cover NW cols once (NF h16x8 per cp step); interleaved panel gives
//       16B/lane weight loads (2 k-rows x 4 cols). NL: wv0 c-path+combine; wv1-4 one gate each
//       (wv3 = o-gate + ctx); wv5 x-prefetch (fallback only). Z order identical to round 8.
template<int NW, int QPRE>
__global__ __launch_bounds__(512, 1) void krow(
    const h16* __restrict__ WTI, const float* __restrict__ xin,
    const float* __restrict__ XNF, const float* __restrict__ Qp,
    int CH, int t0, int t1,
    float* __restrict__ ctx, float* __restrict__ HsOut,
    float* __restrict__ HSV, float* __restrict__ CCV, double* __restrict__ SCV)
{
  constexpr int NF = NW / 2048;         // h16x8 per thread per cp: 1 (QPRE) or 2 (fallback)
  constexpr int D = 6;                  // prefetch depth over cp rows (needs <=199, have 200)
  constexpr int WROW = NW * 2;          // h16 per cp row
  const int tid = threadIdx.x;
  const int wv = tid >> 6, ln = tid & 63;
  const int b = blockIdx.x;             // one batch row per block

  __shared__ __align__(16) float Zrow[NW];
  __shared__ float ALd[384][5];         // slots: 0=h, 1=cc, 2=x, 3=zero (pad 5)
  __shared__ float g384[4][384];
  __shared__ float sc[4];               // {hn, cc2, artanh(hn), pad}

  // ---- init / restore state ----
  for (int i = tid; i < 384 * 5; i += 512) ((float*)ALd)[i] = 0.f;
  __syncthreads();
  if (t0 > 0){
    for (int i = tid; i < 384; i += 512){
      ALd[i][0] = HSV[(size_t)b * 384 + i];
      ALd[i][1] = CCV[(size_t)b * 384 + i];
    }
  }
  if (!QPRE){
    for (int i = tid; i < 384; i += 512)
      ALd[i][2] = xin[((size_t)b * NS + t0) * NH + i];
  }
  float cc6[6], hnf = 0.f, cc2f = 0.f;
  if (wv == 0){
    if (t0 == 0){
      #pragma unroll
      for (int i = 0; i < 6; ++i) cc6[i] = 0.f;
      hnf = sqrtf(1e-15f); cc2f = 0.f;
    } else {
      #pragma unroll
      for (int i = 0; i < 6; ++i) cc6[i] = CCV[(size_t)b * 384 + ln + 64 * i];
      hnf = (float)SCV[b * 2]; cc2f = (float)SCV[b * 2 + 1];
    }
    if (ln == 0){ sc[0] = hnf; sc[1] = cc2f; sc[2] = artanhf_(hnf); }
  }
  __syncthreads();

  // column assignment (cols-once)
  const int col0 = tid * (NF * 4);
  int sel;
  if (col0 < 1536) sel = 0;
  else if (col0 < 1920) sel = 1;
  else if (QPRE) sel = 3;
  else if (col0 < 2048) sel = 3;
  else if (col0 < 3584) sel = 2;
  else sel = 3;

  float qreg[6];
  float xr[6];

  for (int t = t0; t < t1; ++t){
    // ---- per-wave row scalars + prefetches (latency hidden under GEMM) ----
    float4 xf = *(const float4*)&XNF[((size_t)b * NS + t) * 4]; // {xn, art_xn, axnt, ts}
    if (QPRE){
      if (wv >= 1 && wv <= 4){
        const float* qp = Qp + ((size_t)b * CH + (t - t0)) * 1536 + (wv - 1) * 384;
        #pragma unroll
        for (int i = 0; i < 6; ++i) qreg[i] = qp[ln + 64 * i];
      }
    } else {
      if (wv == 5 && t + 1 < t1){
        #pragma unroll
        for (int i = 0; i < 6; ++i) xr[i] = xin[((size_t)b * NS + t + 1) * NH + ln + 64 * i];
      }
    }

    // ---- GEMM: cols-once, 1 row; interleaved fp16 panel (16B loads), fp64 flush per 96c ----
    {
      const h16* pt[D];
      #pragma unroll
      for (int d = 0; d < D; ++d) pt[d] = WTI + (size_t)d * WROW + col0 * 2;
      h16x8 wb[D][NF];
      #pragma unroll
      for (int d = 0; d < D; ++d){
        #pragma unroll
        for (int k = 0; k < NF; ++k) wb[d][k] = *(const h16x8*)(pt[d] + 8 * k);
        pt[d] += (size_t)D * WROW;
      }
      double ad[NF * 4];
      #pragma unroll
      for (int k = 0; k < NF * 4; ++k) ad[k] = 0.0;
      for (int g4 = 0; g4 < 192; g4 += 48){      // 48 cp = 96 c per flush group
        f32x2 acc[NF * 2];
        #pragma unroll
        for (int k = 0; k < NF * 2; ++k) acc[k] = f32x2{0.f, 0.f};
        for (int cc = 0; cc < 48; cc += D){
          #pragma unroll
          for (int d = 0; d < D; ++d){
            const int cp = g4 + cc + d;
            float ae = ALd[2 * cp][sel];
            float ao = ALd[2 * cp + 1][sel];
            f32x2 vae = {ae, ae}, vao = {ao, ao};
            #pragma unroll
            for (int k = 0; k < NF; ++k){
              h16x8 w = wb[d][k];
              acc[2 * k + 0] += f32x2{(float)w[0], (float)w[2]} * vae;  // c = 2cp
              acc[2 * k + 1] += f32x2{(float)w[4], (float)w[6]} * vae;
              acc[2 * k + 0] += f32x2{(float)w[1], (float)w[3]} * vao;  // c = 2cp+1
              acc[2 * k + 1] += f32x2{(float)w[5], (float)w[7]} * vao;
            }
            #pragma unroll
            for (int k = 0; k < NF; ++k) wb[d][k] = *(const h16x8*)(pt[d] + 8 * k);
            pt[d] += (size_t)D * WROW;
          }
        }
        #pragma unroll
        for (int k = 0; k < NF * 2; ++k){
          ad[2 * k]     += (double)acc[k].x;
          ad[2 * k + 1] += (double)acc[k].y;
        }
      }
      #pragma unroll
      for (int k = 0; k < NF; ++k){
        float4 o;
        o.x = (float)ad[4 * k + 0]; o.y = (float)ad[4 * k + 1];
        o.z = (float)ad[4 * k + 2]; o.w = (float)ad[4 * k + 3];
        *(float4*)&Zrow[col0 + 4 * k] = o;
      }
    }
    __syncthreads();   // B1: Zrow ready

    // ---- NL (fp32 scalar chain, double reduces) ----
    float hn_s = sc[0];
    float art_hn = sc[2];
    float cadj[6];
    if (wv == 0){
      float tsf = xf.w, axnt = xf.z;
      float cnf = sqrtf(fmaxf(cc2f, 1e-15f));
      float mv6[6]; double s_mv = 0;
      #pragma unroll
      for (int i = 0; i < 6; ++i){
        mv6[i] = Zrow[1536 + ln + 64 * i];
        s_mv += (double)mv6[i] * mv6[i];
      }
      float mvn = ncf(wredsumd(s_mv));
      float s1 = tanhf(mvn / cnf * artanhf_(cnf));
      float c1f = s1 / mvn;
      float m1[6]; double sm1 = 0;
      #pragma unroll
      for (int i = 0; i < 6; ++i){ m1[i] = c1f * mv6[i]; sm1 += (double)m1[i] * m1[i]; }
      float n1 = ncf(wredsumd(sm1));
      float l1f = artanhf_(n1) / n1;
      float v6[6]; double sv = 0;
      #pragma unroll
      for (int i = 0; i < 6; ++i){ v6[i] = tanhf(l1f * m1[i]); sv += (double)v6[i] * v6[i]; }
      float nv = ncf(wredsumd(sv));
      float e1f = tanhf(nv) / nv;
      float cs1[6]; double scs = 0, sccd = 0;
      #pragma unroll
      for (int i = 0; i < 6; ++i){ cs1[i] = e1f * v6[i]; scs += (double)cs1[i] * cs1[i]; sccd -= (double)cs1[i] * cc6[i]; }
      double swx = 0;
      #pragma unroll
      for (int i = 0; i < 6; ++i){ float w = cs1[i] * tsf; swx += (double)w * w; }
      float wxn1 = ncf(wredsumd(swx));
      float s2f = tanhf(wxn1 * axnt) / wxn1 * tsf;
      float cs2[6];
      #pragma unroll
      for (int i = 0; i < 6; ++i) cs2[i] = s2f * cs1[i];
      float x2a = (float)wredsumd(scs);
      float xya = (float)wredsumd(sccd);
      float y2a = cc2f;
      float dA = fmaxf(1.f + 2.f * xya + x2a * y2a, 1e-15f);
      float fXA = (1.f + 2.f * xya + y2a) / dA;
      float fYA = (1.f - x2a) / dA;
      float A6[6]; double sA = 0, sAc = 0, sc2_ = 0;
      #pragma unroll
      for (int i = 0; i < 6; ++i){
        A6[i] = fXA * (-cs1[i]) + fYA * cc6[i];
        sA += (double)A6[i] * A6[i]; sAc += (double)A6[i] * cs2[i]; sc2_ += (double)cs2[i] * cs2[i];
      }
      float x2b = (float)wredsumd(sA);
      float xyb = (float)wredsumd(sAc);
      float y2b = (float)wredsumd(sc2_);
      float dB = fmaxf(1.f + 2.f * xyb + x2b * y2b, 1e-15f);
      float fXB = (1.f + 2.f * xyb + y2b) / dB;
      float fYB = (1.f - x2b) / dB;
      #pragma unroll
      for (int i = 0; i < 6; ++i) cadj[i] = fXB * A6[i] + fYB * cs2[i];
    } else if (wv >= 1 && wv <= 4){
      const int g = wv - 1;
      float pg[6], qg[6], og[6];
      #pragma unroll
      for (int i = 0; i < 6; ++i){
        int r = ln + 64 * i;
        pg[i] = Zrow[g * 384 + r];
        qg[i] = QPRE ? qreg[i] : Zrow[2048 + g * 384 + r];
      }
      gatef(pg, qg, hn_s, art_hn, xf.x, xf.y, og);
      if (g == 2){
        #pragma unroll
        for (int i = 0; i < 6; ++i){
          int r = ln + 64 * i;
          g384[2][r] = og[i];
          ctx[((size_t)b * NS + t) * NH + r] = og[i];   // o-gate is the context
        }
      } else {
        #pragma unroll
        for (int i = 0; i < 6; ++i) g384[g][ln + 64 * i] = og[i];
      }
    }
    __syncthreads();   // B2: gates ready

    if (wv == 0){
      float g0[6], g1[6], g2[6], g3[6];
      #pragma unroll
      for (int i = 0; i < 6; ++i){
        int r = ln + 64 * i;
        g0[i] = g384[0][r]; g1[i] = g384[1][r];
        g2[i] = g384[2][r]; g3[i] = g384[3][r];
      }
      double sct = 0, sict = 0; float wP[6];
      #pragma unroll
      for (int i = 0; i < 6; ++i){ float ct = g3[i]; sct += (double)ct * ct; wP[i] = g1[i] * ct; sict += (double)wP[i] * wP[i]; }
      float ctn = ncf(wredsumd(sct));
      float wPn = ncf(wredsumd(sict));
      float sPf = tanhf(wPn / ctn * artanhf_(ctn)) / wPn;
      float P6[6]; double sPP = 0;
      #pragma unroll
      for (int i = 0; i < 6; ++i){ P6[i] = sPf * wP[i]; sPP += (double)P6[i] * P6[i]; }
      double sca = 0, sfca = 0; float wQ[6];
      #pragma unroll
      for (int i = 0; i < 6; ++i){ sca += (double)cadj[i] * cadj[i]; wQ[i] = g0[i] * cadj[i]; sfca += (double)wQ[i] * wQ[i]; }
      float can = ncf(wredsumd(sca));
      float wQn = ncf(wredsumd(sfca));
      float sQf = tanhf(wQn / can * artanhf_(can)) / wQn;
      float Q6[6]; double sQQ = 0, sPQ = 0;
      #pragma unroll
      for (int i = 0; i < 6; ++i){ Q6[i] = sQf * wQ[i]; sQQ += (double)Q6[i] * Q6[i]; sPQ += (double)P6[i] * Q6[i]; }
      float x2c = (float)wredsumd(sPP);
      float y2c = (float)wredsumd(sQQ);
      float xyc = (float)wredsumd(sPQ);
      float dC = fmaxf(1.f + 2.f * xyc + x2c * y2c, 1e-15f);
      float fXC = (1.f + 2.f * xyc + y2c) / dC;
      float fYC = (1.f - x2c) / dC;
      float ccn6[6], w6[6]; double sw_ = 0;
      #pragma unroll
      for (int i = 0; i < 6; ++i){ ccn6[i] = fXC * P6[i] + fYC * Q6[i]; w6[i] = tanhf(ccn6[i]); sw_ += (double)w6[i] * w6[i]; }
      float nw = ncf(wredsumd(sw_));
      float eef = tanhf(nw) / nw;
      float e6[6], wH[6]; double se = 0, soe = 0;
      #pragma unroll
      for (int i = 0; i < 6; ++i){ e6[i] = eef * w6[i]; se += (double)e6[i] * e6[i]; wH[i] = g2[i] * e6[i]; soe += (double)wH[i] * wH[i]; }
      float en = ncf(wredsumd(se));
      float wHn = ncf(wredsumd(soe));
      float sHf = tanhf(wHn / en * artanhf_(en)) / wHn;
      float hv[6]; double sh2 = 0, scc2 = 0;
      #pragma unroll
      for (int i = 0; i < 6; ++i){
        hv[i] = sHf * wH[i];
        sh2 += (double)hv[i] * hv[i];
        scc2 += (double)ccn6[i] * ccn6[i];
      }
      float hn_next = ncf(wredsumd(sh2));
      float cc2_next = (float)wredsumd(scc2);
      #pragma unroll
      for (int i = 0; i < 6; ++i){
        int r = ln + 64 * i;
        cc6[i] = ccn6[i];
        ALd[r][0] = hv[i];
        ALd[r][1] = ccn6[i];
      }
      hnf = hn_next; cc2f = cc2_next;
      if (ln == 0){ sc[0] = hn_next; sc[1] = cc2_next; sc[2] = artanhf_(hn_next); }
      if (t == t1 - 1){
        #pragma unroll
        for (int i = 0; i < 6; ++i){
          int r = ln + 64 * i;
          HSV[(size_t)b * 384 + r] = hv[i];
          CCV[(size_t)b * 384 + r] = ccn6[i];
        }
        if (ln == 0){ SCV[b * 2] = (double)hn_next; SCV[b * 2 + 1] = (double)cc2_next; }
      }
      if (t == NS - 1){
        #pragma unroll
        for (int i = 0; i < 6; ++i) HsOut[b * NH + ln + 64 * i] = hv[i];
      }
    }
    if (!QPRE && wv == 5 && t + 1 < t1){
      #pragma unroll
      for (int i = 0; i < 6; ++i) ALd[ln + 64 * i][2] = xr[i];
    }
    __syncthreads();   // B3: state ready for next t
  }
}

// ---------------- block reduce helpers ----------------
__device__ __forceinline__ double blocksumd(double v, double* red){
  v = wredsumd(v);
  __syncthreads();
  if ((threadIdx.x & 63) == 0) red[threadIdx.x >> 6] = v;
  __syncthreads();
  return red[0] + red[1] + red[2] + red[3];
}
__device__ __forceinline__ double blockmaxd(double v, double* red){
  #pragma unroll
  for (int off = 32; off; off >>= 1) v = fmax(v, __shfl_xor(v, off, 64));
  __syncthreads();
  if ((threadIdx.x & 63) == 0) red[threadIdx.x >> 6] = v;
  __syncthreads();
  return fmax(fmax(red[0], red[1]), fmax(red[2], red[3]));
}

// ---------------- query / scores / softmax / aw / bt ----------------
__global__ __launch_bounds__(256) void kattn1(const float* __restrict__ Hs,
    const float* __restrict__ Win, const float* __restrict__ ctx,
    const float* __restrict__ dt, const float* __restrict__ ab,
    double* __restrict__ query, double* __restrict__ aw, double* __restrict__ bt)
{
  int b = blockIdx.x; int tid = threadIdx.x;
  __shared__ double hL[NH], qL[NH], scs[NS];
  __shared__ double red[4];
  for (int r = tid; r < NH; r += 256) hL[r] = (double)Hs[b * NH + r];
  __syncthreads();
  for (int r = tid; r < NH; r += 256){
    double s = 0;
    const float* wr = Win + (size_t)r * NH;
    for (int c = 0; c < NH; ++c) s += hL[c] * (double)wr[c];
    qL[r] = s; query[b * NH + r] = s;
  }
  __syncthreads();
  int wv = tid >> 6, ln = tid & 63;
  for (int s_ = wv; s_ < NS; s_ += 4){
    const float* crow = ctx + ((size_t)b * NS + s_) * NH;
    double par = 0;
    #pragma unroll
    for (int i = 0; i < 6; ++i){ int d = ln + 64 * i; par += qL[d] * (double)crow[d]; }
    par = wredsumd(par);
    if (ln == 0) scs[s_] = par;
  }
  __syncthreads();
  double v0 = scs[tid];
  double v1 = (tid + 256 < NS) ? scs[tid + 256] : -1e300;
  double mx = blockmaxd(fmax(v0, v1), red);
  double e0 = exp(v0 - mx);
  double e1 = (tid + 256 < NS) ? exp(v1 - mx) : 0.0;
  double tot = blocksumd(e0 + e1, red);
  double a0 = e0 / tot, a1 = e1 / tot;
  double n = normclip(blocksumd(a0 * a0 + a1 * a1, red));
  double s1 = tanh(n) / n;
  double w0 = s1 * a0, w1 = s1 * a1;
  double pn = normclip(blocksumd(w0 * w0 + w1 * w1, red));
  if (pn > 0.999){ double f = 0.999 / pn; w0 *= f; w1 *= f; }
  aw[b * NS + tid] = w0;
  if (tid + 256 < NS) aw[b * NS + tid + 256] = w1;
  double abv = (double)ab[b];
  double b0 = exp(-abv * (double)dt[b * NS + tid]);
  double b1v = (tid + 256 < NS) ? exp(-abv * (double)dt[b * NS + tid + 256]) : 0.0;
  double nb = normclip(blocksumd(b0 * b0 + b1v * b1v, red));
  double sb = tanh(nb) / nb;
  double c0 = sb * b0, c1 = sb * b1v;
  double pnb = normclip(blocksumd(c0 * c0 + c1 * c1, red));
  if (pnb > 0.999){ double f = 0.999 / pnb; c0 *= f; c1 *= f; }
  bt[b * NS + tid] = c0;
  if (tid + 256 < NS) bt[b * NS + tid + 256] = c1;
}

// ---------------- hyperbolic attention mixing ----------------
__global__ __launch_bounds__(256) void kmix(const float* __restrict__ ctx,
    const double* __restrict__ aw, const double* __restrict__ bt,
    const float* __restrict__ ae, double* __restrict__ nom, double* __restrict__ den)
{
  int b = blockIdx.y; int h0 = blockIdx.x * 32;
  __shared__ float T[32][385];
  int tid = threadIdx.x;
  for (int idx = tid; idx < NS * 32; idx += 256){
    int s = idx >> 5, hh = idx & 31;
    T[hh][s] = ctx[((size_t)b * NS + s) * NH + h0 + hh];
  }
  __syncthreads();
  int wv = tid >> 6, ln = tid & 63;
  double aev = (double)ae[b];
  double aw6[6], bt6[6]; double sbt = 0;
  #pragma unroll
  for (int i = 0; i < 6; ++i){
    aw6[i] = aw[b * NS + ln + 64 * i];
    bt6[i] = bt[b * NS + ln + 64 * i];
    sbt += bt6[i] * bt6[i];
  }
  double xnb = normclip(wredsumd(sbt));
  double art_xnb = artanh_(xnb);
  double denacc = 0.0;
  for (int k = 0; k < 8; ++k){
    int hh = wv * 8 + k;
    double v[6]; double sx = 0;
    #pragma unroll
    for (int i = 0; i < 6; ++i){ v[i] = (double)T[hh][ln + 64 * i]; sx += v[i] * v[i]; }
    double xnv = normclip(wredsumd(sx));
    double wx[6]; double swx = 0;
    #pragma unroll
    for (int i = 0; i < 6; ++i){ wx[i] = aw6[i] * v[i]; swx += wx[i] * wx[i]; }
    double wxn = normclip(wredsumd(swx));
    double s1 = tanh(wxn / xnv * artanh_(xnv)) / wxn;
    double mix[6]; double sm = 0;
    #pragma unroll
    for (int i = 0; i < 6; ++i){ mix[i] = s1 * wx[i]; sm += mix[i] * mix[i]; }
    double n1 = normclip(wredsumd(sm));
    if (n1 > 0.999){ double f = 0.999 / n1;
      #pragma unroll
      for (int i = 0; i < 6; ++i) mix[i] *= f; }
    double sm2 = 0;
    #pragma unroll
    for (int i = 0; i < 6; ++i) sm2 += mix[i] * mix[i];
    double xn2 = normclip(wredsumd(sm2));
    double wx2[6]; double sw2 = 0;
    #pragma unroll
    for (int i = 0; i < 6; ++i){ wx2[i] = aev * mix[i]; sw2 += wx2[i] * wx2[i]; }
    double wxn2 = normclip(wredsumd(sw2));
    double s2 = tanh(wxn2 / xn2 * artanh_(xn2)) / wxn2;
    double tmp[6]; double st = 0;
    #pragma unroll
    for (int i = 0; i < 6; ++i){ tmp[i] = s2 * wx2[i]; st += tmp[i] * tmp[i]; }
    double n2 = normclip(wredsumd(st));
    if (n2 > 0.999){ double f = 0.999 / n2;
      #pragma unroll
      for (int i = 0; i < 6; ++i) tmp[i] *= f; }
    double wx3[6]; double sw3 = 0;
    #pragma unroll
    for (int i = 0; i < 6; ++i){ wx3[i] = tmp[i] * bt6[i]; sw3 += wx3[i] * wx3[i]; }
    double wxn3 = normclip(wredsumd(sw3));
    double s3 = tanh(wxn3 / xnb * art_xnb) / wxn3;
    double t2[6]; double st2 = 0;
    #pragma unroll
    for (int i = 0; i < 6; ++i){ t2[i] = s3 * wx3[i]; st2 += t2[i] * t2[i]; }
    double n3 = normclip(wredsumd(st2));
    if (n3 > 0.999){ double f = 0.999 / n3;
      #pragma unroll
      for (int i = 0; i < 6; ++i) t2[i] *= f; }
    #pragma unroll
    for (int i = 0; i < 6; ++i) t2[i] = fmax(t2[i], 0.0);
    double sxx = 0, syy = 0, sxy = 0;
    #pragma unroll
    for (int i = 0; i < 6; ++i){ sxx += mix[i] * mix[i]; syy += t2[i] * t2[i]; sxy += mix[i] * t2[i]; }
    sxx = wredsumd(sxx); syy = wredsumd(syy); sxy = wredsumd(sxy);
    double dn = fmax(1.0 + 2.0 * sxy + sxx * syy, 1e-15);
    double ca = (1.0 + 2.0 * sxy + syy) / dn, cb = (1.0 - sxx) / dn;
    double m2[6]; double sm3 = 0;
    #pragma unroll
    for (int i = 0; i < 6; ++i){ m2[i] = ca * mix[i] + cb * t2[i]; sm3 += m2[i] * m2[i]; }
    double n4 = normclip(wredsumd(sm3));
    if (n4 > 0.999){ double f = 0.999 / n4;
      #pragma unroll
      for (int i = 0; i < 6; ++i) m2[i] *= f; }
    double snn = 0;
    #pragma unroll
    for (int i = 0; i < 6; ++i) snn += m2[i] * m2[i];
    snn = wredsumd(snn);
    double lam = 2.0 / fmax(1.0 - snn, 1e-15);
    #pragma unroll
    for (int i = 0; i < 6; ++i) atomicAdd(&nom[b * NS + ln + 64 * i], lam * m2[i]);
    if (ln == 0) denacc += lam - 1.0;
  }
  if (ln == 0) atomicAdd(&den[b], denacc);
}

// ---------------- midpoint + logmap0 + output head ----------------
__global__ __launch_bounds__(256) void kfinal(const double* __restrict__ nom,
    const double* __restrict__ den, const double* __restrict__ query,
    const float* __restrict__ Wout, const float* __restrict__ W1,
    const float* __restrict__ b1, const float* __restrict__ W2,
    const float* __restrict__ b2, float* __restrict__ out)
{
  int b = blockIdx.x; int tid = threadIdx.x;
  __shared__ double comb[768];
  __shared__ double att[NH];
  __shared__ double x1[NH];
  __shared__ double red[4];
  double dnb = fmax(den[b], 1e-10);
  double u0 = nom[b * NS + tid] / dnb;
  double u1 = (tid + 256 < NS) ? nom[b * NS + tid + 256] / dnb : 0.0;
  double n = normclip(blocksumd(u0 * u0 + u1 * u1, red));
  double sf = tanh(0.5 * artanh_(n)) / n;
  double f0 = sf * u0, f1 = sf * u1;
  double n2 = normclip(blocksumd(f0 * f0 + f1 * f1, red));
  double sl = artanh_(n2) / n2;
  comb[tid] = sl * f0;
  if (tid + 256 < NS) comb[tid + 256] = sl * f1;
  for (int r = tid; r < NH; r += 256) comb[NH + r] = query[b * NH + r];
  __syncthreads();
  for (int r = tid; r < NH; r += 256){
    double s = 0;
    const float* wr = Wout + (size_t)r * 768;
    for (int c = 0; c < 768; ++c) s += comb[c] * (double)wr[c];
    att[r] = tanh(s);
  }
  __syncthreads();
  for (int r = tid; r < NH; r += 256){
    double s = (double)b1[r];
    const float* wr = W1 + (size_t)r * NH;
    for (int c = 0; c < NH; ++c) s += att[c] * (double)wr[c];
    x1[r] = fmax(s, 0.0);
  }
  __syncthreads();
  double p0 = 0, p1 = 0;
  for (int c = tid; c < NH; c += 256){ p0 += x1[c] * (double)W2[c]; p1 += x1[c] * (double)W2[NH + c]; }
  p0 = blocksumd(p0, red);
  p1 = blocksumd(p1, red);
  if (tid == 0){ out[b * 2 + 0] = (float)(p0 + (double)b2[0]); out[b * 2 + 1] = (float)(p1 + (double)b2[1]); }
}

extern "C" void kernel_launch(void* const* d_in, const int* in_sizes, int n_in,
                              void* d_out, int out_size, void* d_ws, size_t ws_size,
                              hipStream_t stream)
{
  (void)in_sizes; (void)n_in; (void)out_size;
  const float* inputs  = (const float*)d_in[0];
  const float* tstamps = (const float*)d_in[1];
  const float* delta_t = (const float*)d_in[2];
  const float* W_all   = (const float*)d_in[3];
  const float* U_all   = (const float*)d_in[4];
  const float* W_d     = (const float*)d_in[5];
  const float* Win     = (const float*)d_in[6];
  const float* Wout    = (const float*)d_in[7];
  const float* ae      = (const float*)d_in[8];
  const float* ab      = (const float*)d_in[9];
  const float* W1      = (const float*)d_in[10];
  const float* b1      = (const float*)d_in[11];
  const float* W2      = (const float*)d_in[12];
  const float* b2      = (const float*)d_in[13];
  float* out = (float*)d_out;

  // double region
  double* wd = (double*)d_ws;
  size_t od = 0;
  double* NOMD  = wd + od; od += (size_t)NB * NS;
  double* DEND  = wd + od; od += (size_t)NB;
  double* QUERY = wd + od; od += (size_t)NB * NH;
  double* AW    = wd + od; od += (size_t)NB * NS;
  double* BT    = wd + od; od += (size_t)NB * NS;
  double* SCV   = wd + od; od += (size_t)NB * 2;
  // float region
  float* wf = (float*)(wd + od);
  size_t of = 0;
  h16* WTI    = (h16*)(wf + of); of += (size_t)200 * 8192 / 2;  // interleaved fp16 panel (max)
  float* UT   = wf + of; of += (size_t)384 * 1536;
  float* CTX  = wf + of; of += (size_t)NB * NS * NH;
  float* HS   = wf + of; of += (size_t)NB * NH;
  float* HSV  = wf + of; of += (size_t)NB * NH;        // chunk-boundary h state
  float* CCV  = wf + of; of += (size_t)NB * NH;        // chunk-boundary cc state
  float* XNF  = wf + of; of += (size_t)NB * NS * 4;    // {xn, art_xn, axnt, ts}
  float* Qp   = wf + of;                               // Qp chunk buffer (sized by CH)

  size_t base_bytes = od * 8 + of * 4;

  // pick the largest time-chunk whose Qp buffer fits the workspace
  int CH = 0;
  const int chs[7] = {384, 192, 96, 48, 24, 12, 6};
  for (int ci = 0; ci < 7; ++ci){
    size_t need = base_bytes + (size_t)NB * chs[ci] * 1536 * 4;
    if (ws_size >= need){ CH = chs[ci]; break; }
  }

  // zero midpoint accumulators + per-(b,t) scalar precompute
  int nzd = NB * NS + NB;
  hipLaunchKernelGGL(kzerod, dim3((nzd + 255) / 256), dim3(256), 0, stream, NOMD, nzd);
  hipLaunchKernelGGL(kxn, dim3(768), dim3(256), 0, stream, inputs, tstamps, XNF);

  if (CH > 0){
    // interleaved fp16 panel, 1920 useful cols (1.6 MB, L2-resident per XCD)
    int nWI = 200 * 2048 * 2;
    hipLaunchKernelGGL(kprepWI, dim3((nWI + 255) / 256), dim3(256), 0, stream,
                       W_all, W_d, U_all, WTI, 2048);
    hipLaunchKernelGGL(kprepU, dim3((384 * 1536 + 255) / 256), dim3(256), 0, stream, U_all, UT);
    for (int t0 = 0; t0 < NS; t0 += CH){
      hipLaunchKernelGGL(kqgemmc, dim3(24, 2 * CH), dim3(256), 0, stream,
                         inputs, UT, Qp, t0, CH);
      hipLaunchKernelGGL(HIP_KERNEL_NAME(krow<2048, 1>), dim3(128), dim3(512), 0, stream,
                         WTI, inputs, XNF, Qp, CH, t0, t0 + CH,
                         CTX, HS, HSV, CCV, SCV);
    }
  } else {
    // workspace too small even for CH=6: single-launch fallback (U columns in-panel)
    int nWI = 200 * 4096 * 2;
    hipLaunchKernelGGL(kprepWI, dim3((nWI + 255) / 256), dim3(256), 0, stream,
                       W_all, W_d, U_all, WTI, 4096);
    hipLaunchKernelGGL(HIP_KERNEL_NAME(krow<4096, 0>), dim3(128), dim3(512), 0, stream,
                       WTI, inputs, XNF, Qp /*unused*/, 1, 0, NS,
                       CTX, HS, HSV, CCV, SCV);
  }

  hipLaunchKernelGGL(kattn1, dim3(128), dim3(256), 0, stream,
                     HS, Win, CTX, delta_t, ab, QUERY, AW, BT);
  hipLaunchKernelGGL(kmix, dim3(12, 128), dim3(256), 0, stream, CTX, AW, BT, ae, NOMD, DEND);
  hipLaunchKernelGGL(kfinal, dim3(128), dim3(256), 0, stream,
                     NOMD, DEND, QUERY, Wout, W1, b1, W2, b2, out);
}

// Round 10
// 8701.735 us; speedup vs baseline: 8.4587x; 1.1448x over previous
//
#include <hip/hip_runtime.h>
#include <cmath>

constexpr int NB = 128;     // batch
constexpr int NS = 384;     // seq len
constexpr int NH = 384;     // hidden = input dim

typedef __attribute__((ext_vector_type(2))) float f32x2;
typedef _Float16 h16;
typedef __attribute__((ext_vector_type(2))) _Float16 h16x2;
typedef __attribute__((ext_vector_type(8))) _Float16 h16x8;

__device__ __forceinline__ double clampd(double x, double lo, double hi){ return fmin(fmax(x,lo),hi); }
__device__ __forceinline__ double artanh_(double x){ return atanh(clampd(x, -1.0 + 1e-7, 1.0 - 1e-7)); }
__device__ __forceinline__ double normclip(double s){ return sqrt(fmax(s, 1e-15)); }
__device__ __forceinline__ float clampf_(float x, float lo, float hi){ return fminf(fmaxf(x,lo),hi); }
__device__ __forceinline__ float artanhf_(float x){ return atanhf(clampf_(x, -1.f + 1e-7f, 1.f - 1e-7f)); }
__device__ __forceinline__ double wredsumd(double v){
  #pragma unroll
  for (int off = 32; off; off >>= 1) v += __shfl_xor(v, off, 64);
  return v;
}
// norm from a double sum, fp32 result
__device__ __forceinline__ float ncf(double s){ return sqrtf(fmaxf((float)s, 1e-15f)); }

// ---------------- zero ----------------
__global__ void kzerod(double* p, int n){
  int i = blockIdx.x * 256 + threadIdx.x;
  if (i < n) p[i] = 0.0;
}

// ---------------- weight pack (fp16, k-pair interleaved) ----------------
// WTI[cp][j*2 + (c&1)], c = 2*cp+(jj&1); 200 cp rows (>=198 needed for D=6 prefetch).
// j<1536: gate W (4 gates x 384); [1536,1920): W_d; [2048,3584) (NW=4096 only): U gates; else 0.
__global__ void kprepWI(const float* __restrict__ W_all, const float* __restrict__ W_d,
                        const float* __restrict__ U_all, h16* __restrict__ WTI, int NW)
{
  int i = blockIdx.x * 256 + threadIdx.x;
  int wrow = NW * 2;
  int total = 200 * wrow;
  if (i >= total) return;
  int cp = i / wrow, jj = i - cp * wrow;
  int j = jj >> 1, par = jj & 1;
  int c = cp * 2 + par;
  float v = 0.f;
  if (c < 384){
    if (j < 1536){ int g = j / 384, r = j % 384; v = W_all[r * 1536 + g * 384 + c]; }
    else if (j < 1920){ int r = j - 1536; v = W_d[r * 384 + c]; }
    else if (NW == 4096 && j >= 2048 && j < 3584){
      int jg = j - 2048; int g = jg / 384, r = jg % 384; v = U_all[(g * 384 + r) * 384 + c];
    }
  }
  WTI[i] = (h16)v;
}

// UT[c][jj] = U_g[r][c], stride 1536 (for the Qp precompute GEMM)
__global__ void kprepU(const float* __restrict__ U_all, float* __restrict__ UT)
{
  int i = blockIdx.x * 256 + threadIdx.x;
  if (i >= 384 * 1536) return;
  int c = i / 1536, jj = i % 1536;
  int g = jj / 384, r = jj % 384;
  UT[i] = U_all[(g * 384 + r) * 384 + c];
}

// ---------------- per-(b,t) scalar precompute (double math, fp32 storage) ----------------
// XNF[idx] = {xn, artanh(xn), artanh(xnt)/xnt, ts}
__global__ void kxn(const float* __restrict__ xin, const float* __restrict__ tst,
                    float* __restrict__ XNF)
{
  int w = (blockIdx.x * 256 + threadIdx.x) >> 6;
  int ln = threadIdx.x & 63;
  int nw = (gridDim.x * 256) >> 6;
  for (int idx = w; idx < NB * NS; idx += nw){
    double s = 0;
    #pragma unroll
    for (int i = 0; i < 6; ++i){
      float v = xin[(size_t)idx * NH + ln + 64 * i];
      s += (double)v * v;
    }
    s = wredsumd(s);
    if (ln == 0){
      double xn = normclip(s);
      double ts = (double)tst[idx];
      double xnt = sqrt(fmax(384.0 * ts * ts, 1e-15));
      float4 o;
      o.x = (float)xn;
      o.y = (float)artanh_(xn);
      o.z = (float)(artanh_(xnt) / xnt);
      o.w = (float)ts;
      *(float4*)&XNF[(size_t)idx * 4] = o;
    }
  }
}

// ---------------- chunked Q GEMM: Q[rloc][jj] = sum_c X[b(rloc)][t0+tt(rloc)][c] * UT[c][jj] ----
__global__ __launch_bounds__(256) void kqgemmc(const float* __restrict__ X,
    const float* __restrict__ Bw, float* __restrict__ Q, int t0, int CH)
{
  int j0 = blockIdx.x * 64, i0 = blockIdx.y * 64;
  __shared__ __align__(16) float As[32][68];
  __shared__ __align__(16) float Bs[32][64];
  int tid = threadIdx.x;
  int tn = tid & 15, tm = tid >> 4;
  int slm = tid >> 2;
  int slc = (tid & 3) * 8;
  int blk = tid >> 3;
  int bln = (tid & 7) * 8;
  double accd[4][4] = {{0.0}};
  int rloc = i0 + slm;
  int bb = rloc / CH, tt = rloc - bb * CH;
  const float* arow = X + ((size_t)bb * NS + t0 + tt) * NH;
  for (int c0 = 0; c0 < NH; c0 += 32){
    float4 a4 = *(const float4*)(arow + c0 + slc);
    float4 a4b = *(const float4*)(arow + c0 + slc + 4);
    As[slc+0][slm] = a4.x;  As[slc+1][slm] = a4.y;
    As[slc+2][slm] = a4.z;  As[slc+3][slm] = a4.w;
    As[slc+4][slm] = a4b.x; As[slc+5][slm] = a4b.y;
    As[slc+6][slm] = a4b.z; As[slc+7][slm] = a4b.w;
    const float* bp = Bw + (size_t)(c0 + blk) * 1536 + j0 + bln;
    float4 b4a = *(const float4*)bp;
    float4 b4b = *(const float4*)(bp + 4);
    *(float4*)&Bs[blk][bln] = b4a;
    *(float4*)&Bs[blk][bln+4] = b4b;
    __syncthreads();
    float acc[4][4] = {{0.f}};
    #pragma unroll 8
    for (int c = 0; c < 32; ++c){
      float4 av = *(const float4*)&As[c][tm*4];
      float4 bv = *(const float4*)&Bs[c][tn*4];
      float a[4] = {av.x, av.y, av.z, av.w};
      float bb2[4] = {bv.x, bv.y, bv.z, bv.w};
      #pragma unroll
      for (int mm = 0; mm < 4; ++mm)
        #pragma unroll
        for (int jj = 0; jj < 4; ++jj)
          acc[mm][jj] += a[mm] * bb2[jj];
    }
    __syncthreads();
    #pragma unroll
    for (int mm = 0; mm < 4; ++mm)
      #pragma unroll
      for (int jj = 0; jj < 4; ++jj) accd[mm][jj] += (double)acc[mm][jj];
  }
  #pragma unroll
  for (int mm = 0; mm < 4; ++mm){
    float4 o; o.x = (float)accd[mm][0]; o.y = (float)accd[mm][1];
    o.z = (float)accd[mm][2]; o.w = (float)accd[mm][3];
    *(float4*)(Q + (size_t)(i0 + tm*4 + mm) * 1536 + j0 + tn*4) = o;
  }
}

// ---------------- fp32 gate chain (sums in double, scalars in fp32) ----------------
__device__ __forceinline__ void gatef(const float* __restrict__ pg, const float* __restrict__ qg,
    float hn, float art_hn, float xn, float art_xn, float* __restrict__ out)
{
  double sp = 0, sq = 0;
  #pragma unroll
  for (int i = 0; i < 6; ++i){ sp += (double)pg[i] * pg[i]; sq += (double)qg[i] * qg[i]; }
  float pn = ncf(wredsumd(sp));
  float qn = ncf(wredsumd(sq));
  float saf = tanhf(pn / hn * art_hn) / pn;
  float sbf = tanhf(qn / xn * art_xn) / qn;
  float a6[6], b6[6]; double sx2 = 0, sy2 = 0, sxy = 0;
  #pragma unroll
  for (int i = 0; i < 6; ++i){
    a6[i] = saf * pg[i]; b6[i] = sbf * qg[i];
    sx2 += (double)a6[i] * a6[i]; sy2 += (double)b6[i] * b6[i]; sxy += (double)a6[i] * b6[i];
  }
  float x2 = (float)wredsumd(sx2);
  float y2 = (float)wredsumd(sy2);
  float xy = (float)wredsumd(sxy);
  float dd = fmaxf(1.f + 2.f * xy + x2 * y2, 1e-15f);
  float fX = (1.f + 2.f * xy + y2) / dd;
  float fY = (1.f - x2) / dd;
  float m6[6]; double smm = 0;
  #pragma unroll
  for (int i = 0; i < 6; ++i){ m6[i] = fX * a6[i] + fY * b6[i]; smm += (double)m6[i] * m6[i]; }
  float nm = ncf(wredsumd(smm));
  float slf = artanhf_(nm) / nm;
  #pragma unroll
  for (int i = 0; i < 6; ++i) out[i] = 1.f / (1.f + expf(-slf * m6[i]));
}

// ================= row-local fused recurrence: 1 row/block x 128 blocks ======================
// GEMM: all 512 threads cover NW cols once; interleaved fp16 panel (16B loads) feeds
//       v_dot2_f32_f16 directly (no cvts); A operands (h/cc/x) stored fp16 in LDS, one
//       ds_read_b32 per k-pair (half the LDS traffic of round 9). fp64 flush per 96 c.
// NL: wv0 c-path+combine; wv1-4 one gate each (wv3 = o-gate + ctx); wv5 x-prefetch (fallback).
template<int NW, int QPRE>
__global__ __launch_bounds__(512, 1) void krow(
    const h16* __restrict__ WTI, const float* __restrict__ xin,
    const float* __restrict__ XNF, const float* __restrict__ Qp,
    int CH, int t0, int t1,
    float* __restrict__ ctx, float* __restrict__ HsOut,
    float* __restrict__ HSV, float* __restrict__ CCV, double* __restrict__ SCV)
{
  constexpr int NF = NW / 2048;         // h16x8 per thread per cp: 1 (QPRE) or 2 (fallback)
  constexpr int D = 6;                  // prefetch depth over cp rows (max cp touched 197 < 200)
  constexpr int WROW = NW * 2;          // h16 per cp row
  const int tid = threadIdx.x;
  const int wv = tid >> 6, ln = tid & 63;
  const int b = blockIdx.x;             // one batch row per block

  __shared__ __align__(16) float Zrow[NW];
  __shared__ __align__(8) h16 ALh[4][400];   // [slot][c]: 0=h, 1=cc, 2=x, 3=zero
  __shared__ float g384[4][384];
  __shared__ float sc[4];               // {hn, cc2, artanh(hn), pad}

  // ---- init / restore state ----
  for (int i = tid; i < 800; i += 512) ((unsigned*)ALh)[i] = 0u;
  __syncthreads();
  if (t0 > 0){
    for (int i = tid; i < 384; i += 512){
      ALh[0][i] = (h16)HSV[(size_t)b * 384 + i];
      ALh[1][i] = (h16)CCV[(size_t)b * 384 + i];
    }
  }
  if (!QPRE){
    for (int i = tid; i < 384; i += 512)
      ALh[2][i] = (h16)xin[((size_t)b * NS + t0) * NH + i];
  }
  float cc6[6], hnf = 0.f, cc2f = 0.f;
  if (wv == 0){
    if (t0 == 0){
      #pragma unroll
      for (int i = 0; i < 6; ++i) cc6[i] = 0.f;
      hnf = sqrtf(1e-15f); cc2f = 0.f;
    } else {
      #pragma unroll
      for (int i = 0; i < 6; ++i) cc6[i] = CCV[(size_t)b * 384 + ln + 64 * i];
      hnf = (float)SCV[b * 2]; cc2f = (float)SCV[b * 2 + 1];
    }
    if (ln == 0){ sc[0] = hnf; sc[1] = cc2f; sc[2] = artanhf_(hnf); }
  }
  __syncthreads();

  // column assignment (cols-once)
  const int col0 = tid * (NF * 4);
  int sel;
  if (col0 < 1536) sel = 0;
  else if (col0 < 1920) sel = 1;
  else if (QPRE) sel = 3;
  else if (col0 < 2048) sel = 3;
  else if (col0 < 3584) sel = 2;
  else sel = 3;

  float qreg[6];
  float xr[6];

  for (int t = t0; t < t1; ++t){
    // ---- per-wave row scalars + prefetches (latency hidden under GEMM) ----
    float4 xf = *(const float4*)&XNF[((size_t)b * NS + t) * 4]; // {xn, art_xn, axnt, ts}
    if (QPRE){
      if (wv >= 1 && wv <= 4){
        const float* qp = Qp + ((size_t)b * CH + (t - t0)) * 1536 + (wv - 1) * 384;
        #pragma unroll
        for (int i = 0; i < 6; ++i) qreg[i] = qp[ln + 64 * i];
      }
    } else {
      if (wv == 5 && t + 1 < t1){
        #pragma unroll
        for (int i = 0; i < 6; ++i) xr[i] = xin[((size_t)b * NS + t + 1) * NH + ln + 64 * i];
      }
    }

    // ---- GEMM: cols-once, 1 row; fp16 panel + fp16 A via v_dot2_f32_f16 ----
    {
      const h16* pt[D];
      #pragma unroll
      for (int d = 0; d < D; ++d) pt[d] = WTI + (size_t)d * WROW + col0 * 2;
      h16x8 wb[D][NF];
      #pragma unroll
      for (int d = 0; d < D; ++d){
        #pragma unroll
        for (int k = 0; k < NF; ++k) wb[d][k] = *(const h16x8*)(pt[d] + 8 * k);
        pt[d] += (size_t)D * WROW;
      }
      double ad[NF * 4];
      #pragma unroll
      for (int k = 0; k < NF * 4; ++k) ad[k] = 0.0;
      for (int g4 = 0; g4 < 192; g4 += 48){      // 48 cp = 96 c per flush group
        float acc[NF * 4];
        #pragma unroll
        for (int k = 0; k < NF * 4; ++k) acc[k] = 0.f;
        for (int cc = 0; cc < 48; cc += D){
          #pragma unroll
          for (int d = 0; d < D; ++d){
            const int cp = g4 + cc + d;
            h16x2 ap = *(const h16x2*)&ALh[sel][2 * cp];
            #pragma unroll
            for (int k = 0; k < NF; ++k){
              h16x8 w = wb[d][k];
              h16x2 w0 = {w[0], w[1]}, w1 = {w[2], w[3]};
              h16x2 w2 = {w[4], w[5]}, w3 = {w[6], w[7]};
              acc[4*k+0] = __builtin_amdgcn_fdot2(w0, ap, acc[4*k+0], false);
              acc[4*k+1] = __builtin_amdgcn_fdot2(w1, ap, acc[4*k+1], false);
              acc[4*k+2] = __builtin_amdgcn_fdot2(w2, ap, acc[4*k+2], false);
              acc[4*k+3] = __builtin_amdgcn_fdot2(w3, ap, acc[4*k+3], false);
            }
            #pragma unroll
            for (int k = 0; k < NF; ++k) wb[d][k] = *(const h16x8*)(pt[d] + 8 * k);
            pt[d] += (size_t)D * WROW;
          }
        }
        #pragma unroll
        for (int k = 0; k < NF * 4; ++k) ad[k] += (double)acc[k];
      }
      #pragma unroll
      for (int k = 0; k < NF; ++k){
        float4 o;
        o.x = (float)ad[4 * k + 0]; o.y = (float)ad[4 * k + 1];
        o.z = (float)ad[4 * k + 2]; o.w = (float)ad[4 * k + 3];
        *(float4*)&Zrow[col0 + 4 * k] = o;
      }
    }
    __syncthreads();   // B1: Zrow ready

    // ---- NL (fp32 scalar chain, double reduces) ----
    float hn_s = sc[0];
    float art_hn = sc[2];
    float cadj[6];
    if (wv == 0){
      float tsf = xf.w, axnt = xf.z;
      float cnf = sqrtf(fmaxf(cc2f, 1e-15f));
      float mv6[6]; double s_mv = 0;
      #pragma unroll
      for (int i = 0; i < 6; ++i){
        mv6[i] = Zrow[1536 + ln + 64 * i];
        s_mv += (double)mv6[i] * mv6[i];
      }
      float mvn = ncf(wredsumd(s_mv));
      float s1 = tanhf(mvn / cnf * artanhf_(cnf));
      float c1f = s1 / mvn;
      float m1[6]; double sm1 = 0;
      #pragma unroll
      for (int i = 0; i < 6; ++i){ m1[i] = c1f * mv6[i]; sm1 += (double)m1[i] * m1[i]; }
      float n1 = ncf(wredsumd(sm1));
      float l1f = artanhf_(n1) / n1;
      float v6[6]; double sv = 0;
      #pragma unroll
      for (int i = 0; i < 6; ++i){ v6[i] = tanhf(l1f * m1[i]); sv += (double)v6[i] * v6[i]; }
      float nv = ncf(wredsumd(sv));
      float e1f = tanhf(nv) / nv;
      float cs1[6]; double scs = 0, sccd = 0;
      #pragma unroll
      for (int i = 0; i < 6; ++i){ cs1[i] = e1f * v6[i]; scs += (double)cs1[i] * cs1[i]; sccd -= (double)cs1[i] * cc6[i]; }
      double swx = 0;
      #pragma unroll
      for (int i = 0; i < 6; ++i){ float w = cs1[i] * tsf; swx += (double)w * w; }
      float wxn1 = ncf(wredsumd(swx));
      float s2f = tanhf(wxn1 * axnt) / wxn1 * tsf;
      float cs2[6];
      #pragma unroll
      for (int i = 0; i < 6; ++i) cs2[i] = s2f * cs1[i];
      float x2a = (float)wredsumd(scs);
      float xya = (float)wredsumd(sccd);
      float y2a = cc2f;
      float dA = fmaxf(1.f + 2.f * xya + x2a * y2a, 1e-15f);
      float fXA = (1.f + 2.f * xya + y2a) / dA;
      float fYA = (1.f - x2a) / dA;
      float A6[6]; double sA = 0, sAc = 0, sc2_ = 0;
      #pragma unroll
      for (int i = 0; i < 6; ++i){
        A6[i] = fXA * (-cs1[i]) + fYA * cc6[i];
        sA += (double)A6[i] * A6[i]; sAc += (double)A6[i] * cs2[i]; sc2_ += (double)cs2[i] * cs2[i];
      }
      float x2b = (float)wredsumd(sA);
      float xyb = (float)wredsumd(sAc);
      float y2b = (float)wredsumd(sc2_);
      float dB = fmaxf(1.f + 2.f * xyb + x2b * y2b, 1e-15f);
      float fXB = (1.f + 2.f * xyb + y2b) / dB;
      float fYB = (1.f - x2b) / dB;
      #pragma unroll
      for (int i = 0; i < 6; ++i) cadj[i] = fXB * A6[i] + fYB * cs2[i];
    } else if (wv >= 1 && wv <= 4){
      const int g = wv - 1;
      float pg[6], qg[6], og[6];
      #pragma unroll
      for (int i = 0; i < 6; ++i){
        int r = ln + 64 * i;
        pg[i] = Zrow[g * 384 + r];
        qg[i] = QPRE ? qreg[i] : Zrow[2048 + g * 384 + r];
      }
      gatef(pg, qg, hn_s, art_hn, xf.x, xf.y, og);
      if (g == 2){
        #pragma unroll
        for (int i = 0; i < 6; ++i){
          int r = ln + 64 * i;
          g384[2][r] = og[i];
          ctx[((size_t)b * NS + t) * NH + r] = og[i];   // o-gate is the context
        }
      } else {
        #pragma unroll
        for (int i = 0; i < 6; ++i) g384[g][ln + 64 * i] = og[i];
      }
    }
    __syncthreads();   // B2: gates ready

    if (wv == 0){
      float g0[6], g1[6], g2[6], g3[6];
      #pragma unroll
      for (int i = 0; i < 6; ++i){
        int r = ln + 64 * i;
        g0[i] = g384[0][r]; g1[i] = g384[1][r];
        g2[i] = g384[2][r]; g3[i] = g384[3][r];
      }
      double sct = 0, sict = 0; float wP[6];
      #pragma unroll
      for (int i = 0; i < 6; ++i){ float ct = g3[i]; sct += (double)ct * ct; wP[i] = g1[i] * ct; sict += (double)wP[i] * wP[i]; }
      float ctn = ncf(wredsumd(sct));
      float wPn = ncf(wredsumd(sict));
      float sPf = tanhf(wPn / ctn * artanhf_(ctn)) / wPn;
      float P6[6]; double sPP = 0;
      #pragma unroll
      for (int i = 0; i < 6; ++i){ P6[i] = sPf * wP[i]; sPP += (double)P6[i] * P6[i]; }
      double sca = 0, sfca = 0; float wQ[6];
      #pragma unroll
      for (int i = 0; i < 6; ++i){ sca += (double)cadj[i] * cadj[i]; wQ[i] = g0[i] * cadj[i]; sfca += (double)wQ[i] * wQ[i]; }
      float can = ncf(wredsumd(sca));
      float wQn = ncf(wredsumd(sfca));
      float sQf = tanhf(wQn / can * artanhf_(can)) / wQn;
      float Q6[6]; double sQQ = 0, sPQ = 0;
      #pragma unroll
      for (int i = 0; i < 6; ++i){ Q6[i] = sQf * wQ[i]; sQQ += (double)Q6[i] * Q6[i]; sPQ += (double)P6[i] * Q6[i]; }
      float x2c = (float)wredsumd(sPP);
      float y2c = (float)wredsumd(sQQ);
      float xyc = (float)wredsumd(sPQ);
      float dC = fmaxf(1.f + 2.f * xyc + x2c * y2c, 1e-15f);
      float fXC = (1.f + 2.f * xyc + y2c) / dC;
      float fYC = (1.f - x2c) / dC;
      float ccn6[6], w6[6]; double sw_ = 0;
      #pragma unroll
      for (int i = 0; i < 6; ++i){ ccn6[i] = fXC * P6[i] + fYC * Q6[i]; w6[i] = tanhf(ccn6[i]); sw_ += (double)w6[i] * w6[i]; }
      float nw = ncf(wredsumd(sw_));
      float eef = tanhf(nw) / nw;
      float e6[6], wH[6]; double se = 0, soe = 0;
      #pragma unroll
      for (int i = 0; i < 6; ++i){ e6[i] = eef * w6[i]; se += (double)e6[i] * e6[i]; wH[i] = g2[i] * e6[i]; soe += (double)wH[i] * wH[i]; }
      float en = ncf(wredsumd(se));
      float wHn = ncf(wredsumd(soe));
      float sHf = tanhf(wHn / en * artanhf_(en)) / wHn;
      float hv[6]; double sh2 = 0, scc2 = 0;
      #pragma unroll
      for (int i = 0; i < 6; ++i){
        hv[i] = sHf * wH[i];
        sh2 += (double)hv[i] * hv[i];
        scc2 += (double)ccn6[i] * ccn6[i];
      }
      float hn_next = ncf(wredsumd(sh2));
      float cc2_next = (float)wredsumd(scc2);
      #pragma unroll
      for (int i = 0; i < 6; ++i){
        int r = ln + 64 * i;
        cc6[i] = ccn6[i];
        ALh[0][r] = (h16)hv[i];
        ALh[1][r] = (h16)ccn6[i];
      }
      hnf = hn_next; cc2f = cc2_next;
      if (ln == 0){ sc[0] = hn_next; sc[1] = cc2_next; sc[2] = artanhf_(hn_next); }
      if (t == t1 - 1){
        #pragma unroll
        for (int i = 0; i < 6; ++i){
          int r = ln + 64 * i;
          HSV[(size_t)b * 384 + r] = hv[i];
          CCV[(size_t)b * 384 + r] = ccn6[i];
        }
        if (ln == 0){ SCV[b * 2] = (double)hn_next; SCV[b * 2 + 1] = (double)cc2_next; }
      }
      if (t == NS - 1){
        #pragma unroll
        for (int i = 0; i < 6; ++i) HsOut[b * NH + ln + 64 * i] = hv[i];
      }
    }
    if (!QPRE && wv == 5 && t + 1 < t1){
      #pragma unroll
      for (int i = 0; i < 6; ++i) ALh[2][ln + 64 * i] = (h16)xr[i];
    }
    __syncthreads();   // B3: state ready for next t
  }
}

// ---------------- block reduce helpers ----------------
__device__ __forceinline__ double blocksumd(double v, double* red){
  v = wredsumd(v);
  __syncthreads();
  if ((threadIdx.x & 63) == 0) red[threadIdx.x >> 6] = v;
  __syncthreads();
  return red[0] + red[1] + red[2] + red[3];
}
__device__ __forceinline__ double blockmaxd(double v, double* red){
  #pragma unroll
  for (int off = 32; off; off >>= 1) v = fmax(v, __shfl_xor(v, off, 64));
  __syncthreads();
  if ((threadIdx.x & 63) == 0) red[threadIdx.x >> 6] = v;
  __syncthreads();
  return fmax(fmax(red[0], red[1]), fmax(red[2], red[3]));
}

// ---------------- query / scores / softmax / aw / bt ----------------
__global__ __launch_bounds__(256) void kattn1(const float* __restrict__ Hs,
    const float* __restrict__ Win, const float* __restrict__ ctx,
    const float* __restrict__ dt, const float* __restrict__ ab,
    double* __restrict__ query, double* __restrict__ aw, double* __restrict__ bt)
{
  int b = blockIdx.x; int tid = threadIdx.x;
  __shared__ double hL[NH], qL[NH], scs[NS];
  __shared__ double red[4];
  for (int r = tid; r < NH; r += 256) hL[r] = (double)Hs[b * NH + r];
  __syncthreads();
  for (int r = tid; r < NH; r += 256){
    double s = 0;
    const float* wr = Win + (size_t)r * NH;
    for (int c = 0; c < NH; ++c) s += hL[c] * (double)wr[c];
    qL[r] = s; query[b * NH + r] = s;
  }
  __syncthreads();
  int wv = tid >> 6, ln = tid & 63;
  for (int s_ = wv; s_ < NS; s_ += 4){
    const float* crow = ctx + ((size_t)b * NS + s_) * NH;
    double par = 0;
    #pragma unroll
    for (int i = 0; i < 6; ++i){ int d = ln + 64 * i; par += qL[d] * (double)crow[d]; }
    par = wredsumd(par);
    if (ln == 0) scs[s_] = par;
  }
  __syncthreads();
  double v0 = scs[tid];
  double v1 = (tid + 256 < NS) ? scs[tid + 256] : -1e300;
  double mx = blockmaxd(fmax(v0, v1), red);
  double e0 = exp(v0 - mx);
  double e1 = (tid + 256 < NS) ? exp(v1 - mx) : 0.0;
  double tot = blocksumd(e0 + e1, red);
  double a0 = e0 / tot, a1 = e1 / tot;
  double n = normclip(blocksumd(a0 * a0 + a1 * a1, red));
  double s1 = tanh(n) / n;
  double w0 = s1 * a0, w1 = s1 * a1;
  double pn = normclip(blocksumd(w0 * w0 + w1 * w1, red));
  if (pn > 0.999){ double f = 0.999 / pn; w0 *= f; w1 *= f; }
  aw[b * NS + tid] = w0;
  if (tid + 256 < NS) aw[b * NS + tid + 256] = w1;
  double abv = (double)ab[b];
  double b0 = exp(-abv * (double)dt[b * NS + tid]);
  double b1v = (tid + 256 < NS) ? exp(-abv * (double)dt[b * NS + tid + 256]) : 0.0;
  double nb = normclip(blocksumd(b0 * b0 + b1v * b1v, red));
  double sb = tanh(nb) / nb;
  double c0 = sb * b0, c1 = sb * b1v;
  double pnb = normclip(blocksumd(c0 * c0 + c1 * c1, red));
  if (pnb > 0.999){ double f = 0.999 / pnb; c0 *= f; c1 *= f; }
  bt[b * NS + tid] = c0;
  if (tid + 256 < NS) bt[b * NS + tid + 256] = c1;
}

// ---------------- hyperbolic attention mixing ----------------
__global__ __launch_bounds__(256) void kmix(const float* __restrict__ ctx,
    const double* __restrict__ aw, const double* __restrict__ bt,
    const float* __restrict__ ae, double* __restrict__ nom, double* __restrict__ den)
{
  int b = blockIdx.y; int h0 = blockIdx.x * 32;
  __shared__ float T[32][385];
  int tid = threadIdx.x;
  for (int idx = tid; idx < NS * 32; idx += 256){
    int s = idx >> 5, hh = idx & 31;
    T[hh][s] = ctx[((size_t)b * NS + s) * NH + h0 + hh];
  }
  __syncthreads();
  int wv = tid >> 6, ln = tid & 63;
  double aev = (double)ae[b];
  double aw6[6], bt6[6]; double sbt = 0;
  #pragma unroll
  for (int i = 0; i < 6; ++i){
    aw6[i] = aw[b * NS + ln + 64 * i];
    bt6[i] = bt[b * NS + ln + 64 * i];
    sbt += bt6[i] * bt6[i];
  }
  double xnb = normclip(wredsumd(sbt));
  double art_xnb = artanh_(xnb);
  double denacc = 0.0;
  for (int k = 0; k < 8; ++k){
    int hh = wv * 8 + k;
    double v[6]; double sx = 0;
    #pragma unroll
    for (int i = 0; i < 6; ++i){ v[i] = (double)T[hh][ln + 64 * i]; sx += v[i] * v[i]; }
    double xnv = normclip(wredsumd(sx));
    double wx[6]; double swx = 0;
    #pragma unroll
    for (int i = 0; i < 6; ++i){ wx[i] = aw6[i] * v[i]; swx += wx[i] * wx[i]; }
    double wxn = normclip(wredsumd(swx));
    double s1 = tanh(wxn / xnv * artanh_(xnv)) / wxn;
    double mix[6]; double sm = 0;
    #pragma unroll
    for (int i = 0; i < 6; ++i){ mix[i] = s1 * wx[i]; sm += mix[i] * mix[i]; }
    double n1 = normclip(wredsumd(sm));
    if (n1 > 0.999){ double f = 0.999 / n1;
      #pragma unroll
      for (int i = 0; i < 6; ++i) mix[i] *= f; }
    double sm2 = 0;
    #pragma unroll
    for (int i = 0; i < 6; ++i) sm2 += mix[i] * mix[i];
    double xn2 = normclip(wredsumd(sm2));
    double wx2[6]; double sw2 = 0;
    #pragma unroll
    for (int i = 0; i < 6; ++i){ wx2[i] = aev * mix[i]; sw2 += wx2[i] * wx2[i]; }
    double wxn2 = normclip(wredsumd(sw2));
    double s2 = tanh(wxn2 / xn2 * artanh_(xn2)) / wxn2;
    double tmp[6]; double st = 0;
    #pragma unroll
    for (int i = 0; i < 6; ++i){ tmp[i] = s2 * wx2[i]; st += tmp[i] * tmp[i]; }
    double n2 = normclip(wredsumd(st));
    if (n2 > 0.999){ double f = 0.999 / n2;
      #pragma unroll
      for (int i = 0; i < 6; ++i) tmp[i] *= f; }
    double wx3[6]; double sw3 = 0;
    #pragma unroll
    for (int i = 0; i < 6; ++i){ wx3[i] = tmp[i] * bt6[i]; sw3 += wx3[i] * wx3[i]; }
    double wxn3 = normclip(wredsumd(sw3));
    double s3 = tanh(wxn3 / xnb * art_xnb) / wxn3;
    double t2[6]; double st2 = 0;
    #pragma unroll
    for (int i = 0; i < 6; ++i){ t2[i] = s3 * wx3[i]; st2 += t2[i] * t2[i]; }
    double n3 = normclip(wredsumd(st2));
    if (n3 > 0.999){ double f = 0.999 / n3;
      #pragma unroll
      for (int i = 0; i < 6; ++i) t2[i] *= f; }
    #pragma unroll
    for (int i = 0; i < 6; ++i) t2[i] = fmax(t2[i], 0.0);
    double sxx = 0, syy = 0, sxy = 0;
    #pragma unroll
    for (int i = 0; i < 6; ++i){ sxx += mix[i] * mix[i]; syy += t2[i] * t2[i]; sxy += mix[i] * t2[i]; }
    sxx = wredsumd(sxx); syy = wredsumd(syy); sxy = wredsumd(sxy);
    double dn = fmax(1.0 + 2.0 * sxy + sxx * syy, 1e-15);
    double ca = (1.0 + 2.0 * sxy + syy) / dn, cb = (1.0 - sxx) / dn;
    double m2[6]; double sm3 = 0;
    #pragma unroll
    for (int i = 0; i < 6; ++i){ m2[i] = ca * mix[i] + cb * t2[i]; sm3 += m2[i] * m2[i]; }
    double n4 = normclip(wredsumd(sm3));
    if (n4 > 0.999){ double f = 0.999 / n4;
      #pragma unroll
      for (int i = 0; i < 6; ++i) m2[i] *= f; }
    double snn = 0;
    #pragma unroll
    for (int i = 0; i < 6; ++i) snn += m2[i] * m2[i];
    snn = wredsumd(snn);
    double lam = 2.0 / fmax(1.0 - snn, 1e-15);
    #pragma unroll
    for (int i = 0; i < 6; ++i) atomicAdd(&nom[b * NS + ln + 64 * i], lam * m2[i]);
    if (ln == 0) denacc += lam - 1.0;
  }
  if (ln == 0) atomicAdd(&den[b], denacc);
}

// ---------------- midpoint + logmap0 + output head ----------------
__global__ __launch_bounds__(256) void kfinal(const double* __restrict__ nom,
    const double* __restrict__ den, const double* __restrict__ query,
    const float* __restrict__ Wout, const float* __restrict__ W1,
    const float* __restrict__ b1, const float* __restrict__ W2,
    const float* __restrict__ b2, float* __restrict__ out)
{
  int b = blockIdx.x; int tid = threadIdx.x;
  __shared__ double comb[768];
  __shared__ double att[NH];
  __shared__ double x1[NH];
  __shared__ double red[4];
  double dnb = fmax(den[b], 1e-10);
  double u0 = nom[b * NS + tid] / dnb;
  double u1 = (tid + 256 < NS) ? nom[b * NS + tid + 256] / dnb : 0.0;
  double n = normclip(blocksumd(u0 * u0 + u1 * u1, red));
  double sf = tanh(0.5 * artanh_(n)) / n;
  double f0 = sf * u0, f1 = sf * u1;
  double n2 = normclip(blocksumd(f0 * f0 + f1 * f1, red));
  double sl = artanh_(n2) / n2;
  comb[tid] = sl * f0;
  if (tid + 256 < NS) comb[tid + 256] = sl * f1;
  for (int r = tid; r < NH; r += 256) comb[NH + r] = query[b * NH + r];
  __syncthreads();
  for (int r = tid; r < NH; r += 256){
    double s = 0;
    const float* wr = Wout + (size_t)r * 768;
    for (int c = 0; c < 768; ++c) s += comb[c] * (double)wr[c];
    att[r] = tanh(s);
  }
  __syncthreads();
  for (int r = tid; r < NH; r += 256){
    double s = (double)b1[r];
    const float* wr = W1 + (size_t)r * NH;
    for (int c = 0; c < NH; ++c) s += att[c] * (double)wr[c];
    x1[r] = fmax(s, 0.0);
  }
  __syncthreads();
  double p0 = 0, p1 = 0;
  for (int c = tid; c < NH; c += 256){ p0 += x1[c] * (double)W2[c]; p1 += x1[c] * (double)W2[NH + c]; }
  p0 = blocksumd(p0, red);
  p1 = blocksumd(p1, red);
  if (tid == 0){ out[b * 2 + 0] = (float)(p0 + (double)b2[0]); out[b * 2 + 1] = (float)(p1 + (double)b2[1]); }
}

extern "C" void kernel_launch(void* const* d_in, const int* in_sizes, int n_in,
                              void* d_out, int out_size, void* d_ws, size_t ws_size,
                              hipStream_t stream)
{
  (void)in_sizes; (void)n_in; (void)out_size;
  const float* inputs  = (const float*)d_in[0];
  const float* tstamps = (const float*)d_in[1];
  const float* delta_t = (const float*)d_in[2];
  const float* W_all   = (const float*)d_in[3];
  const float* U_all   = (const float*)d_in[4];
  const float* W_d     = (const float*)d_in[5];
  const float* Win     = (const float*)d_in[6];
  const float* Wout    = (const float*)d_in[7];
  const float* ae      = (const float*)d_in[8];
  const float* ab      = (const float*)d_in[9];
  const float* W1      = (const float*)d_in[10];
  const float* b1      = (const float*)d_in[11];
  const float* W2      = (const float*)d_in[12];
  const float* b2      = (const float*)d_in[13];
  float* out = (float*)d_out;

  // double region
  double* wd = (double*)d_ws;
  size_t od = 0;
  double* NOMD  = wd + od; od += (size_t)NB * NS;
  double* DEND  = wd + od; od += (size_t)NB;
  double* QUERY = wd + od; od += (size_t)NB * NH;
  double* AW    = wd + od; od += (size_t)NB * NS;
  double* BT    = wd + od; od += (size_t)NB * NS;
  double* SCV   = wd + od; od += (size_t)NB * 2;
  // float region
  float* wf = (float*)(wd + od);
  size_t of = 0;
  h16* WTI    = (h16*)(wf + of); of += (size_t)200 * 8192 / 2;  // interleaved fp16 panel (max)
  float* UT   = wf + of; of += (size_t)384 * 1536;
  float* CTX  = wf + of; of += (size_t)NB * NS * NH;
  float* HS   = wf + of; of += (size_t)NB * NH;
  float* HSV  = wf + of; of += (size_t)NB * NH;        // chunk-boundary h state
  float* CCV  = wf + of; of += (size_t)NB * NH;        // chunk-boundary cc state
  float* XNF  = wf + of; of += (size_t)NB * NS * 4;    // {xn, art_xn, axnt, ts}
  float* Qp   = wf + of;                               // Qp chunk buffer (sized by CH)

  size_t base_bytes = od * 8 + of * 4;

  // pick the largest time-chunk whose Qp buffer fits the workspace
  int CH = 0;
  const int chs[7] = {384, 192, 96, 48, 24, 12, 6};
  for (int ci = 0; ci < 7; ++ci){
    size_t need = base_bytes + (size_t)NB * chs[ci] * 1536 * 4;
    if (ws_size >= need){ CH = chs[ci]; break; }
  }

  // zero midpoint accumulators + per-(b,t) scalar precompute
  int nzd = NB * NS + NB;
  hipLaunchKernelGGL(kzerod, dim3((nzd + 255) / 256), dim3(256), 0, stream, NOMD, nzd);
  hipLaunchKernelGGL(kxn, dim3(768), dim3(256), 0, stream, inputs, tstamps, XNF);

  if (CH > 0){
    // interleaved fp16 panel, 1920 useful cols (1.5 MB, L2-resident per XCD)
    int nWI = 200 * 2048 * 2;
    hipLaunchKernelGGL(kprepWI, dim3((nWI + 255) / 256), dim3(256), 0, stream,
                       W_all, W_d, U_all, WTI, 2048);
    hipLaunchKernelGGL(kprepU, dim3((384 * 1536 + 255) / 256), dim3(256), 0, stream, U_all, UT);
    for (int t0 = 0; t0 < NS; t0 += CH){
      hipLaunchKernelGGL(kqgemmc, dim3(24, 2 * CH), dim3(256), 0, stream,
                         inputs, UT, Qp, t0, CH);
      hipLaunchKernelGGL(HIP_KERNEL_NAME(krow<2048, 1>), dim3(128), dim3(512), 0, stream,
                         WTI, inputs, XNF, Qp, CH, t0, t0 + CH,
                         CTX, HS, HSV, CCV, SCV);
    }
  } else {
    // workspace too small even for CH=6: single-launch fallback (U columns in-panel)
    int nWI = 200 * 4096 * 2;
    hipLaunchKernelGGL(kprepWI, dim3((nWI + 255) / 256), dim3(256), 0, stream,
                       W_all, W_d, U_all, WTI, 4096);
    hipLaunchKernelGGL(HIP_KERNEL_NAME(krow<4096, 0>), dim3(128), dim3(512), 0, stream,
                       WTI, inputs, XNF, Qp /*unused*/, 1, 0, NS,
                       CTX, HS, HSV, CCV, SCV);
  }

  hipLaunchKernelGGL(kattn1, dim3(128), dim3(256), 0, stream,
                     HS, Win, CTX, delta_t, ab, QUERY, AW, BT);
  hipLaunchKernelGGL(kmix, dim3(12, 128), dim3(256), 0, stream, CTX, AW, BT, ae, NOMD, DEND);
  hipLaunchKernelGGL(kfinal, dim3(128), dim3(256), 0, stream,
                     NOMD, DEND, QUERY, Wout, W1, b1, W2, b2, out);
}